// Round 5
// baseline (736.807 us; speedup 1.0000x reference)
//
#include <hip/hip_runtime.h>
#include <hip/hip_bf16.h>

// ---- problem constants ----
#define BQ 16      // batch
#define CN 96      // channels
#define HQ 48      // quadrant H = W
#define LL 2304    // HQ*HQ
#define NK 4       // scan directions
#define RR 6       // dt rank
#define NNS 8      // state size
#define DPJ 22     // R + 2N
#define CRr 12     // attention rank
#define LOG2E 1.4426950408889634f

using bf16 = __hip_bfloat16;

__device__ __forceinline__ float b2f(bf16 v) { return __bfloat162float(v); }
__device__ __forceinline__ bf16  f2b(float v){ return __float2bfloat16(v); }
__device__ __forceinline__ float bflo(unsigned u){ return __uint_as_float(u << 16); }
__device__ __forceinline__ float bfhi(unsigned u){ return __uint_as_float(u & 0xffff0000u); }
__device__ __forceinline__ float sigf(float x){ return 1.f / (1.f + __expf(-x)); }
__device__ __forceinline__ float siluf(float x){ return x / (1.f + __expf(-x)); }
__device__ __forceinline__ unsigned packbf(float a, float b){
    unsigned lo = (unsigned)__builtin_bit_cast(unsigned short, f2b(a));
    unsigned hi = (unsigned)__builtin_bit_cast(unsigned short, f2b(b));
    return lo | (hi << 16);
}
__device__ __forceinline__ unsigned rot16(unsigned u){ return (u >> 16) | (u << 16); }
__device__ __forceinline__ void unpack8(uint4 v, float* f){
    f[0]=bflo(v.x); f[1]=bfhi(v.x); f[2]=bflo(v.y); f[3]=bfhi(v.y);
    f[4]=bflo(v.z); f[5]=bfhi(v.z); f[6]=bflo(v.w); f[7]=bfhi(v.w);
}
__device__ __forceinline__ void unpack4(uint2 v, float* f){
    f[0]=bflo(v.x); f[1]=bfhi(v.x); f[2]=bflo(v.y); f[3]=bfhi(v.y);
}
__device__ __forceinline__ float fexp2(float x){
#if __has_builtin(__builtin_amdgcn_exp2f)
    return __builtin_amdgcn_exp2f(x);
#else
    return __expf(x * 0.6931471805599453f);
#endif
}
// quad_perm DPP xor within groups of 4 lanes (VALU pipe, no LDS)
__device__ __forceinline__ float qxor(float v, int ctrl_b1){
    int x;
    if (ctrl_b1) x = __builtin_amdgcn_mov_dpp(__float_as_int(v), 0xB1, 0xF, 0xF, true);
    else         x = __builtin_amdgcn_mov_dpp(__float_as_int(v), 0x4E, 0xF, 0xF, true);
    return __int_as_float(x);
}

// ============================================================================
// K1: channel LN + conv1x1 (a-branch with silu, z-branch raw -> bf16)
// grid (24, 16, 4) = (hh-pair, b, q), block 192
// ============================================================================
__global__ __launch_bounds__(192) void k_lnconv(
    const float* __restrict__ x, const float* __restrict__ ln_g, const float* __restrict__ ln_b,
    const float* __restrict__ p1w, const float* __restrict__ p1b,
    const float* __restrict__ p2w, const float* __restrict__ p2b,
    bf16* __restrict__ a_out, bf16* __restrict__ z0_out)
{
    const int hh2 = blockIdx.x;           // 0..23 (covers 2 rows each)
    const int b = blockIdx.y, q = blockIdx.z;
    const int h0 = (q >> 1) * HQ, w0 = (q & 1) * HQ;
    const int tid = threadIdx.x;
    const int qb = q * BQ + b;

    __shared__ alignas(16) bf16 hn[CN * 96];    // [c][p], p = local pos 0..95 (2 rows x 48)
    __shared__ alignas(16) bf16 wl[CN * 200];   // [c][row 0..191, pad to 200]
    __shared__ float mu[96], rs[96];

    // stage weights transposed: wl[c][d] = p1, wl[c][96+d] = p2in
    for (int t = tid; t < CN * CN; t += 192) {
        int d = t / CN, c = t % CN;
        wl[c * 200 + d]      = f2b(p1w[(q * CN + d) * CN + c]);
        wl[c * 200 + 96 + d] = f2b(p2w[(q * CN + d) * CN + c]);
    }
    // stage x tile: float4 loads, packed uint2 LDS writes
    for (int t = tid; t < CN * 24; t += 192) {
        int c = t / 24, v = t % 24;
        int row = v / 12, col = (v % 12) * 4;
        float4 xv = *reinterpret_cast<const float4*>(
            &x[((b * CN + c) * 96 + h0 + 2 * hh2 + row) * 96 + w0 + col]);
        uint2 pk; pk.x = packbf(xv.x, xv.y); pk.y = packbf(xv.z, xv.w);
        *reinterpret_cast<uint2*>(&hn[c * 96 + v * 4]) = pk;
    }
    __syncthreads();
    // LN stats per position
    if (tid < 96) {
        float s = 0.f, s2 = 0.f;
        for (int c = 0; c < CN; ++c) { float v = b2f(hn[c * 96 + tid]); s += v; s2 += v * v; }
        float m = s * (1.f / 96.f);
        float var = s2 * (1.f / 96.f) - m * m;
        mu[tid] = m; rs[tid] = rsqrtf(var + 1e-6f);
    }
    __syncthreads();
    // normalize in place
    for (int t = tid; t < CN * 96; t += 192) {
        int c = t / 96, p = t % 96;
        float g = ln_g[q * CN + c], bb = ln_b[q * CN + c];
        hn[t] = f2b((b2f(hn[t]) - mu[p]) * rs[p] * g + bb);
    }
    __syncthreads();
    // matvec: thread -> 8 output rows x 12 positions
    const int rg = tid >> 3, pg = tid & 7;
    const int row0 = rg * 8, pp0 = pg * 12;
    float acc[8][12];
    #pragma unroll
    for (int i = 0; i < 8; ++i)
        #pragma unroll
        for (int j = 0; j < 12; ++j) acc[i][j] = 0.f;

    for (int c = 0; c < CN; ++c) {
        uint4 wv = *reinterpret_cast<const uint4*>(&wl[c * 200 + row0]);
        float w[8];
        w[0] = bflo(wv.x); w[1] = bfhi(wv.x);
        w[2] = bflo(wv.y); w[3] = bfhi(wv.y);
        w[4] = bflo(wv.z); w[5] = bfhi(wv.z);
        w[6] = bflo(wv.w); w[7] = bfhi(wv.w);
        uint2 ha = *reinterpret_cast<const uint2*>(&hn[c * 96 + pp0]);
        uint2 hb = *reinterpret_cast<const uint2*>(&hn[c * 96 + pp0 + 4]);
        uint2 hc = *reinterpret_cast<const uint2*>(&hn[c * 96 + pp0 + 8]);
        float hv[12];
        hv[0] = bflo(ha.x); hv[1] = bfhi(ha.x); hv[2]  = bflo(ha.y); hv[3]  = bfhi(ha.y);
        hv[4] = bflo(hb.x); hv[5] = bfhi(hb.x); hv[6]  = bflo(hb.y); hv[7]  = bfhi(hb.y);
        hv[8] = bflo(hc.x); hv[9] = bfhi(hc.x); hv[10] = bflo(hc.y); hv[11] = bfhi(hc.y);
        #pragma unroll
        for (int i = 0; i < 8; ++i)
            #pragma unroll
            for (int j = 0; j < 12; ++j)
                acc[i][j] = fmaf(w[i], hv[j], acc[i][j]);
    }
    // epilogue: packed bf16 stores (12 contiguous elems per row)
    const int lbase = (2 * hh2 + pp0 / 48) * 48 + (pp0 % 48);
    #pragma unroll
    for (int i = 0; i < 8; ++i) {
        int row = row0 + i;
        bool isA = row < 96;
        int d = isA ? row : row - 96;
        float bias = isA ? p1b[q * CN + d] : p2b[q * CN + d];
        int oidx = (qb * CN + d) * LL + lbase;
        float v[12];
        #pragma unroll
        for (int j = 0; j < 12; ++j) v[j] = acc[i][j] + bias;
        if (isA) {
            #pragma unroll
            for (int j = 0; j < 12; ++j) v[j] = siluf(v[j]);
        }
        uint2 w0p, w1p, w2p;
        w0p.x = packbf(v[0], v[1]);  w0p.y = packbf(v[2], v[3]);
        w1p.x = packbf(v[4], v[5]);  w1p.y = packbf(v[6], v[7]);
        w2p.x = packbf(v[8], v[9]);  w2p.y = packbf(v[10], v[11]);
        bf16* dst = isA ? a_out : z0_out;
        *reinterpret_cast<uint2*>(&dst[oidx])     = w0p;
        *reinterpret_cast<uint2*>(&dst[oidx + 4]) = w1p;
        *reinterpret_cast<uint2*>(&dst[oidx + 8]) = w2p;
    }
}

// ============================================================================
// K2: depthwise 3x3 SAME + bias + silu + block_idx transform (bf16 in/out)
// grid (96, 16, 4) = (c, b, q), block 256
// ============================================================================
__global__ __launch_bounds__(256) void k_dwconv(
    const bf16* __restrict__ z0, const float* __restrict__ dww, const float* __restrict__ dwb,
    const int* __restrict__ bidx, bf16* __restrict__ zt, bf16* __restrict__ ztT)
{
    const int c = blockIdx.x, b = blockIdx.y, q = blockIdx.z;
    const int tid = threadIdx.x;
    const int base = ((q * BQ + b) * CN + c) * LL;
    __shared__ float zin[LL];
    __shared__ float zo[48 * 49];   // padded rows: conflict-free transposed reads
    for (int t = tid; t < 288; t += 256) {
        uint4 v = *reinterpret_cast<const uint4*>(&z0[base + t * 8]);
        float f[8]; unpack8(v, f);
        *reinterpret_cast<float4*>(&zin[t * 8])     = make_float4(f[0], f[1], f[2], f[3]);
        *reinterpret_cast<float4*>(&zin[t * 8 + 4]) = make_float4(f[4], f[5], f[6], f[7]);
    }
    float wk[9];
    #pragma unroll
    for (int i = 0; i < 9; ++i) wk[i] = dww[(q * CN + c) * 9 + i];
    const float bias = dwb[q * CN + c];
    __syncthreads();
    for (int t = tid; t < LL; t += 256) {
        int hh = t / 48, ww = t % 48;
        float s = bias;
        #pragma unroll
        for (int dy = -1; dy <= 1; ++dy)
            #pragma unroll
            for (int dx = -1; dx <= 1; ++dx) {
                int yy = hh + dy, xx = ww + dx;
                if (yy >= 0 && yy < 48 && xx >= 0 && xx < 48)
                    s = fmaf(wk[(dy + 1) * 3 + (dx + 1)], zin[yy * 48 + xx], s);
            }
        zo[hh * 49 + ww] = siluf(s);
    }
    __syncthreads();
    const bool even = ((bidx[0] & 1) == 0);
    for (int t = tid; t < LL; t += 256) {
        int i = t / 48, j = t % 48;
        float vz, vzT;
        if (even) { vz = zo[j * 49 + i];               vzT = zo[i * 49 + j]; }
        else      { vz = zo[(47 - i) * 49 + (47 - j)]; vzT = zo[(47 - j) * 49 + (47 - i)]; }
        zt[base + t]  = f2b(vz);
        ztT[base + t] = f2b(vzT);
    }
}

// ============================================================================
// K3: x_dbl = xproj_w @ u_k  (direction mapping + reversal folded in)
// grid (12, 4, 64) = (l-tile, k, q*16+b), block 256
// compute retiled: 2 d-rows x 12 l = 176 tiles, single pass
// ============================================================================
__global__ __launch_bounds__(256) void k_xdbl(
    const bf16* __restrict__ zt, const bf16* __restrict__ ztT,
    const float* __restrict__ xprojw, bf16* __restrict__ xdbl)
{
    const int lt = blockIdx.x, k = blockIdx.y, qb = blockIdx.z;
    const int tid = threadIdx.x;
    const int l0 = lt * 192;
    const int q = qb >> 4;
    __shared__ alignas(16) bf16 ul[CN * 200];
    __shared__ alignas(16) bf16 wl[CN * 24];    // transposed [c][d], pad 22->24
    const bf16* __restrict__ src = (k & 1) ? ztT : zt;
    const bool rev = (k >= 2);
    // vectorized staging: 96c x 24 vectors of 8 bf16
    for (int t = tid; t < CN * 24; t += 256) {
        int cc = t / 24, j0 = (t % 24) * 8;
        uint4 v;
        if (!rev) {
            v = *reinterpret_cast<const uint4*>(&src[(size_t)(qb * CN + cc) * LL + l0 + j0]);
        } else {
            v = *reinterpret_cast<const uint4*>(&src[(size_t)(qb * CN + cc) * LL + (LL - (l0 + j0) - 8)]);
            uint4 r; r.x = rot16(v.w); r.y = rot16(v.z); r.z = rot16(v.y); r.w = rot16(v.x);
            v = r;
        }
        *reinterpret_cast<uint4*>(&ul[cc * 200 + j0]) = v;
    }
    for (int t = tid; t < DPJ * CN; t += 256) {
        int d = t / CN, c = t % CN;
        wl[c * 24 + d] = f2b(xprojw[(q * NK + k) * DPJ * CN + t]);
    }
    __syncthreads();
    // tiles: 2 d-rows x 12 l : 11 * 16 = 176 tiles, single pass
    if (tid < 176) {
        const int dp = tid / 16, lg = tid % 16;
        const int d0 = dp * 2, llp = lg * 12;
        float acc0[12], acc1[12];
        #pragma unroll
        for (int j = 0; j < 12; ++j) { acc0[j] = 0.f; acc1[j] = 0.f; }
        for (int c = 0; c < CN; ++c) {
            unsigned wv = *reinterpret_cast<const unsigned*>(&wl[c * 24 + d0]);
            float w0 = bflo(wv), w1 = bfhi(wv);
            uint2 ua = *reinterpret_cast<const uint2*>(&ul[c * 200 + llp]);
            uint2 ub = *reinterpret_cast<const uint2*>(&ul[c * 200 + llp + 4]);
            uint2 uc = *reinterpret_cast<const uint2*>(&ul[c * 200 + llp + 8]);
            float uf[12];
            unpack4(ua, uf); unpack4(ub, uf + 4); unpack4(uc, uf + 8);
            #pragma unroll
            for (int j = 0; j < 12; ++j) {
                acc0[j] = fmaf(w0, uf[j], acc0[j]);
                acc1[j] = fmaf(w1, uf[j], acc1[j]);
            }
        }
        int ob = (qb * NK + k) * DPJ * LL + l0 + llp;
        uint2 o0a, o0b, o0c, o1a, o1b, o1c;
        o0a.x = packbf(acc0[0], acc0[1]);  o0a.y = packbf(acc0[2], acc0[3]);
        o0b.x = packbf(acc0[4], acc0[5]);  o0b.y = packbf(acc0[6], acc0[7]);
        o0c.x = packbf(acc0[8], acc0[9]);  o0c.y = packbf(acc0[10], acc0[11]);
        o1a.x = packbf(acc1[0], acc1[1]);  o1a.y = packbf(acc1[2], acc1[3]);
        o1b.x = packbf(acc1[4], acc1[5]);  o1b.y = packbf(acc1[6], acc1[7]);
        o1c.x = packbf(acc1[8], acc1[9]);  o1c.y = packbf(acc1[10], acc1[11]);
        *reinterpret_cast<uint2*>(&xdbl[ob + d0 * LL])           = o0a;
        *reinterpret_cast<uint2*>(&xdbl[ob + d0 * LL + 4])       = o0b;
        *reinterpret_cast<uint2*>(&xdbl[ob + d0 * LL + 8])       = o0c;
        *reinterpret_cast<uint2*>(&xdbl[ob + (d0 + 1) * LL])     = o1a;
        *reinterpret_cast<uint2*>(&xdbl[ob + (d0 + 1) * LL + 4]) = o1b;
        *reinterpret_cast<uint2*>(&xdbl[ob + (d0 + 1) * LL + 8]) = o1c;
    }
}

// ============================================================================
// K4: fused delta(softplus) + selective scan + Ds*u term
// grid (512), block 384 = producer/consumer wave specialization:
//   waves 0-2 (tid 0-191):   SCAN  - u in regs, serial scan, y store
//   waves 3-5 (tid 192-383): PROD  - xdbl load + commit + delta(softplus)
// 12 waves/CU (3/SIMD) vs 6 before: producer issue fills scanner stall slots.
// Triple-buffered xr/dd/bcv; ONE lgkmcnt-only barrier per chunk (global
// loads stay in flight across it). Pipeline at iter ch:
//   PROD: commit(ch+2) | prefetch px(ch+4) | delta(ch+1)
//   SCAN: scan(ch) | refill u(ch+2)
// Hazards (all mod-3 distinct or barrier-separated): scan reads buf ch;
// delta writes ch+1; commit writes ch+2; scan finished ch-1==ch+2 at the
// barrier ending iter ch-1.
// ============================================================================

// raw barrier: drain LDS (cross-wave visibility of ds_writes) but NOT vmcnt
#define SCAN_BARRIER() asm volatile("s_waitcnt lgkmcnt(0)\n\ts_barrier" ::: "memory")

// word IDX (0..23) of a 6-uint4 register array holding 48 bf16
// (param must NOT be named x/y/z/w: the preprocessor would substitute the
//  member-access tokens too)
#define UWORD(NUA, IDX) (((IDX) & 3) == 0 ? NUA[(IDX) >> 2].x : \
                         ((IDX) & 3) == 1 ? NUA[(IDX) >> 2].y : \
                         ((IDX) & 3) == 2 ? NUA[(IDX) >> 2].z : NUA[(IDX) >> 2].w)

#define ROT3(v) (v) = ((v) == 2) ? 0 : ((v) + 1)

__global__ __launch_bounds__(384) void k_scan(
    const bf16* __restrict__ zt, const bf16* __restrict__ ztT,
    const bf16* __restrict__ xdbl,
    const float* __restrict__ dtw_g, const float* __restrict__ dtb_g,
    const float* __restrict__ Alog_g, const float* __restrict__ Ds_g,
    bf16* __restrict__ ys)
{
    const int bid = blockIdx.x;
    const int ch2 = bid & 1, k = (bid >> 1) & 3, qb = bid >> 3, q = qb >> 4;
    const int qk = q * NK + k;
    const int tid = threadIdx.x;
    const bool isScan = (tid < 192);
    const int lt = isScan ? tid : (tid - 192);   // role-local 0..191
    const int ca = lt >> 2, p = lt & 3;
    const int c = ch2 * 48 + ca;          // global channel

    __shared__ float dd3[3][48 * 52];
    __shared__ float xr3[3][6 * 52];          // dts rows
    __shared__ float bcv3[3][48 * 16];        // [j][p*4 + {B0,B1,C0,C1}]

    const bf16* __restrict__ src = (k & 1) ? ztT : zt;
    const bool rev = (k >= 2);
    const int ja = p * 12;

    // ---- producer-role parameters ----
    float wdt[6] = {0.f, 0.f, 0.f, 0.f, 0.f, 0.f};
    float dtbc = 0.f;
    if (!isScan) {
        const float* wp = dtw_g + (size_t)qk * CN * RR + c * RR;
        float2 wa = *reinterpret_cast<const float2*>(wp);
        float2 wb = *reinterpret_cast<const float2*>(wp + 2);
        float2 wc = *reinterpret_cast<const float2*>(wp + 4);
        wdt[0] = wa.x; wdt[1] = wa.y; wdt[2] = wb.x; wdt[3] = wb.y; wdt[4] = wc.x; wdt[5] = wc.y;
        dtbc = dtb_g[qk * CN + c];
    }
    // xdbl staging: producer threads with lt<132 stage one uint4 from row vr
    const bool xload = (!isScan) && (lt < 132);
    const int vr = lt / 6, jx = (lt % 6) * 8;
    const bf16* gx = xdbl + (size_t)(qb * NK + k) * (DPJ * LL) + (size_t)vr * LL + jx;
    int bccol = 0;
    if (vr >= 6) {
        int v = vr - 6;           // 0..15: 0-7 B, 8-15 C
        int n = v & 7;
        bccol = (n >> 1) * 4 + ((v >= 8) ? 2 : 0) + (n & 1);
    }

    // ---- scan-role parameters ----
    float A0L = 0.f, A1L = 0.f, Dc = 0.f;
    if (isScan) {
        A0L = -__expf(Alog_g[((size_t)qk * CN + c) * NNS + 2 * p])     * LOG2E;
        A1L = -__expf(Alog_g[((size_t)qk * CN + c) * NNS + 2 * p + 1]) * LOG2E;
        Dc = Ds_g[qk * CN + c];
    }
    float h0 = 0.f, h1 = 0.f;
    const bf16* gu = src + (size_t)(qb * CN + c) * LL + (rev ? (LL - 48) : 0);
    const int ustep = rev ? -48 : 48;
    bf16* yp = ys + (size_t)(qb * NK + k) * (CN * LL) + (size_t)c * LL;  // p==0 stores

    #define COMMIT_BLOCK(PXV, XRB, BCB) do {                                          \
        if (xload) {                                                                  \
            float g[8]; unpack8(PXV, g);                                              \
            if (vr < 6) {                                                             \
                *reinterpret_cast<float4*>(&(XRB)[vr * 52 + jx])                      \
                    = make_float4(g[0], g[1], g[2], g[3]);                            \
                *reinterpret_cast<float4*>(&(XRB)[vr * 52 + jx + 4])                  \
                    = make_float4(g[4], g[5], g[6], g[7]);                            \
            } else {                                                                  \
                _Pragma("unroll")                                                     \
                for (int i = 0; i < 8; ++i) (BCB)[(jx + i) * 16 + bccol] = g[i];      \
            }                                                                         \
        }                                                                             \
    } while (0)

    #define DELTA_BLOCK(XRB, DDB) do {                                                \
        float acc[12];                                                                \
        _Pragma("unroll")                                                             \
        for (int i = 0; i < 12; ++i) acc[i] = dtbc;                                   \
        _Pragma("unroll")                                                             \
        for (int r = 0; r < 6; ++r) {                                                 \
            float4 d0 = *reinterpret_cast<const float4*>(&(XRB)[r * 52 + ja]);        \
            float4 d1 = *reinterpret_cast<const float4*>(&(XRB)[r * 52 + ja + 4]);    \
            float4 d2 = *reinterpret_cast<const float4*>(&(XRB)[r * 52 + ja + 8]);    \
            float wr_ = wdt[r];                                                       \
            acc[0] = fmaf(wr_, d0.x, acc[0]);  acc[1] = fmaf(wr_, d0.y, acc[1]);      \
            acc[2] = fmaf(wr_, d0.z, acc[2]);  acc[3] = fmaf(wr_, d0.w, acc[3]);      \
            acc[4] = fmaf(wr_, d1.x, acc[4]);  acc[5] = fmaf(wr_, d1.y, acc[5]);      \
            acc[6] = fmaf(wr_, d1.z, acc[6]);  acc[7] = fmaf(wr_, d1.w, acc[7]);      \
            acc[8] = fmaf(wr_, d2.x, acc[8]);  acc[9] = fmaf(wr_, d2.y, acc[9]);      \
            acc[10] = fmaf(wr_, d2.z, acc[10]); acc[11] = fmaf(wr_, d2.w, acc[11]);   \
        }                                                                             \
        _Pragma("unroll")                                                             \
        for (int i = 0; i < 12; ++i) {                                                \
            float a = acc[i];                                                         \
            acc[i] = (a > 15.f) ? a : __logf(1.f + __expf(a));                        \
        }                                                                             \
        float4* dp = reinterpret_cast<float4*>(&(DDB)[ca * 52 + ja]);                 \
        dp[0] = make_float4(acc[0], acc[1], acc[2], acc[3]);                          \
        dp[1] = make_float4(acc[4], acc[5], acc[6], acc[7]);                          \
        dp[2] = make_float4(acc[8], acc[9], acc[10], acc[11]);                        \
    } while (0)

    // ---- prologue ----
    uint4 u_a[6], u_b[6];
    uint4 px_a = {0,0,0,0}, px_b = {0,0,0,0}, px1 = {0,0,0,0};
    if (isScan) {
        #pragma unroll
        for (int i = 0; i < 6; ++i) u_a[i] = *reinterpret_cast<const uint4*>(gu + i * 8);  // chunk 0
        gu += ustep;
        #pragma unroll
        for (int i = 0; i < 6; ++i) u_b[i] = *reinterpret_cast<const uint4*>(gu + i * 8);  // chunk 1
        gu += ustep;                                           // -> chunk 2
    } else {
        uint4 px0 = {0,0,0,0};
        if (xload) {
            px0  = *reinterpret_cast<const uint4*>(gx);        // chunk 0
            px1  = *reinterpret_cast<const uint4*>(gx + 48);   // chunk 1
            px_a = *reinterpret_cast<const uint4*>(gx + 96);   // chunk 2
            px_b = *reinterpret_cast<const uint4*>(gx + 144);  // chunk 3
            gx += 192;                                         // -> chunk 4
        }
        COMMIT_BLOCK(px0, xr3[0], bcv3[0]);
    }
    SCAN_BARRIER();
    if (!isScan) {
        DELTA_BLOCK(xr3[0], dd3[0]);
        COMMIT_BLOCK(px1, xr3[1], bcv3[1]);
    }
    SCAN_BARRIER();

    // buffer cursors
    int s_cur = 0;              // scan:  buf of chunk ch
    int d_idx = 1, c_idx = 2;   // prod:  delta buf (ch+1), commit buf (ch+2)

    #define PROD_BODY(CH, PX) do {                                                    \
        const int chp_ = (CH);                                                        \
        if (chp_ + 2 < 48) COMMIT_BLOCK(PX, xr3[c_idx], bcv3[c_idx]);                 \
        if (chp_ + 4 < 48 && xload) { PX = *reinterpret_cast<const uint4*>(gx); gx += 48; } \
        if (chp_ + 1 < 48) DELTA_BLOCK(xr3[d_idx], dd3[d_idx]);                       \
        ROT3(d_idx); ROT3(c_idx);                                                     \
    } while (0)

    #define SCAN_CHUNK(CH, UC) do {                                                   \
        const int ch_ = (CH);                                                         \
        uint4 nu[6];                                                                  \
        if (!rev) {                                                                   \
            nu[0] = UC[0]; nu[1] = UC[1]; nu[2] = UC[2];                              \
            nu[3] = UC[3]; nu[4] = UC[4]; nu[5] = UC[5];                              \
        } else {                                                                      \
            _Pragma("unroll")                                                         \
            for (int qq = 0; qq < 6; ++qq) {                                          \
                nu[qq].x = rot16(UC[5 - qq].w); nu[qq].y = rot16(UC[5 - qq].z);       \
                nu[qq].z = rot16(UC[5 - qq].y); nu[qq].w = rot16(UC[5 - qq].x);       \
            }                                                                         \
        }                                                                             \
        {                                                                             \
            const int l0 = ch_ * 48;                                                  \
            const float* ddc = &dd3[s_cur][ca * 52];                                  \
            const float* bcc = &bcv3[s_cur][p * 4];                                   \
            _Pragma("unroll")                                                         \
            for (int gg = 0; gg < 6; ++gg) {                                          \
                unsigned pk[4];                                                       \
                _Pragma("unroll")                                                     \
                for (int half = 0; half < 2; ++half) {                                \
                    const int j0 = gg * 8 + half * 4;                                 \
                    float4 d4 = *reinterpret_cast<const float4*>(ddc + j0);           \
                    const float* df = reinterpret_cast<const float*>(&d4);            \
                    _Pragma("unroll")                                                 \
                    for (int s = 0; s < 4; ++s) {                                     \
                        const int j = j0 + s;                                         \
                        const unsigned uwv = UWORD(nu, j >> 1);                       \
                        float u = (j & 1) ? bfhi(uwv) : bflo(uwv);                    \
                        float d = df[s];                                              \
                        float4 bq = *reinterpret_cast<const float4*>(bcc + j * 16);   \
                        float du = d * u;                                             \
                        float dA0 = fexp2(d * A0L);                                   \
                        float dA1 = fexp2(d * A1L);                                   \
                        h0 = fmaf(dA0, h0, du * bq.x);                                \
                        h1 = fmaf(dA1, h1, du * bq.y);                                \
                        float y = fmaf(h0, bq.z, h1 * bq.w);                          \
                        y += qxor(y, 1); y += qxor(y, 0);                             \
                        y = fmaf(Dc, u, y);                                           \
                        unsigned hb = (unsigned)__builtin_bit_cast(unsigned short, f2b(y)); \
                        const int sl = half * 4 + s;                                  \
                        if (sl & 1) pk[sl >> 1] |= hb << 16; else pk[sl >> 1] = hb;   \
                    }                                                                 \
                }                                                                     \
                if (p == 0) {                                                         \
                    uint4 wv4; wv4.x = pk[0]; wv4.y = pk[1]; wv4.z = pk[2]; wv4.w = pk[3]; \
                    *reinterpret_cast<uint4*>(yp + l0 + gg * 8) = wv4;                \
                }                                                                     \
            }                                                                         \
        }                                                                             \
        if (ch_ + 2 < 48) {                                                           \
            _Pragma("unroll")                                                         \
            for (int i = 0; i < 6; ++i) UC[i] = *reinterpret_cast<const uint4*>(gu + i * 8); \
            gu += ustep;                                                              \
        }                                                                             \
        ROT3(s_cur);                                                                  \
    } while (0)

    for (int t = 0; t < 24; ++t) {
        if (isScan) SCAN_CHUNK(2 * t, u_a);
        else        PROD_BODY(2 * t, px_a);
        SCAN_BARRIER();
        if (isScan) SCAN_CHUNK(2 * t + 1, u_b);
        else        PROD_BODY(2 * t + 1, px_b);
        SCAN_BARRIER();
    }

    #undef SCAN_CHUNK
    #undef PROD_BODY
    #undef DELTA_BLOCK
    #undef COMMIT_BLOCK
}

// ============================================================================
// K4b: k_sum — combine 4 directions into one tensor at combine-index m
// grid (96, 16, 4) = (c, b, q), block 256
// ============================================================================
__global__ __launch_bounds__(256) void k_sum(
    const bf16* __restrict__ ys, bf16* __restrict__ s_out)
{
    const int c = blockIdx.x, b = blockIdx.y, q = blockIdx.z;
    const int qb = q * BQ + b;
    const int tid = threadIdx.x;
    __shared__ float t0[48 * 49];
    __shared__ float t2[48 * 49];
    const size_t base0 = ((size_t)(qb * NK + 0) * CN + c) * LL;
    const size_t base1 = ((size_t)(qb * NK + 1) * CN + c) * LL;
    const size_t base2 = ((size_t)(qb * NK + 2) * CN + c) * LL;
    const size_t base3 = ((size_t)(qb * NK + 3) * CN + c) * LL;
    for (int idx = tid; idx < 288; idx += 256) {
        int e0 = idx * 8, h = e0 / 48, w = e0 % 48;
        float f[8];
        unpack8(*reinterpret_cast<const uint4*>(&ys[base0 + e0]), f);
        #pragma unroll
        for (int i = 0; i < 8; ++i) t0[h * 49 + w + i] = f[i];
        unpack8(*reinterpret_cast<const uint4*>(&ys[base2 + e0]), f);
        #pragma unroll
        for (int i = 0; i < 8; ++i) t2[h * 49 + w + i] = f[i];
    }
    __syncthreads();
    const size_t cbase = ((size_t)qb * CN + c) * LL;
    for (int idx = tid; idx < 288; idx += 256) {
        int m0 = idx * 8, ww = m0 / 48, hh = m0 % 48;
        float f1[8], f3[8];
        unpack8(*reinterpret_cast<const uint4*>(&ys[base1 + m0]), f1);
        unpack8(*reinterpret_cast<const uint4*>(&ys[base3 + (LL - 8 - m0)]), f3);
        float o[8];
        #pragma unroll
        for (int i = 0; i < 8; ++i) {
            float v0 = t0[(hh + i) * 49 + ww];
            float v2 = t2[(47 - hh - i) * 49 + (47 - ww)];
            o[i] = v0 + f1[i] + v2 + f3[7 - i];
        }
        uint4 w;
        w.x = packbf(o[0], o[1]); w.y = packbf(o[2], o[3]);
        w.z = packbf(o[4], o[5]); w.w = packbf(o[6], o[7]);
        *reinterpret_cast<uint4*>(&s_out[cbase + m0]) = w;
    }
}

// ============================================================================
// K5: combine: LN(ssln) + LN(p2n) + y=a*z + attention partial sums
// grid (48, 16, 4) = (ww, b, q), block 256
// ============================================================================
__global__ __launch_bounds__(256) void k_combine(
    const bf16* __restrict__ s_in, const bf16* __restrict__ a_in,
    const float* __restrict__ ssg, const float* __restrict__ ssb,
    const float* __restrict__ png, const float* __restrict__ pnb,
    const int* __restrict__ bidx,
    bf16* __restrict__ y_out, float* __restrict__ s_buf)
{
    const int ww = blockIdx.x, b = blockIdx.y, q = blockIdx.z;
    const int qb = q * BQ + b;
    const int tid = threadIdx.x;
    __shared__ float o[CN * 48];
    __shared__ float mu[48], rs[48];
    for (int v = tid; v < 576; v += 256) {
        int e0 = v * 8, cc = e0 / 48, hh = e0 % 48;
        float f[8];
        unpack8(*reinterpret_cast<const uint4*>(&s_in[((size_t)qb * CN + cc) * LL + ww * 48 + hh]), f);
        #pragma unroll
        for (int i = 0; i < 8; ++i) o[cc * 48 + hh + i] = f[i];
    }
    __syncthreads();
    if (tid < 48) {
        float s = 0.f, s2 = 0.f;
        for (int cc = 0; cc < CN; ++cc) { float v = o[cc * 48 + tid]; s += v; s2 += v * v; }
        float m = s * (1.f / 96.f), var = s2 * (1.f / 96.f) - m * m;
        mu[tid] = m; rs[tid] = rsqrtf(var + 1e-6f);
    }
    __syncthreads();
    for (int t = tid; t < CN * 48; t += 256) {
        int cc = t / 48, hh = t % 48;
        o[t] = (o[t] - mu[hh]) * rs[hh] * ssg[q * CN + cc] + ssb[q * CN + cc];
    }
    __syncthreads();
    if (tid < 48) {
        float s = 0.f, s2 = 0.f;
        for (int cc = 0; cc < CN; ++cc) { float v = o[cc * 48 + tid]; s += v; s2 += v * v; }
        float m = s * (1.f / 96.f), var = s2 * (1.f / 96.f) - m * m;
        mu[tid] = m; rs[tid] = rsqrtf(var + 1e-6f);
    }
    __syncthreads();
    const bool even = ((bidx[0] & 1) == 0);
    if (even) {
        for (int v = tid; v < 576; v += 256) {
            int e0 = v * 8, cc = e0 / 48, hh = e0 % 48;
            size_t oidx = ((size_t)qb * CN + cc) * LL + ww * 48 + hh;
            float af[8];
            unpack8(*reinterpret_cast<const uint4*>(&a_in[oidx]), af);
            float yv[8];
            #pragma unroll
            for (int i = 0; i < 8; ++i) {
                float z2 = (o[cc * 48 + hh + i] - mu[hh + i]) * rs[hh + i] * png[q * CN + cc] + pnb[q * CN + cc];
                yv[i] = af[i] * z2;
                o[cc * 48 + hh + i] = yv[i];
            }
            uint4 w;
            w.x = packbf(yv[0], yv[1]); w.y = packbf(yv[2], yv[3]);
            w.z = packbf(yv[4], yv[5]); w.w = packbf(yv[6], yv[7]);
            *reinterpret_cast<uint4*>(&y_out[oidx]) = w;
        }
    } else {
        for (int t = tid; t < CN * 48; t += 256) {
            int cc = t / 48, hh = t % 48;
            float z2 = (o[t] - mu[hh]) * rs[hh] * png[q * CN + cc] + pnb[q * CN + cc];
            size_t oidx = ((size_t)qb * CN + cc) * LL + (47 - hh) * 48 + (47 - ww);
            float yv = b2f(a_in[oidx]) * z2;
            y_out[oidx] = f2b(yv);
            o[t] = yv;
        }
    }
    __syncthreads();
    if (tid < CN) {
        float s = 0.f;
        for (int j = 0; j < 48; ++j) s += o[tid * 48 + j];
        atomicAdd(&s_buf[qb * CN + tid], s);
    }
}

// ============================================================================
// K7: out = x + y * att  with channel attention computed in-block
// grid (96, 16, 4) = (c, b, q), block 256
// ============================================================================
__global__ __launch_bounds__(256) void k_final(
    const float* __restrict__ x, const bf16* __restrict__ y_in,
    const float* __restrict__ s_buf,
    const float* __restrict__ w1, const float* __restrict__ b1,
    const float* __restrict__ w2, const float* __restrict__ b2,
    float* __restrict__ out)
{
    const int c = blockIdx.x, b = blockIdx.y, q = blockIdx.z;
    const int h0 = (q >> 1) * HQ, w0 = (q & 1) * HQ;
    const int qb = q * BQ + b;
    const int tid = threadIdx.x;
    __shared__ float tl[CRr];
    __shared__ float attv;
    if (tid < CRr) {
        float acc = b1[q * CRr + tid];
        const float* wr = w1 + (q * CRr + tid) * CN;
        const float* sb = s_buf + qb * CN;
        for (int cc = 0; cc < CN; ++cc)
            acc = fmaf(wr[cc], sb[cc] * (1.f / (float)LL), acc);
        tl[tid] = siluf(acc);
    }
    __syncthreads();
    if (tid == 0) {
        float acc = b2[q * CN + c];
        #pragma unroll
        for (int r = 0; r < CRr; ++r) acc = fmaf(w2[(q * CN + c) * CRr + r], tl[r], acc);
        attv = sigf(acc);
    }
    __syncthreads();
    const float av = attv;
    const size_t ybase = (size_t)(qb * CN + c) * LL;
    const int xb = (b * CN + c) * 9216 + h0 * 96 + w0;
    for (int t = tid; t < LL / 8; t += 256) {
        int e0 = t * 8;
        int gi = xb + (e0 / 48) * 96 + (e0 % 48);
        uint4 yv = *reinterpret_cast<const uint4*>(&y_in[ybase + e0]);
        float yf[8]; unpack8(yv, yf);
        float4 xa = *reinterpret_cast<const float4*>(&x[gi]);
        float4 xc = *reinterpret_cast<const float4*>(&x[gi + 4]);
        float4 o0 = {xa.x + yf[0]*av, xa.y + yf[1]*av, xa.z + yf[2]*av, xa.w + yf[3]*av};
        float4 o1 = {xc.x + yf[4]*av, xc.y + yf[5]*av, xc.z + yf[6]*av, xc.w + yf[7]*av};
        *reinterpret_cast<float4*>(&out[gi])     = o0;
        *reinterpret_cast<float4*>(&out[gi + 4]) = o1;
    }
}

// ============================================================================
extern "C" void kernel_launch(void* const* d_in, const int* in_sizes, int n_in,
                              void* d_out, int out_size, void* d_ws, size_t ws_size,
                              hipStream_t stream)
{
    (void)in_sizes; (void)n_in; (void)out_size; (void)ws_size;
    const float* x       = (const float*)d_in[0];
    const float* ln_g    = (const float*)d_in[1];
    const float* ln_b    = (const float*)d_in[2];
    const float* p1_w    = (const float*)d_in[3];
    const float* p1_b    = (const float*)d_in[4];
    const float* p2in_w  = (const float*)d_in[5];
    const float* p2in_b  = (const float*)d_in[6];
    const float* dw_w    = (const float*)d_in[7];
    const float* dw_b    = (const float*)d_in[8];
    const float* xproj_w = (const float*)d_in[9];
    const float* dtproj_w= (const float*)d_in[10];
    const float* dtproj_b= (const float*)d_in[11];
    const float* A_logs  = (const float*)d_in[12];
    const float* Ds      = (const float*)d_in[13];
    const float* ssln_g  = (const float*)d_in[14];
    const float* ssln_b  = (const float*)d_in[15];
    const float* p2n_g   = (const float*)d_in[16];
    const float* p2n_b   = (const float*)d_in[17];
    const float* ca_w1   = (const float*)d_in[18];
    const float* ca_b1   = (const float*)d_in[19];
    const float* ca_w2   = (const float*)d_in[20];
    const float* ca_b2   = (const float*)d_in[21];
    const int*  bidx     = (const int*)d_in[22];
    float* out = (float*)d_out;

    char* ws = (char*)d_ws;
    const size_t off_a    = 0;                                  // bf16, live K1->K5
    const size_t off_zt   = 28311552;                           // bf16, live K2->K4
    const size_t off_ztT  = 56623104;                           // bf16, live K2->K4
    const size_t off_xdbl = 84934656;                           // bf16, live K3->K4
    const size_t off_ys   = 110886912;                          // bf16, live K4->K4b
    const size_t off_z0   = off_ys;                             // bf16 alias (dead before ys)
    const size_t off_s    = off_zt;                             // bf16 alias: sum tensor (K4b->K5)
    const size_t off_y    = off_ztT;                            // bf16 alias: gated y (K5->K7)
    const size_t off_sb   = 224133120;                          // fp32 attention sums

    bf16*  a_buf   = (bf16*)(ws + off_a);
    bf16*  zt_buf  = (bf16*)(ws + off_zt);
    bf16*  ztT_buf = (bf16*)(ws + off_ztT);
    bf16*  xdbl_buf= (bf16*)(ws + off_xdbl);
    bf16*  ys_buf  = (bf16*)(ws + off_ys);
    bf16*  z0_buf  = (bf16*)(ws + off_z0);
    bf16*  s_sum   = (bf16*)(ws + off_s);
    bf16*  y_buf   = (bf16*)(ws + off_y);
    float* s_buf   = (float*)(ws + off_sb);

    (void)hipMemsetAsync(ws + off_sb, 0, 24576, stream);

    k_lnconv<<<dim3(24, 16, 4), 192, 0, stream>>>(
        x, ln_g, ln_b, p1_w, p1_b, p2in_w, p2in_b, a_buf, z0_buf);
    k_dwconv<<<dim3(96, 16, 4), 256, 0, stream>>>(
        z0_buf, dw_w, dw_b, bidx, zt_buf, ztT_buf);
    k_xdbl<<<dim3(12, 4, 64), 256, 0, stream>>>(
        zt_buf, ztT_buf, xproj_w, xdbl_buf);
    k_scan<<<dim3(512), 384, 0, stream>>>(
        zt_buf, ztT_buf, xdbl_buf, dtproj_w, dtproj_b, A_logs, Ds, ys_buf);
    k_sum<<<dim3(96, 16, 4), 256, 0, stream>>>(
        ys_buf, s_sum);
    k_combine<<<dim3(48, 16, 4), 256, 0, stream>>>(
        s_sum, a_buf, ssln_g, ssln_b, p2n_g, p2n_b, bidx, y_buf, s_buf);
    k_final<<<dim3(96, 16, 4), 256, 0, stream>>>(
        x, y_buf, s_buf, ca_w1, ca_b1, ca_w2, ca_b2, out);
}

// Round 6
// 729.321 us; speedup vs baseline: 1.0103x; 1.0103x over previous
//
#include <hip/hip_runtime.h>
#include <hip/hip_bf16.h>

// ---- problem constants ----
#define BQ 16      // batch
#define CN 96      // channels
#define HQ 48      // quadrant H = W
#define LL 2304    // HQ*HQ
#define NK 4       // scan directions
#define RR 6       // dt rank
#define NNS 8      // state size
#define DPJ 22     // R + 2N
#define CRr 12     // attention rank
#define LOG2E 1.4426950408889634f

using bf16 = __hip_bfloat16;

__device__ __forceinline__ float b2f(bf16 v) { return __bfloat162float(v); }
__device__ __forceinline__ bf16  f2b(float v){ return __float2bfloat16(v); }
__device__ __forceinline__ float bflo(unsigned u){ return __uint_as_float(u << 16); }
__device__ __forceinline__ float bfhi(unsigned u){ return __uint_as_float(u & 0xffff0000u); }
__device__ __forceinline__ float sigf(float x){ return 1.f / (1.f + __expf(-x)); }
__device__ __forceinline__ float siluf(float x){ return x / (1.f + __expf(-x)); }
__device__ __forceinline__ unsigned packbf(float a, float b){
    unsigned lo = (unsigned)__builtin_bit_cast(unsigned short, f2b(a));
    unsigned hi = (unsigned)__builtin_bit_cast(unsigned short, f2b(b));
    return lo | (hi << 16);
}
__device__ __forceinline__ unsigned rot16(unsigned u){ return (u >> 16) | (u << 16); }
__device__ __forceinline__ void unpack8(uint4 v, float* f){
    f[0]=bflo(v.x); f[1]=bfhi(v.x); f[2]=bflo(v.y); f[3]=bfhi(v.y);
    f[4]=bflo(v.z); f[5]=bfhi(v.z); f[6]=bflo(v.w); f[7]=bfhi(v.w);
}
__device__ __forceinline__ void unpack4(uint2 v, float* f){
    f[0]=bflo(v.x); f[1]=bfhi(v.x); f[2]=bflo(v.y); f[3]=bfhi(v.y);
}
__device__ __forceinline__ float fexp2(float x){
#if __has_builtin(__builtin_amdgcn_exp2f)
    return __builtin_amdgcn_exp2f(x);
#else
    return __expf(x * 0.6931471805599453f);
#endif
}
// quad_perm DPP xor within groups of 4 lanes (VALU pipe, no LDS)
__device__ __forceinline__ float qxor(float v, int ctrl_b1){
    int x;
    if (ctrl_b1) x = __builtin_amdgcn_mov_dpp(__float_as_int(v), 0xB1, 0xF, 0xF, true);
    else         x = __builtin_amdgcn_mov_dpp(__float_as_int(v), 0x4E, 0xF, 0xF, true);
    return __int_as_float(x);
}

// ============================================================================
// K1: channel LN + conv1x1 (a-branch with silu, z-branch raw -> bf16)
// grid (24, 16, 4) = (hh-pair, b, q), block 192
// R6: LN stats parallelized (192 threads x 48ch partials, 2-way combine)
// ============================================================================
__global__ __launch_bounds__(192) void k_lnconv(
    const float* __restrict__ x, const float* __restrict__ ln_g, const float* __restrict__ ln_b,
    const float* __restrict__ p1w, const float* __restrict__ p1b,
    const float* __restrict__ p2w, const float* __restrict__ p2b,
    bf16* __restrict__ a_out, bf16* __restrict__ z0_out)
{
    const int hh2 = blockIdx.x;           // 0..23 (covers 2 rows each)
    const int b = blockIdx.y, q = blockIdx.z;
    const int h0 = (q >> 1) * HQ, w0 = (q & 1) * HQ;
    const int tid = threadIdx.x;
    const int qb = q * BQ + b;

    __shared__ alignas(16) bf16 hn[CN * 96];    // [c][p], p = local pos 0..95 (2 rows x 48)
    __shared__ alignas(16) bf16 wl[CN * 200];   // [c][row 0..191, pad to 200]
    __shared__ float mu[96], rs[96];
    __shared__ float pmu[192], pv2[192];        // stat partials [half][96]

    // stage weights transposed: wl[c][d] = p1, wl[c][96+d] = p2in
    for (int t = tid; t < CN * CN; t += 192) {
        int d = t / CN, c = t % CN;
        wl[c * 200 + d]      = f2b(p1w[(q * CN + d) * CN + c]);
        wl[c * 200 + 96 + d] = f2b(p2w[(q * CN + d) * CN + c]);
    }
    // stage x tile: float4 loads, packed uint2 LDS writes
    for (int t = tid; t < CN * 24; t += 192) {
        int c = t / 24, v = t % 24;
        int row = v / 12, col = (v % 12) * 4;
        float4 xv = *reinterpret_cast<const float4*>(
            &x[((b * CN + c) * 96 + h0 + 2 * hh2 + row) * 96 + w0 + col]);
        uint2 pk; pk.x = packbf(xv.x, xv.y); pk.y = packbf(xv.z, xv.w);
        *reinterpret_cast<uint2*>(&hn[c * 96 + v * 4]) = pk;
    }
    __syncthreads();
    // LN stats per position: 192 threads = 96 pos x 2 halves of 48 ch each
    {
        int p = tid % 96, half = tid / 96;
        float s = 0.f, s2 = 0.f;
        for (int c = half * 48; c < half * 48 + 48; ++c) {
            float v = b2f(hn[c * 96 + p]); s += v; s2 += v * v;
        }
        pmu[half * 96 + p] = s; pv2[half * 96 + p] = s2;
    }
    __syncthreads();
    if (tid < 96) {
        float s = pmu[tid] + pmu[96 + tid];
        float s2 = pv2[tid] + pv2[96 + tid];
        float m = s * (1.f / 96.f);
        float var = s2 * (1.f / 96.f) - m * m;
        mu[tid] = m; rs[tid] = rsqrtf(var + 1e-6f);
    }
    __syncthreads();
    // normalize in place
    for (int t = tid; t < CN * 96; t += 192) {
        int c = t / 96, p = t % 96;
        float g = ln_g[q * CN + c], bb = ln_b[q * CN + c];
        hn[t] = f2b((b2f(hn[t]) - mu[p]) * rs[p] * g + bb);
    }
    __syncthreads();
    // matvec: thread -> 8 output rows x 12 positions
    const int rg = tid >> 3, pg = tid & 7;
    const int row0 = rg * 8, pp0 = pg * 12;
    float acc[8][12];
    #pragma unroll
    for (int i = 0; i < 8; ++i)
        #pragma unroll
        for (int j = 0; j < 12; ++j) acc[i][j] = 0.f;

    for (int c = 0; c < CN; ++c) {
        uint4 wv = *reinterpret_cast<const uint4*>(&wl[c * 200 + row0]);
        float w[8];
        w[0] = bflo(wv.x); w[1] = bfhi(wv.x);
        w[2] = bflo(wv.y); w[3] = bfhi(wv.y);
        w[4] = bflo(wv.z); w[5] = bfhi(wv.z);
        w[6] = bflo(wv.w); w[7] = bfhi(wv.w);
        uint2 ha = *reinterpret_cast<const uint2*>(&hn[c * 96 + pp0]);
        uint2 hb = *reinterpret_cast<const uint2*>(&hn[c * 96 + pp0 + 4]);
        uint2 hc = *reinterpret_cast<const uint2*>(&hn[c * 96 + pp0 + 8]);
        float hv[12];
        hv[0] = bflo(ha.x); hv[1] = bfhi(ha.x); hv[2]  = bflo(ha.y); hv[3]  = bfhi(ha.y);
        hv[4] = bflo(hb.x); hv[5] = bfhi(hb.x); hv[6]  = bflo(hb.y); hv[7]  = bfhi(hb.y);
        hv[8] = bflo(hc.x); hv[9] = bfhi(hc.x); hv[10] = bflo(hc.y); hv[11] = bfhi(hc.y);
        #pragma unroll
        for (int i = 0; i < 8; ++i)
            #pragma unroll
            for (int j = 0; j < 12; ++j)
                acc[i][j] = fmaf(w[i], hv[j], acc[i][j]);
    }
    // epilogue: packed bf16 stores (12 contiguous elems per row)
    const int lbase = (2 * hh2 + pp0 / 48) * 48 + (pp0 % 48);
    #pragma unroll
    for (int i = 0; i < 8; ++i) {
        int row = row0 + i;
        bool isA = row < 96;
        int d = isA ? row : row - 96;
        float bias = isA ? p1b[q * CN + d] : p2b[q * CN + d];
        int oidx = (qb * CN + d) * LL + lbase;
        float v[12];
        #pragma unroll
        for (int j = 0; j < 12; ++j) v[j] = acc[i][j] + bias;
        if (isA) {
            #pragma unroll
            for (int j = 0; j < 12; ++j) v[j] = siluf(v[j]);
        }
        uint2 w0p, w1p, w2p;
        w0p.x = packbf(v[0], v[1]);  w0p.y = packbf(v[2], v[3]);
        w1p.x = packbf(v[4], v[5]);  w1p.y = packbf(v[6], v[7]);
        w2p.x = packbf(v[8], v[9]);  w2p.y = packbf(v[10], v[11]);
        bf16* dst = isA ? a_out : z0_out;
        *reinterpret_cast<uint2*>(&dst[oidx])     = w0p;
        *reinterpret_cast<uint2*>(&dst[oidx + 4]) = w1p;
        *reinterpret_cast<uint2*>(&dst[oidx + 8]) = w2p;
    }
}

// ============================================================================
// K2: depthwise 3x3 SAME + bias + silu + block_idx transform (bf16 in/out)
// grid (96, 16, 4) = (c, b, q), block 256
// R6: zero-padded zin[50][50] -> branchless 9-tap interior (no per-tap cmp)
// ============================================================================
__global__ __launch_bounds__(256) void k_dwconv(
    const bf16* __restrict__ z0, const float* __restrict__ dww, const float* __restrict__ dwb,
    const int* __restrict__ bidx, bf16* __restrict__ zt, bf16* __restrict__ ztT)
{
    const int c = blockIdx.x, b = blockIdx.y, q = blockIdx.z;
    const int tid = threadIdx.x;
    const int base = ((q * BQ + b) * CN + c) * LL;
    __shared__ float zin[50 * 50];  // 1-elem zero border
    __shared__ float zo[48 * 49];   // padded rows: conflict-free transposed reads
    // zero the border (196 cells, disjoint from interior staging)
    if (tid < 196) {
        int idx;
        if (tid < 50)       idx = tid;                    // row 0
        else if (tid < 100) idx = 49 * 50 + (tid - 50);   // row 49
        else if (tid < 148) idx = (tid - 99) * 50;        // col 0, rows 1..48
        else                idx = (tid - 147) * 50 + 49;  // col 49, rows 1..48
        zin[idx] = 0.f;
    }
    for (int t = tid; t < 288; t += 256) {
        uint4 v = *reinterpret_cast<const uint4*>(&z0[base + t * 8]);
        float f[8]; unpack8(v, f);
        int e0 = t * 8, row = e0 / 48, col = e0 % 48;
        float* dst = &zin[(row + 1) * 50 + col + 1];
        #pragma unroll
        for (int i = 0; i < 8; ++i) dst[i] = f[i];
    }
    float wk[9];
    #pragma unroll
    for (int i = 0; i < 9; ++i) wk[i] = dww[(q * CN + c) * 9 + i];
    const float bias = dwb[q * CN + c];
    __syncthreads();
    for (int t = tid; t < LL; t += 256) {
        int hh = t / 48, ww = t % 48;
        const float* z0r = &zin[hh * 50 + ww];        // top-left tap
        float s = bias;
        s = fmaf(wk[0], z0r[0],        s);
        s = fmaf(wk[1], z0r[1],        s);
        s = fmaf(wk[2], z0r[2],        s);
        s = fmaf(wk[3], z0r[50],       s);
        s = fmaf(wk[4], z0r[51],       s);
        s = fmaf(wk[5], z0r[52],       s);
        s = fmaf(wk[6], z0r[100],      s);
        s = fmaf(wk[7], z0r[101],      s);
        s = fmaf(wk[8], z0r[102],      s);
        zo[hh * 49 + ww] = siluf(s);
    }
    __syncthreads();
    const bool even = ((bidx[0] & 1) == 0);
    for (int t = tid; t < LL; t += 256) {
        int i = t / 48, j = t % 48;
        float vz, vzT;
        if (even) { vz = zo[j * 49 + i];               vzT = zo[i * 49 + j]; }
        else      { vz = zo[(47 - i) * 49 + (47 - j)]; vzT = zo[(47 - j) * 49 + (47 - i)]; }
        zt[base + t]  = f2b(vz);
        ztT[base + t] = f2b(vzT);
    }
}

// ============================================================================
// K3: x_dbl = xproj_w @ u_k  (direction mapping + reversal folded in)
// grid (12, 4, 64) = (l-tile, k, q*16+b), block 256
// compute retiled: 2 d-rows x 12 l = 176 tiles, single pass
// ============================================================================
__global__ __launch_bounds__(256) void k_xdbl(
    const bf16* __restrict__ zt, const bf16* __restrict__ ztT,
    const float* __restrict__ xprojw, bf16* __restrict__ xdbl)
{
    const int lt = blockIdx.x, k = blockIdx.y, qb = blockIdx.z;
    const int tid = threadIdx.x;
    const int l0 = lt * 192;
    const int q = qb >> 4;
    __shared__ alignas(16) bf16 ul[CN * 200];
    __shared__ alignas(16) bf16 wl[CN * 24];    // transposed [c][d], pad 22->24
    const bf16* __restrict__ src = (k & 1) ? ztT : zt;
    const bool rev = (k >= 2);
    // vectorized staging: 96c x 24 vectors of 8 bf16
    for (int t = tid; t < CN * 24; t += 256) {
        int cc = t / 24, j0 = (t % 24) * 8;
        uint4 v;
        if (!rev) {
            v = *reinterpret_cast<const uint4*>(&src[(size_t)(qb * CN + cc) * LL + l0 + j0]);
        } else {
            v = *reinterpret_cast<const uint4*>(&src[(size_t)(qb * CN + cc) * LL + (LL - (l0 + j0) - 8)]);
            uint4 r; r.x = rot16(v.w); r.y = rot16(v.z); r.z = rot16(v.y); r.w = rot16(v.x);
            v = r;
        }
        *reinterpret_cast<uint4*>(&ul[cc * 200 + j0]) = v;
    }
    for (int t = tid; t < DPJ * CN; t += 256) {
        int d = t / CN, c = t % CN;
        wl[c * 24 + d] = f2b(xprojw[(q * NK + k) * DPJ * CN + t]);
    }
    __syncthreads();
    // tiles: 2 d-rows x 12 l : 11 * 16 = 176 tiles, single pass
    if (tid < 176) {
        const int dp = tid / 16, lg = tid % 16;
        const int d0 = dp * 2, llp = lg * 12;
        float acc0[12], acc1[12];
        #pragma unroll
        for (int j = 0; j < 12; ++j) { acc0[j] = 0.f; acc1[j] = 0.f; }
        for (int c = 0; c < CN; ++c) {
            unsigned wv = *reinterpret_cast<const unsigned*>(&wl[c * 24 + d0]);
            float w0 = bflo(wv), w1 = bfhi(wv);
            uint2 ua = *reinterpret_cast<const uint2*>(&ul[c * 200 + llp]);
            uint2 ub = *reinterpret_cast<const uint2*>(&ul[c * 200 + llp + 4]);
            uint2 uc = *reinterpret_cast<const uint2*>(&ul[c * 200 + llp + 8]);
            float uf[12];
            unpack4(ua, uf); unpack4(ub, uf + 4); unpack4(uc, uf + 8);
            #pragma unroll
            for (int j = 0; j < 12; ++j) {
                acc0[j] = fmaf(w0, uf[j], acc0[j]);
                acc1[j] = fmaf(w1, uf[j], acc1[j]);
            }
        }
        int ob = (qb * NK + k) * DPJ * LL + l0 + llp;
        uint2 o0a, o0b, o0c, o1a, o1b, o1c;
        o0a.x = packbf(acc0[0], acc0[1]);  o0a.y = packbf(acc0[2], acc0[3]);
        o0b.x = packbf(acc0[4], acc0[5]);  o0b.y = packbf(acc0[6], acc0[7]);
        o0c.x = packbf(acc0[8], acc0[9]);  o0c.y = packbf(acc0[10], acc0[11]);
        o1a.x = packbf(acc1[0], acc1[1]);  o1a.y = packbf(acc1[2], acc1[3]);
        o1b.x = packbf(acc1[4], acc1[5]);  o1b.y = packbf(acc1[6], acc1[7]);
        o1c.x = packbf(acc1[8], acc1[9]);  o1c.y = packbf(acc1[10], acc1[11]);
        *reinterpret_cast<uint2*>(&xdbl[ob + d0 * LL])           = o0a;
        *reinterpret_cast<uint2*>(&xdbl[ob + d0 * LL + 4])       = o0b;
        *reinterpret_cast<uint2*>(&xdbl[ob + d0 * LL + 8])       = o0c;
        *reinterpret_cast<uint2*>(&xdbl[ob + (d0 + 1) * LL])     = o1a;
        *reinterpret_cast<uint2*>(&xdbl[ob + (d0 + 1) * LL + 4]) = o1b;
        *reinterpret_cast<uint2*>(&xdbl[ob + (d0 + 1) * LL + 8]) = o1c;
    }
}

// ============================================================================
// K4: fused delta(softplus) + selective scan + Ds*u term
// grid (512), block 384 producer/consumer — UNCHANGED from round 5
// (measured 261.5 us; attribution anchor for this round's edits)
// ============================================================================

// raw barrier: drain LDS (cross-wave visibility of ds_writes) but NOT vmcnt
#define SCAN_BARRIER() asm volatile("s_waitcnt lgkmcnt(0)\n\ts_barrier" ::: "memory")

// word IDX (0..23) of a 6-uint4 register array holding 48 bf16
#define UWORD(NUA, IDX) (((IDX) & 3) == 0 ? NUA[(IDX) >> 2].x : \
                         ((IDX) & 3) == 1 ? NUA[(IDX) >> 2].y : \
                         ((IDX) & 3) == 2 ? NUA[(IDX) >> 2].z : NUA[(IDX) >> 2].w)

#define ROT3(v) (v) = ((v) == 2) ? 0 : ((v) + 1)

__global__ __launch_bounds__(384) void k_scan(
    const bf16* __restrict__ zt, const bf16* __restrict__ ztT,
    const bf16* __restrict__ xdbl,
    const float* __restrict__ dtw_g, const float* __restrict__ dtb_g,
    const float* __restrict__ Alog_g, const float* __restrict__ Ds_g,
    bf16* __restrict__ ys)
{
    const int bid = blockIdx.x;
    const int ch2 = bid & 1, k = (bid >> 1) & 3, qb = bid >> 3, q = qb >> 4;
    const int qk = q * NK + k;
    const int tid = threadIdx.x;
    const bool isScan = (tid < 192);
    const int lt = isScan ? tid : (tid - 192);   // role-local 0..191
    const int ca = lt >> 2, p = lt & 3;
    const int c = ch2 * 48 + ca;          // global channel

    __shared__ float dd3[3][48 * 52];
    __shared__ float xr3[3][6 * 52];          // dts rows
    __shared__ float bcv3[3][48 * 16];        // [j][p*4 + {B0,B1,C0,C1}]

    const bf16* __restrict__ src = (k & 1) ? ztT : zt;
    const bool rev = (k >= 2);
    const int ja = p * 12;

    // ---- producer-role parameters ----
    float wdt[6] = {0.f, 0.f, 0.f, 0.f, 0.f, 0.f};
    float dtbc = 0.f;
    if (!isScan) {
        const float* wp = dtw_g + (size_t)qk * CN * RR + c * RR;
        float2 wa = *reinterpret_cast<const float2*>(wp);
        float2 wb = *reinterpret_cast<const float2*>(wp + 2);
        float2 wc = *reinterpret_cast<const float2*>(wp + 4);
        wdt[0] = wa.x; wdt[1] = wa.y; wdt[2] = wb.x; wdt[3] = wb.y; wdt[4] = wc.x; wdt[5] = wc.y;
        dtbc = dtb_g[qk * CN + c];
    }
    // xdbl staging: producer threads with lt<132 stage one uint4 from row vr
    const bool xload = (!isScan) && (lt < 132);
    const int vr = lt / 6, jx = (lt % 6) * 8;
    const bf16* gx = xdbl + (size_t)(qb * NK + k) * (DPJ * LL) + (size_t)vr * LL + jx;
    int bccol = 0;
    if (vr >= 6) {
        int v = vr - 6;           // 0..15: 0-7 B, 8-15 C
        int n = v & 7;
        bccol = (n >> 1) * 4 + ((v >= 8) ? 2 : 0) + (n & 1);
    }

    // ---- scan-role parameters ----
    float A0L = 0.f, A1L = 0.f, Dc = 0.f;
    if (isScan) {
        A0L = -__expf(Alog_g[((size_t)qk * CN + c) * NNS + 2 * p])     * LOG2E;
        A1L = -__expf(Alog_g[((size_t)qk * CN + c) * NNS + 2 * p + 1]) * LOG2E;
        Dc = Ds_g[qk * CN + c];
    }
    float h0 = 0.f, h1 = 0.f;
    const bf16* gu = src + (size_t)(qb * CN + c) * LL + (rev ? (LL - 48) : 0);
    const int ustep = rev ? -48 : 48;
    bf16* yp = ys + (size_t)(qb * NK + k) * (CN * LL) + (size_t)c * LL;  // p==0 stores

    #define COMMIT_BLOCK(PXV, XRB, BCB) do {                                          \
        if (xload) {                                                                  \
            float g[8]; unpack8(PXV, g);                                              \
            if (vr < 6) {                                                             \
                *reinterpret_cast<float4*>(&(XRB)[vr * 52 + jx])                      \
                    = make_float4(g[0], g[1], g[2], g[3]);                            \
                *reinterpret_cast<float4*>(&(XRB)[vr * 52 + jx + 4])                  \
                    = make_float4(g[4], g[5], g[6], g[7]);                            \
            } else {                                                                  \
                _Pragma("unroll")                                                     \
                for (int i = 0; i < 8; ++i) (BCB)[(jx + i) * 16 + bccol] = g[i];      \
            }                                                                         \
        }                                                                             \
    } while (0)

    #define DELTA_BLOCK(XRB, DDB) do {                                                \
        float acc[12];                                                                \
        _Pragma("unroll")                                                             \
        for (int i = 0; i < 12; ++i) acc[i] = dtbc;                                   \
        _Pragma("unroll")                                                             \
        for (int r = 0; r < 6; ++r) {                                                 \
            float4 d0 = *reinterpret_cast<const float4*>(&(XRB)[r * 52 + ja]);        \
            float4 d1 = *reinterpret_cast<const float4*>(&(XRB)[r * 52 + ja + 4]);    \
            float4 d2 = *reinterpret_cast<const float4*>(&(XRB)[r * 52 + ja + 8]);    \
            float wr_ = wdt[r];                                                       \
            acc[0] = fmaf(wr_, d0.x, acc[0]);  acc[1] = fmaf(wr_, d0.y, acc[1]);      \
            acc[2] = fmaf(wr_, d0.z, acc[2]);  acc[3] = fmaf(wr_, d0.w, acc[3]);      \
            acc[4] = fmaf(wr_, d1.x, acc[4]);  acc[5] = fmaf(wr_, d1.y, acc[5]);      \
            acc[6] = fmaf(wr_, d1.z, acc[6]);  acc[7] = fmaf(wr_, d1.w, acc[7]);      \
            acc[8] = fmaf(wr_, d2.x, acc[8]);  acc[9] = fmaf(wr_, d2.y, acc[9]);      \
            acc[10] = fmaf(wr_, d2.z, acc[10]); acc[11] = fmaf(wr_, d2.w, acc[11]);   \
        }                                                                             \
        _Pragma("unroll")                                                             \
        for (int i = 0; i < 12; ++i) {                                                \
            float a = acc[i];                                                         \
            acc[i] = (a > 15.f) ? a : __logf(1.f + __expf(a));                        \
        }                                                                             \
        float4* dp = reinterpret_cast<float4*>(&(DDB)[ca * 52 + ja]);                 \
        dp[0] = make_float4(acc[0], acc[1], acc[2], acc[3]);                          \
        dp[1] = make_float4(acc[4], acc[5], acc[6], acc[7]);                          \
        dp[2] = make_float4(acc[8], acc[9], acc[10], acc[11]);                        \
    } while (0)

    // ---- prologue ----
    uint4 u_a[6], u_b[6];
    uint4 px_a = {0,0,0,0}, px_b = {0,0,0,0}, px1 = {0,0,0,0};
    if (isScan) {
        #pragma unroll
        for (int i = 0; i < 6; ++i) u_a[i] = *reinterpret_cast<const uint4*>(gu + i * 8);  // chunk 0
        gu += ustep;
        #pragma unroll
        for (int i = 0; i < 6; ++i) u_b[i] = *reinterpret_cast<const uint4*>(gu + i * 8);  // chunk 1
        gu += ustep;                                           // -> chunk 2
    } else {
        uint4 px0 = {0,0,0,0};
        if (xload) {
            px0  = *reinterpret_cast<const uint4*>(gx);        // chunk 0
            px1  = *reinterpret_cast<const uint4*>(gx + 48);   // chunk 1
            px_a = *reinterpret_cast<const uint4*>(gx + 96);   // chunk 2
            px_b = *reinterpret_cast<const uint4*>(gx + 144);  // chunk 3
            gx += 192;                                         // -> chunk 4
        }
        COMMIT_BLOCK(px0, xr3[0], bcv3[0]);
    }
    SCAN_BARRIER();
    if (!isScan) {
        DELTA_BLOCK(xr3[0], dd3[0]);
        COMMIT_BLOCK(px1, xr3[1], bcv3[1]);
    }
    SCAN_BARRIER();

    // buffer cursors
    int s_cur = 0;              // scan:  buf of chunk ch
    int d_idx = 1, c_idx = 2;   // prod:  delta buf (ch+1), commit buf (ch+2)

    #define PROD_BODY(CH, PX) do {                                                    \
        const int chp_ = (CH);                                                        \
        if (chp_ + 2 < 48) COMMIT_BLOCK(PX, xr3[c_idx], bcv3[c_idx]);                 \
        if (chp_ + 4 < 48 && xload) { PX = *reinterpret_cast<const uint4*>(gx); gx += 48; } \
        if (chp_ + 1 < 48) DELTA_BLOCK(xr3[d_idx], dd3[d_idx]);                       \
        ROT3(d_idx); ROT3(c_idx);                                                     \
    } while (0)

    #define SCAN_CHUNK(CH, UC) do {                                                   \
        const int ch_ = (CH);                                                         \
        uint4 nu[6];                                                                  \
        if (!rev) {                                                                   \
            nu[0] = UC[0]; nu[1] = UC[1]; nu[2] = UC[2];                              \
            nu[3] = UC[3]; nu[4] = UC[4]; nu[5] = UC[5];                              \
        } else {                                                                      \
            _Pragma("unroll")                                                         \
            for (int qq = 0; qq < 6; ++qq) {                                          \
                nu[qq].x = rot16(UC[5 - qq].w); nu[qq].y = rot16(UC[5 - qq].z);       \
                nu[qq].z = rot16(UC[5 - qq].y); nu[qq].w = rot16(UC[5 - qq].x);       \
            }                                                                         \
        }                                                                             \
        {                                                                             \
            const int l0 = ch_ * 48;                                                  \
            const float* ddc = &dd3[s_cur][ca * 52];                                  \
            const float* bcc = &bcv3[s_cur][p * 4];                                   \
            _Pragma("unroll")                                                         \
            for (int gg = 0; gg < 6; ++gg) {                                          \
                unsigned pk[4];                                                       \
                _Pragma("unroll")                                                     \
                for (int half = 0; half < 2; ++half) {                                \
                    const int j0 = gg * 8 + half * 4;                                 \
                    float4 d4 = *reinterpret_cast<const float4*>(ddc + j0);           \
                    const float* df = reinterpret_cast<const float*>(&d4);            \
                    _Pragma("unroll")                                                 \
                    for (int s = 0; s < 4; ++s) {                                     \
                        const int j = j0 + s;                                         \
                        const unsigned uwv = UWORD(nu, j >> 1);                       \
                        float u = (j & 1) ? bfhi(uwv) : bflo(uwv);                    \
                        float d = df[s];                                              \
                        float4 bq = *reinterpret_cast<const float4*>(bcc + j * 16);   \
                        float du = d * u;                                             \
                        float dA0 = fexp2(d * A0L);                                   \
                        float dA1 = fexp2(d * A1L);                                   \
                        h0 = fmaf(dA0, h0, du * bq.x);                                \
                        h1 = fmaf(dA1, h1, du * bq.y);                                \
                        float y = fmaf(h0, bq.z, h1 * bq.w);                          \
                        y += qxor(y, 1); y += qxor(y, 0);                             \
                        y = fmaf(Dc, u, y);                                           \
                        unsigned hb = (unsigned)__builtin_bit_cast(unsigned short, f2b(y)); \
                        const int sl = half * 4 + s;                                  \
                        if (sl & 1) pk[sl >> 1] |= hb << 16; else pk[sl >> 1] = hb;   \
                    }                                                                 \
                }                                                                     \
                if (p == 0) {                                                         \
                    uint4 wv4; wv4.x = pk[0]; wv4.y = pk[1]; wv4.z = pk[2]; wv4.w = pk[3]; \
                    *reinterpret_cast<uint4*>(yp + l0 + gg * 8) = wv4;                \
                }                                                                     \
            }                                                                         \
        }                                                                             \
        if (ch_ + 2 < 48) {                                                           \
            _Pragma("unroll")                                                         \
            for (int i = 0; i < 6; ++i) UC[i] = *reinterpret_cast<const uint4*>(gu + i * 8); \
            gu += ustep;                                                              \
        }                                                                             \
        ROT3(s_cur);                                                                  \
    } while (0)

    for (int t = 0; t < 24; ++t) {
        if (isScan) SCAN_CHUNK(2 * t, u_a);
        else        PROD_BODY(2 * t, px_a);
        SCAN_BARRIER();
        if (isScan) SCAN_CHUNK(2 * t + 1, u_b);
        else        PROD_BODY(2 * t + 1, px_b);
        SCAN_BARRIER();
    }

    #undef SCAN_CHUNK
    #undef PROD_BODY
    #undef DELTA_BLOCK
    #undef COMMIT_BLOCK
}

// ============================================================================
// K4b: k_sum — combine 4 directions into one tensor at combine-index m
// grid (96, 16, 4) = (c, b, q), block 256
// ============================================================================
__global__ __launch_bounds__(256) void k_sum(
    const bf16* __restrict__ ys, bf16* __restrict__ s_out)
{
    const int c = blockIdx.x, b = blockIdx.y, q = blockIdx.z;
    const int qb = q * BQ + b;
    const int tid = threadIdx.x;
    __shared__ float t0[48 * 49];
    __shared__ float t2[48 * 49];
    const size_t base0 = ((size_t)(qb * NK + 0) * CN + c) * LL;
    const size_t base1 = ((size_t)(qb * NK + 1) * CN + c) * LL;
    const size_t base2 = ((size_t)(qb * NK + 2) * CN + c) * LL;
    const size_t base3 = ((size_t)(qb * NK + 3) * CN + c) * LL;
    for (int idx = tid; idx < 288; idx += 256) {
        int e0 = idx * 8, h = e0 / 48, w = e0 % 48;
        float f[8];
        unpack8(*reinterpret_cast<const uint4*>(&ys[base0 + e0]), f);
        #pragma unroll
        for (int i = 0; i < 8; ++i) t0[h * 49 + w + i] = f[i];
        unpack8(*reinterpret_cast<const uint4*>(&ys[base2 + e0]), f);
        #pragma unroll
        for (int i = 0; i < 8; ++i) t2[h * 49 + w + i] = f[i];
    }
    __syncthreads();
    const size_t cbase = ((size_t)qb * CN + c) * LL;
    for (int idx = tid; idx < 288; idx += 256) {
        int m0 = idx * 8, ww = m0 / 48, hh = m0 % 48;
        float f1[8], f3[8];
        unpack8(*reinterpret_cast<const uint4*>(&ys[base1 + m0]), f1);
        unpack8(*reinterpret_cast<const uint4*>(&ys[base3 + (LL - 8 - m0)]), f3);
        float o[8];
        #pragma unroll
        for (int i = 0; i < 8; ++i) {
            float v0 = t0[(hh + i) * 49 + ww];
            float v2 = t2[(47 - hh - i) * 49 + (47 - ww)];
            o[i] = v0 + f1[i] + v2 + f3[7 - i];
        }
        uint4 w;
        w.x = packbf(o[0], o[1]); w.y = packbf(o[2], o[3]);
        w.z = packbf(o[4], o[5]); w.w = packbf(o[6], o[7]);
        *reinterpret_cast<uint4*>(&s_out[cbase + m0]) = w;
    }
}

// ============================================================================
// K5: combine: LN(ssln) + LN(p2n) + y=a*z + attention partial sums
// grid (48, 16, 4) = (ww, b, q), block 256
// R6: both LN stat phases parallelized (192 threads x 24ch, 4-way combine)
// ============================================================================
__global__ __launch_bounds__(256) void k_combine(
    const bf16* __restrict__ s_in, const bf16* __restrict__ a_in,
    const float* __restrict__ ssg, const float* __restrict__ ssb,
    const float* __restrict__ png, const float* __restrict__ pnb,
    const int* __restrict__ bidx,
    bf16* __restrict__ y_out, float* __restrict__ s_buf)
{
    const int ww = blockIdx.x, b = blockIdx.y, q = blockIdx.z;
    const int qb = q * BQ + b;
    const int tid = threadIdx.x;
    __shared__ float o[CN * 48];
    __shared__ float mu[48], rs[48];
    __shared__ float pp[192], pp2[192];
    for (int v = tid; v < 576; v += 256) {
        int e0 = v * 8, cc = e0 / 48, hh = e0 % 48;
        float f[8];
        unpack8(*reinterpret_cast<const uint4*>(&s_in[((size_t)qb * CN + cc) * LL + ww * 48 + hh]), f);
        #pragma unroll
        for (int i = 0; i < 8; ++i) o[cc * 48 + hh + i] = f[i];
    }
    __syncthreads();
    // stats phase 1: 192 threads = 48 hh x 4 parts of 24 ch
    if (tid < 192) {
        int hh = tid % 48, part = tid / 48;
        float s = 0.f, s2 = 0.f;
        int c0 = part * 24;
        for (int cc = c0; cc < c0 + 24; ++cc) { float v = o[cc * 48 + hh]; s += v; s2 += v * v; }
        pp[tid] = s; pp2[tid] = s2;
    }
    __syncthreads();
    if (tid < 48) {
        float s = pp[tid] + pp[tid + 48] + pp[tid + 96] + pp[tid + 144];
        float s2 = pp2[tid] + pp2[tid + 48] + pp2[tid + 96] + pp2[tid + 144];
        float m = s * (1.f / 96.f), var = s2 * (1.f / 96.f) - m * m;
        mu[tid] = m; rs[tid] = rsqrtf(var + 1e-6f);
    }
    __syncthreads();
    for (int t = tid; t < CN * 48; t += 256) {
        int cc = t / 48, hh = t % 48;
        o[t] = (o[t] - mu[hh]) * rs[hh] * ssg[q * CN + cc] + ssb[q * CN + cc];
    }
    __syncthreads();
    // stats phase 2
    if (tid < 192) {
        int hh = tid % 48, part = tid / 48;
        float s = 0.f, s2 = 0.f;
        int c0 = part * 24;
        for (int cc = c0; cc < c0 + 24; ++cc) { float v = o[cc * 48 + hh]; s += v; s2 += v * v; }
        pp[tid] = s; pp2[tid] = s2;
    }
    __syncthreads();
    if (tid < 48) {
        float s = pp[tid] + pp[tid + 48] + pp[tid + 96] + pp[tid + 144];
        float s2 = pp2[tid] + pp2[tid + 48] + pp2[tid + 96] + pp2[tid + 144];
        float m = s * (1.f / 96.f), var = s2 * (1.f / 96.f) - m * m;
        mu[tid] = m; rs[tid] = rsqrtf(var + 1e-6f);
    }
    __syncthreads();
    const bool even = ((bidx[0] & 1) == 0);
    if (even) {
        for (int v = tid; v < 576; v += 256) {
            int e0 = v * 8, cc = e0 / 48, hh = e0 % 48;
            size_t oidx = ((size_t)qb * CN + cc) * LL + ww * 48 + hh;
            float af[8];
            unpack8(*reinterpret_cast<const uint4*>(&a_in[oidx]), af);
            float yv[8];
            #pragma unroll
            for (int i = 0; i < 8; ++i) {
                float z2 = (o[cc * 48 + hh + i] - mu[hh + i]) * rs[hh + i] * png[q * CN + cc] + pnb[q * CN + cc];
                yv[i] = af[i] * z2;
                o[cc * 48 + hh + i] = yv[i];
            }
            uint4 w;
            w.x = packbf(yv[0], yv[1]); w.y = packbf(yv[2], yv[3]);
            w.z = packbf(yv[4], yv[5]); w.w = packbf(yv[6], yv[7]);
            *reinterpret_cast<uint4*>(&y_out[oidx]) = w;
        }
    } else {
        for (int t = tid; t < CN * 48; t += 256) {
            int cc = t / 48, hh = t % 48;
            float z2 = (o[t] - mu[hh]) * rs[hh] * png[q * CN + cc] + pnb[q * CN + cc];
            size_t oidx = ((size_t)qb * CN + cc) * LL + (47 - hh) * 48 + (47 - ww);
            float yv = b2f(a_in[oidx]) * z2;
            y_out[oidx] = f2b(yv);
            o[t] = yv;
        }
    }
    __syncthreads();
    if (tid < CN) {
        float s = 0.f;
        for (int j = 0; j < 48; ++j) s += o[tid * 48 + j];
        atomicAdd(&s_buf[qb * CN + tid], s);
    }
}

// ============================================================================
// K7: out = x + y * att  with channel attention computed in-block
// grid (96, 16, 4) = (c, b, q), block 256
// R6: first CA matvec parallelized (192 threads = 12 r x 16 parts of 6 ch)
// ============================================================================
__global__ __launch_bounds__(256) void k_final(
    const float* __restrict__ x, const bf16* __restrict__ y_in,
    const float* __restrict__ s_buf,
    const float* __restrict__ w1, const float* __restrict__ b1,
    const float* __restrict__ w2, const float* __restrict__ b2,
    float* __restrict__ out)
{
    const int c = blockIdx.x, b = blockIdx.y, q = blockIdx.z;
    const int h0 = (q >> 1) * HQ, w0 = (q & 1) * HQ;
    const int qb = q * BQ + b;
    const int tid = threadIdx.x;
    __shared__ float tl[CRr];
    __shared__ float tpart[16 * CRr];
    __shared__ float attv;
    if (tid < 192) {
        int r = tid % CRr, part = tid / CRr;   // 16 parts x 6 channels
        float acc = 0.f;
        const float* wr = w1 + (q * CRr + r) * CN;
        const float* sb = s_buf + qb * CN;
        int c0 = part * 6;
        for (int cc = c0; cc < c0 + 6; ++cc)
            acc = fmaf(wr[cc], sb[cc] * (1.f / (float)LL), acc);
        tpart[part * CRr + r] = acc;
    }
    __syncthreads();
    if (tid < CRr) {
        float acc = b1[q * CRr + tid];
        #pragma unroll
        for (int pt = 0; pt < 16; ++pt) acc += tpart[pt * CRr + tid];
        tl[tid] = siluf(acc);
    }
    __syncthreads();
    if (tid == 0) {
        float acc = b2[q * CN + c];
        #pragma unroll
        for (int r = 0; r < CRr; ++r) acc = fmaf(w2[(q * CN + c) * CRr + r], tl[r], acc);
        attv = sigf(acc);
    }
    __syncthreads();
    const float av = attv;
    const size_t ybase = (size_t)(qb * CN + c) * LL;
    const int xb = (b * CN + c) * 9216 + h0 * 96 + w0;
    for (int t = tid; t < LL / 8; t += 256) {
        int e0 = t * 8;
        int gi = xb + (e0 / 48) * 96 + (e0 % 48);
        uint4 yv = *reinterpret_cast<const uint4*>(&y_in[ybase + e0]);
        float yf[8]; unpack8(yv, yf);
        float4 xa = *reinterpret_cast<const float4*>(&x[gi]);
        float4 xc = *reinterpret_cast<const float4*>(&x[gi + 4]);
        float4 o0 = {xa.x + yf[0]*av, xa.y + yf[1]*av, xa.z + yf[2]*av, xa.w + yf[3]*av};
        float4 o1 = {xc.x + yf[4]*av, xc.y + yf[5]*av, xc.z + yf[6]*av, xc.w + yf[7]*av};
        *reinterpret_cast<float4*>(&out[gi])     = o0;
        *reinterpret_cast<float4*>(&out[gi + 4]) = o1;
    }
}

// ============================================================================
extern "C" void kernel_launch(void* const* d_in, const int* in_sizes, int n_in,
                              void* d_out, int out_size, void* d_ws, size_t ws_size,
                              hipStream_t stream)
{
    (void)in_sizes; (void)n_in; (void)out_size; (void)ws_size;
    const float* x       = (const float*)d_in[0];
    const float* ln_g    = (const float*)d_in[1];
    const float* ln_b    = (const float*)d_in[2];
    const float* p1_w    = (const float*)d_in[3];
    const float* p1_b    = (const float*)d_in[4];
    const float* p2in_w  = (const float*)d_in[5];
    const float* p2in_b  = (const float*)d_in[6];
    const float* dw_w    = (const float*)d_in[7];
    const float* dw_b    = (const float*)d_in[8];
    const float* xproj_w = (const float*)d_in[9];
    const float* dtproj_w= (const float*)d_in[10];
    const float* dtproj_b= (const float*)d_in[11];
    const float* A_logs  = (const float*)d_in[12];
    const float* Ds      = (const float*)d_in[13];
    const float* ssln_g  = (const float*)d_in[14];
    const float* ssln_b  = (const float*)d_in[15];
    const float* p2n_g   = (const float*)d_in[16];
    const float* p2n_b   = (const float*)d_in[17];
    const float* ca_w1   = (const float*)d_in[18];
    const float* ca_b1   = (const float*)d_in[19];
    const float* ca_w2   = (const float*)d_in[20];
    const float* ca_b2   = (const float*)d_in[21];
    const int*  bidx     = (const int*)d_in[22];
    float* out = (float*)d_out;

    char* ws = (char*)d_ws;
    const size_t off_a    = 0;                                  // bf16, live K1->K5
    const size_t off_zt   = 28311552;                           // bf16, live K2->K4
    const size_t off_ztT  = 56623104;                           // bf16, live K2->K4
    const size_t off_xdbl = 84934656;                           // bf16, live K3->K4
    const size_t off_ys   = 110886912;                          // bf16, live K4->K4b
    const size_t off_z0   = off_ys;                             // bf16 alias (dead before ys)
    const size_t off_s    = off_zt;                             // bf16 alias: sum tensor (K4b->K5)
    const size_t off_y    = off_ztT;                            // bf16 alias: gated y (K5->K7)
    const size_t off_sb   = 224133120;                          // fp32 attention sums

    bf16*  a_buf   = (bf16*)(ws + off_a);
    bf16*  zt_buf  = (bf16*)(ws + off_zt);
    bf16*  ztT_buf = (bf16*)(ws + off_ztT);
    bf16*  xdbl_buf= (bf16*)(ws + off_xdbl);
    bf16*  ys_buf  = (bf16*)(ws + off_ys);
    bf16*  z0_buf  = (bf16*)(ws + off_z0);
    bf16*  s_sum   = (bf16*)(ws + off_s);
    bf16*  y_buf   = (bf16*)(ws + off_y);
    float* s_buf   = (float*)(ws + off_sb);

    (void)hipMemsetAsync(ws + off_sb, 0, 24576, stream);

    k_lnconv<<<dim3(24, 16, 4), 192, 0, stream>>>(
        x, ln_g, ln_b, p1_w, p1_b, p2in_w, p2in_b, a_buf, z0_buf);
    k_dwconv<<<dim3(96, 16, 4), 256, 0, stream>>>(
        z0_buf, dw_w, dw_b, bidx, zt_buf, ztT_buf);
    k_xdbl<<<dim3(12, 4, 64), 256, 0, stream>>>(
        zt_buf, ztT_buf, xproj_w, xdbl_buf);
    k_scan<<<dim3(512), 384, 0, stream>>>(
        zt_buf, ztT_buf, xdbl_buf, dtproj_w, dtproj_b, A_logs, Ds, ys_buf);
    k_sum<<<dim3(96, 16, 4), 256, 0, stream>>>(
        ys_buf, s_sum);
    k_combine<<<dim3(48, 16, 4), 256, 0, stream>>>(
        s_sum, a_buf, ssln_g, ssln_b, p2n_g, p2n_b, bidx, y_buf, s_buf);
    k_final<<<dim3(96, 16, 4), 256, 0, stream>>>(
        x, y_buf, s_buf, ca_w1, ca_b1, ca_w2, ca_b2, out);
}

// Round 8
// 632.771 us; speedup vs baseline: 1.1644x; 1.1526x over previous
//
#include <hip/hip_runtime.h>
#include <hip/hip_bf16.h>

// ---- problem constants ----
#define BQ 16      // batch
#define CN 96      // channels
#define HQ 48      // quadrant H = W
#define LL 2304    // HQ*HQ
#define NK 4       // scan directions
#define RR 6       // dt rank
#define NNS 8      // state size
#define DPJ 22     // R + 2N
#define CRr 12     // attention rank
#define LOG2E 1.4426950408889634f

using bf16 = __hip_bfloat16;

typedef __attribute__((ext_vector_type(8))) short bf16x8;   // 8 bf16 (4 VGPRs)
typedef __attribute__((ext_vector_type(4))) float f32x4;    // 4 fp32 acc

__device__ __forceinline__ float b2f(bf16 v) { return __bfloat162float(v); }
__device__ __forceinline__ bf16  f2b(float v){ return __float2bfloat16(v); }
__device__ __forceinline__ float bflo(unsigned u){ return __uint_as_float(u << 16); }
__device__ __forceinline__ float bfhi(unsigned u){ return __uint_as_float(u & 0xffff0000u); }
__device__ __forceinline__ float sigf(float x){ return 1.f / (1.f + __expf(-x)); }
__device__ __forceinline__ float siluf(float x){ return x / (1.f + __expf(-x)); }
__device__ __forceinline__ unsigned packbf(float a, float b){
    unsigned lo = (unsigned)__builtin_bit_cast(unsigned short, f2b(a));
    unsigned hi = (unsigned)__builtin_bit_cast(unsigned short, f2b(b));
    return lo | (hi << 16);
}
__device__ __forceinline__ unsigned rot16(unsigned u){ return (u >> 16) | (u << 16); }
__device__ __forceinline__ void unpack8(uint4 v, float* f){
    f[0]=bflo(v.x); f[1]=bfhi(v.x); f[2]=bflo(v.y); f[3]=bfhi(v.y);
    f[4]=bflo(v.z); f[5]=bfhi(v.z); f[6]=bflo(v.w); f[7]=bfhi(v.w);
}
__device__ __forceinline__ void unpack4(uint2 v, float* f){
    f[0]=bflo(v.x); f[1]=bfhi(v.x); f[2]=bflo(v.y); f[3]=bfhi(v.y);
}
__device__ __forceinline__ float fexp2(float x){
#if __has_builtin(__builtin_amdgcn_exp2f)
    return __builtin_amdgcn_exp2f(x);
#else
    return __expf(x * 0.6931471805599453f);
#endif
}
// quad_perm DPP xor within groups of 4 lanes (VALU pipe, no LDS)
__device__ __forceinline__ float qxor(float v, int ctrl_b1){
    int x;
    if (ctrl_b1) x = __builtin_amdgcn_mov_dpp(__float_as_int(v), 0xB1, 0xF, 0xF, true);
    else         x = __builtin_amdgcn_mov_dpp(__float_as_int(v), 0x4E, 0xF, 0xF, true);
    return __int_as_float(x);
}

// ============================================================================
// K1: channel LN + conv1x1 via MFMA (a-branch silu, z-branch raw -> bf16)
// grid (24, 16, 4) = (hh-pair, b, q), block 192 = 3 waves
// R8: fix R7's lbase bug — `col & 47` is NOT col%48 (48 not a pow2); row-1
//     outputs were scattered/colliding. Single-line fix, rest unchanged.
//   C[192 rows][96 pos] = W[192][96k] x H[96k][96 pos]; 12x6x3 = 216 MFMA/blk.
//   A frag: lane%16 = M row, k contiguous per lane.  B frag: lane%16 = N col.
//   D: col = lane&15, row = (lane>>4)*4 + reg  (guide m89-verified mapping).
// ============================================================================
__global__ __launch_bounds__(192) void k_lnconv(
    const float* __restrict__ x, const float* __restrict__ ln_g, const float* __restrict__ ln_b,
    const float* __restrict__ p1w, const float* __restrict__ p1b,
    const float* __restrict__ p2w, const float* __restrict__ p2b,
    bf16* __restrict__ a_out, bf16* __restrict__ z0_out)
{
    const int hh2 = blockIdx.x;           // 0..23 (covers 2 rows each)
    const int b = blockIdx.y, q = blockIdx.z;
    const int h0 = (q >> 1) * HQ, w0 = (q & 1) * HQ;
    const int tid = threadIdx.x;
    const int qb = q * BQ + b;

    __shared__ alignas(16) bf16 wl2[192 * 104];   // [row][k]
    __shared__ alignas(16) bf16 hn2[96 * 104];    // [p][c]
    __shared__ float mu[96], rs[96];
    __shared__ float pmu[192], pv2[192];
    __shared__ float biasLds[192];
    __shared__ float gl[96], bl[96];

    // stage weights [row][k] bf16: rows 0-95 = p1 (a), 96-191 = p2 (z);
    // global p1w/p2w are [d][c] row-major already.
    for (int t = tid; t < 192 * 24; t += 192) {
        int row = t / 24, c4 = (t % 24) * 4;
        const float* srcw = (row < 96) ? &p1w[(q * CN + row) * CN + c4]
                                       : &p2w[(q * CN + (row - 96)) * CN + c4];
        float4 wv = *reinterpret_cast<const float4*>(srcw);
        uint2 pk; pk.x = packbf(wv.x, wv.y); pk.y = packbf(wv.z, wv.w);
        *reinterpret_cast<uint2*>(&wl2[row * 104 + c4]) = pk;
    }
    if (tid < 192)
        biasLds[tid] = (tid < 96) ? p1b[q * CN + tid] : p2b[q * CN + (tid - 96)];
    if (tid < 96) { gl[tid] = ln_g[q * CN + tid]; bl[tid] = ln_b[q * CN + tid]; }
    // stage x tile TRANSPOSED to [p][c]
    for (int t = tid; t < CN * 24; t += 192) {
        int c = t / 24, v = t % 24;
        int row = v / 12, col = (v % 12) * 4;
        int p = row * 48 + col;
        float4 xv = *reinterpret_cast<const float4*>(
            &x[((b * CN + c) * 96 + h0 + 2 * hh2 + row) * 96 + w0 + col]);
        hn2[p * 104 + c]       = f2b(xv.x);
        hn2[(p + 1) * 104 + c] = f2b(xv.y);
        hn2[(p + 2) * 104 + c] = f2b(xv.z);
        hn2[(p + 3) * 104 + c] = f2b(xv.w);
    }
    __syncthreads();
    // LN stats: 192 thr = 96 pos x 2 halves of 48 ch (vectorized)
    {
        int p = tid % 96, half = tid / 96;
        const bf16* hp = &hn2[p * 104 + half * 48];
        float s = 0.f, s2 = 0.f;
        #pragma unroll
        for (int c8 = 0; c8 < 48; c8 += 8) {
            float f[8]; unpack8(*reinterpret_cast<const uint4*>(hp + c8), f);
            #pragma unroll
            for (int i = 0; i < 8; ++i) { s += f[i]; s2 += f[i] * f[i]; }
        }
        pmu[half * 96 + p] = s; pv2[half * 96 + p] = s2;
    }
    __syncthreads();
    if (tid < 96) {
        float s = pmu[tid] + pmu[96 + tid];
        float s2 = pv2[tid] + pv2[96 + tid];
        float m = s * (1.f / 96.f);
        float var = s2 * (1.f / 96.f) - m * m;
        mu[tid] = m; rs[tid] = rsqrtf(var + 1e-6f);
    }
    __syncthreads();
    // normalize in place: 96 pos x 12 octets
    for (int t = tid; t < 96 * 12; t += 192) {
        int p = t / 12, c8 = (t % 12) * 8;
        float f[8]; unpack8(*reinterpret_cast<const uint4*>(&hn2[p * 104 + c8]), f);
        float m = mu[p], r = rs[p];
        unsigned ou[4];
        #pragma unroll
        for (int i = 0; i < 8; i += 2) {
            float v0 = (f[i]     - m) * r * gl[c8 + i]     + bl[c8 + i];
            float v1 = (f[i + 1] - m) * r * gl[c8 + i + 1] + bl[c8 + i + 1];
            ou[i >> 1] = packbf(v0, v1);
        }
        uint4 ov; ov.x = ou[0]; ov.y = ou[1]; ov.z = ou[2]; ov.w = ou[3];
        *reinterpret_cast<uint4*>(&hn2[p * 104 + c8]) = ov;
    }
    __syncthreads();
    // MFMA: wave w owns M rows [w*64, w*64+64) = 4 M-tiles x 6 N-tiles
    const int w = tid >> 6;
    const int l = tid & 63;
    const int lr = l & 15;          // M row / N col within tile
    const int lq = l >> 4;          // quarter: k-block for A/B, row-block for D
    f32x4 acc[4][6];
    #pragma unroll
    for (int m = 0; m < 4; ++m)
        #pragma unroll
        for (int n = 0; n < 6; ++n)
            acc[m][n] = (f32x4){0.f, 0.f, 0.f, 0.f};
    #pragma unroll
    for (int k0 = 0; k0 < 96; k0 += 32) {
        bf16x8 afr[4], bfr[6];
        #pragma unroll
        for (int m = 0; m < 4; ++m)
            afr[m] = *reinterpret_cast<const bf16x8*>(
                &wl2[(w * 64 + m * 16 + lr) * 104 + k0 + lq * 8]);
        #pragma unroll
        for (int n = 0; n < 6; ++n)
            bfr[n] = *reinterpret_cast<const bf16x8*>(
                &hn2[(n * 16 + lr) * 104 + k0 + lq * 8]);
        #pragma unroll
        for (int m = 0; m < 4; ++m)
            #pragma unroll
            for (int n = 0; n < 6; ++n)
                acc[m][n] = __builtin_amdgcn_mfma_f32_16x16x32_bf16(
                    afr[m], bfr[n], acc[m][n], 0, 0, 0);
    }
    // epilogue: bias + (silu for a-rows) + bf16 store
    #pragma unroll
    for (int m = 0; m < 4; ++m) {
        const int Rbase = w * 64 + m * 16 + lq * 4;
        #pragma unroll
        for (int n = 0; n < 6; ++n) {
            const int col = n * 16 + lr;
            const int colin = (col >= 48) ? (col - 48) : col;       // col % 48 (48 != pow2!)
            const int lbase = (2 * hh2 + (col >= 48 ? 1 : 0)) * 48 + colin;
            #pragma unroll
            for (int r = 0; r < 4; ++r) {
                const int R = Rbase + r;
                const bool isA = R < 96;
                const int d = isA ? R : R - 96;
                float v = acc[m][n][r] + biasLds[R];
                if (isA) v = siluf(v);
                bf16* dst = isA ? a_out : z0_out;
                dst[(size_t)(qb * CN + d) * LL + lbase] = f2b(v);
            }
        }
    }
}

// ============================================================================
// K2: depthwise 3x3 SAME + bias + silu + block_idx transform (bf16 in/out)
// grid (96, 16, 4) = (c, b, q), block 256
// R6: zero-padded zin[50][50] -> branchless 9-tap interior (no per-tap cmp)
// ============================================================================
__global__ __launch_bounds__(256) void k_dwconv(
    const bf16* __restrict__ z0, const float* __restrict__ dww, const float* __restrict__ dwb,
    const int* __restrict__ bidx, bf16* __restrict__ zt, bf16* __restrict__ ztT)
{
    const int c = blockIdx.x, b = blockIdx.y, q = blockIdx.z;
    const int tid = threadIdx.x;
    const int base = ((q * BQ + b) * CN + c) * LL;
    __shared__ float zin[50 * 50];  // 1-elem zero border
    __shared__ float zo[48 * 49];   // padded rows: conflict-free transposed reads
    // zero the border (196 cells, disjoint from interior staging)
    if (tid < 196) {
        int idx;
        if (tid < 50)       idx = tid;                    // row 0
        else if (tid < 100) idx = 49 * 50 + (tid - 50);   // row 49
        else if (tid < 148) idx = (tid - 99) * 50;        // col 0, rows 1..48
        else                idx = (tid - 147) * 50 + 49;  // col 49, rows 1..48
        zin[idx] = 0.f;
    }
    for (int t = tid; t < 288; t += 256) {
        uint4 v = *reinterpret_cast<const uint4*>(&z0[base + t * 8]);
        float f[8]; unpack8(v, f);
        int e0 = t * 8, row = e0 / 48, col = e0 % 48;
        float* dst = &zin[(row + 1) * 50 + col + 1];
        #pragma unroll
        for (int i = 0; i < 8; ++i) dst[i] = f[i];
    }
    float wk[9];
    #pragma unroll
    for (int i = 0; i < 9; ++i) wk[i] = dww[(q * CN + c) * 9 + i];
    const float bias = dwb[q * CN + c];
    __syncthreads();
    for (int t = tid; t < LL; t += 256) {
        int hh = t / 48, ww = t % 48;
        const float* z0r = &zin[hh * 50 + ww];        // top-left tap
        float s = bias;
        s = fmaf(wk[0], z0r[0],        s);
        s = fmaf(wk[1], z0r[1],        s);
        s = fmaf(wk[2], z0r[2],        s);
        s = fmaf(wk[3], z0r[50],       s);
        s = fmaf(wk[4], z0r[51],       s);
        s = fmaf(wk[5], z0r[52],       s);
        s = fmaf(wk[6], z0r[100],      s);
        s = fmaf(wk[7], z0r[101],      s);
        s = fmaf(wk[8], z0r[102],      s);
        zo[hh * 49 + ww] = siluf(s);
    }
    __syncthreads();
    const bool even = ((bidx[0] & 1) == 0);
    for (int t = tid; t < LL; t += 256) {
        int i = t / 48, j = t % 48;
        float vz, vzT;
        if (even) { vz = zo[j * 49 + i];               vzT = zo[i * 49 + j]; }
        else      { vz = zo[(47 - i) * 49 + (47 - j)]; vzT = zo[(47 - j) * 49 + (47 - i)]; }
        zt[base + t]  = f2b(vz);
        ztT[base + t] = f2b(vzT);
    }
}

// ============================================================================
// K3: x_dbl = xproj_w @ u_k  (direction mapping + reversal folded in)
// grid (12, 4, 64) = (l-tile, k, q*16+b), block 256
// compute retiled: 2 d-rows x 12 l = 176 tiles, single pass
// ============================================================================
__global__ __launch_bounds__(256) void k_xdbl(
    const bf16* __restrict__ zt, const bf16* __restrict__ ztT,
    const float* __restrict__ xprojw, bf16* __restrict__ xdbl)
{
    const int lt = blockIdx.x, k = blockIdx.y, qb = blockIdx.z;
    const int tid = threadIdx.x;
    const int l0 = lt * 192;
    const int q = qb >> 4;
    __shared__ alignas(16) bf16 ul[CN * 200];
    __shared__ alignas(16) bf16 wl[CN * 24];    // transposed [c][d], pad 22->24
    const bf16* __restrict__ src = (k & 1) ? ztT : zt;
    const bool rev = (k >= 2);
    // vectorized staging: 96c x 24 vectors of 8 bf16
    for (int t = tid; t < CN * 24; t += 256) {
        int cc = t / 24, j0 = (t % 24) * 8;
        uint4 v;
        if (!rev) {
            v = *reinterpret_cast<const uint4*>(&src[(size_t)(qb * CN + cc) * LL + l0 + j0]);
        } else {
            v = *reinterpret_cast<const uint4*>(&src[(size_t)(qb * CN + cc) * LL + (LL - (l0 + j0) - 8)]);
            uint4 r; r.x = rot16(v.w); r.y = rot16(v.z); r.z = rot16(v.y); r.w = rot16(v.x);
            v = r;
        }
        *reinterpret_cast<uint4*>(&ul[cc * 200 + j0]) = v;
    }
    for (int t = tid; t < DPJ * CN; t += 256) {
        int d = t / CN, c = t % CN;
        wl[c * 24 + d] = f2b(xprojw[(q * NK + k) * DPJ * CN + t]);
    }
    __syncthreads();
    // tiles: 2 d-rows x 12 l : 11 * 16 = 176 tiles, single pass
    if (tid < 176) {
        const int dp = tid / 16, lg = tid % 16;
        const int d0 = dp * 2, llp = lg * 12;
        float acc0[12], acc1[12];
        #pragma unroll
        for (int j = 0; j < 12; ++j) { acc0[j] = 0.f; acc1[j] = 0.f; }
        for (int c = 0; c < CN; ++c) {
            unsigned wv = *reinterpret_cast<const unsigned*>(&wl[c * 24 + d0]);
            float w0 = bflo(wv), w1 = bfhi(wv);
            uint2 ua = *reinterpret_cast<const uint2*>(&ul[c * 200 + llp]);
            uint2 ub = *reinterpret_cast<const uint2*>(&ul[c * 200 + llp + 4]);
            uint2 uc = *reinterpret_cast<const uint2*>(&ul[c * 200 + llp + 8]);
            float uf[12];
            unpack4(ua, uf); unpack4(ub, uf + 4); unpack4(uc, uf + 8);
            #pragma unroll
            for (int j = 0; j < 12; ++j) {
                acc0[j] = fmaf(w0, uf[j], acc0[j]);
                acc1[j] = fmaf(w1, uf[j], acc1[j]);
            }
        }
        int ob = (qb * NK + k) * DPJ * LL + l0 + llp;
        uint2 o0a, o0b, o0c, o1a, o1b, o1c;
        o0a.x = packbf(acc0[0], acc0[1]);  o0a.y = packbf(acc0[2], acc0[3]);
        o0b.x = packbf(acc0[4], acc0[5]);  o0b.y = packbf(acc0[6], acc0[7]);
        o0c.x = packbf(acc0[8], acc0[9]);  o0c.y = packbf(acc0[10], acc0[11]);
        o1a.x = packbf(acc1[0], acc1[1]);  o1a.y = packbf(acc1[2], acc1[3]);
        o1b.x = packbf(acc1[4], acc1[5]);  o1b.y = packbf(acc1[6], acc1[7]);
        o1c.x = packbf(acc1[8], acc1[9]);  o1c.y = packbf(acc1[10], acc1[11]);
        *reinterpret_cast<uint2*>(&xdbl[ob + d0 * LL])           = o0a;
        *reinterpret_cast<uint2*>(&xdbl[ob + d0 * LL + 4])       = o0b;
        *reinterpret_cast<uint2*>(&xdbl[ob + d0 * LL + 8])       = o0c;
        *reinterpret_cast<uint2*>(&xdbl[ob + (d0 + 1) * LL])     = o1a;
        *reinterpret_cast<uint2*>(&xdbl[ob + (d0 + 1) * LL + 4]) = o1b;
        *reinterpret_cast<uint2*>(&xdbl[ob + (d0 + 1) * LL + 8]) = o1c;
    }
}

// ============================================================================
// K4: fused delta(softplus) + selective scan + Ds*u term
// grid (512), block 384 producer/consumer — UNCHANGED from round 5/6
// ============================================================================

// raw barrier: drain LDS (cross-wave visibility of ds_writes) but NOT vmcnt
#define SCAN_BARRIER() asm volatile("s_waitcnt lgkmcnt(0)\n\ts_barrier" ::: "memory")

// word IDX (0..23) of a 6-uint4 register array holding 48 bf16
#define UWORD(NUA, IDX) (((IDX) & 3) == 0 ? NUA[(IDX) >> 2].x : \
                         ((IDX) & 3) == 1 ? NUA[(IDX) >> 2].y : \
                         ((IDX) & 3) == 2 ? NUA[(IDX) >> 2].z : NUA[(IDX) >> 2].w)

#define ROT3(v) (v) = ((v) == 2) ? 0 : ((v) + 1)

__global__ __launch_bounds__(384) void k_scan(
    const bf16* __restrict__ zt, const bf16* __restrict__ ztT,
    const bf16* __restrict__ xdbl,
    const float* __restrict__ dtw_g, const float* __restrict__ dtb_g,
    const float* __restrict__ Alog_g, const float* __restrict__ Ds_g,
    bf16* __restrict__ ys)
{
    const int bid = blockIdx.x;
    const int ch2 = bid & 1, k = (bid >> 1) & 3, qb = bid >> 3, q = qb >> 4;
    const int qk = q * NK + k;
    const int tid = threadIdx.x;
    const bool isScan = (tid < 192);
    const int lt = isScan ? tid : (tid - 192);   // role-local 0..191
    const int ca = lt >> 2, p = lt & 3;
    const int c = ch2 * 48 + ca;          // global channel

    __shared__ float dd3[3][48 * 52];
    __shared__ float xr3[3][6 * 52];          // dts rows
    __shared__ float bcv3[3][48 * 16];        // [j][p*4 + {B0,B1,C0,C1}]

    const bf16* __restrict__ src = (k & 1) ? ztT : zt;
    const bool rev = (k >= 2);
    const int ja = p * 12;

    // ---- producer-role parameters ----
    float wdt[6] = {0.f, 0.f, 0.f, 0.f, 0.f, 0.f};
    float dtbc = 0.f;
    if (!isScan) {
        const float* wp = dtw_g + (size_t)qk * CN * RR + c * RR;
        float2 wa = *reinterpret_cast<const float2*>(wp);
        float2 wb = *reinterpret_cast<const float2*>(wp + 2);
        float2 wc = *reinterpret_cast<const float2*>(wp + 4);
        wdt[0] = wa.x; wdt[1] = wa.y; wdt[2] = wb.x; wdt[3] = wb.y; wdt[4] = wc.x; wdt[5] = wc.y;
        dtbc = dtb_g[qk * CN + c];
    }
    // xdbl staging: producer threads with lt<132 stage one uint4 from row vr
    const bool xload = (!isScan) && (lt < 132);
    const int vr = lt / 6, jx = (lt % 6) * 8;
    const bf16* gx = xdbl + (size_t)(qb * NK + k) * (DPJ * LL) + (size_t)vr * LL + jx;
    int bccol = 0;
    if (vr >= 6) {
        int v = vr - 6;           // 0..15: 0-7 B, 8-15 C
        int n = v & 7;
        bccol = (n >> 1) * 4 + ((v >= 8) ? 2 : 0) + (n & 1);
    }

    // ---- scan-role parameters ----
    float A0L = 0.f, A1L = 0.f, Dc = 0.f;
    if (isScan) {
        A0L = -__expf(Alog_g[((size_t)qk * CN + c) * NNS + 2 * p])     * LOG2E;
        A1L = -__expf(Alog_g[((size_t)qk * CN + c) * NNS + 2 * p + 1]) * LOG2E;
        Dc = Ds_g[qk * CN + c];
    }
    float h0 = 0.f, h1 = 0.f;
    const bf16* gu = src + (size_t)(qb * CN + c) * LL + (rev ? (LL - 48) : 0);
    const int ustep = rev ? -48 : 48;
    bf16* yp = ys + (size_t)(qb * NK + k) * (CN * LL) + (size_t)c * LL;  // p==0 stores

    #define COMMIT_BLOCK(PXV, XRB, BCB) do {                                          \
        if (xload) {                                                                  \
            float g[8]; unpack8(PXV, g);                                              \
            if (vr < 6) {                                                             \
                *reinterpret_cast<float4*>(&(XRB)[vr * 52 + jx])                      \
                    = make_float4(g[0], g[1], g[2], g[3]);                            \
                *reinterpret_cast<float4*>(&(XRB)[vr * 52 + jx + 4])                  \
                    = make_float4(g[4], g[5], g[6], g[7]);                            \
            } else {                                                                  \
                _Pragma("unroll")                                                     \
                for (int i = 0; i < 8; ++i) (BCB)[(jx + i) * 16 + bccol] = g[i];      \
            }                                                                         \
        }                                                                             \
    } while (0)

    #define DELTA_BLOCK(XRB, DDB) do {                                                \
        float acc[12];                                                                \
        _Pragma("unroll")                                                             \
        for (int i = 0; i < 12; ++i) acc[i] = dtbc;                                   \
        _Pragma("unroll")                                                             \
        for (int r = 0; r < 6; ++r) {                                                 \
            float4 d0 = *reinterpret_cast<const float4*>(&(XRB)[r * 52 + ja]);        \
            float4 d1 = *reinterpret_cast<const float4*>(&(XRB)[r * 52 + ja + 4]);    \
            float4 d2 = *reinterpret_cast<const float4*>(&(XRB)[r * 52 + ja + 8]);    \
            float wr_ = wdt[r];                                                       \
            acc[0] = fmaf(wr_, d0.x, acc[0]);  acc[1] = fmaf(wr_, d0.y, acc[1]);      \
            acc[2] = fmaf(wr_, d0.z, acc[2]);  acc[3] = fmaf(wr_, d0.w, acc[3]);      \
            acc[4] = fmaf(wr_, d1.x, acc[4]);  acc[5] = fmaf(wr_, d1.y, acc[5]);      \
            acc[6] = fmaf(wr_, d1.z, acc[6]);  acc[7] = fmaf(wr_, d1.w, acc[7]);      \
            acc[8] = fmaf(wr_, d2.x, acc[8]);  acc[9] = fmaf(wr_, d2.y, acc[9]);      \
            acc[10] = fmaf(wr_, d2.z, acc[10]); acc[11] = fmaf(wr_, d2.w, acc[11]);   \
        }                                                                             \
        _Pragma("unroll")                                                             \
        for (int i = 0; i < 12; ++i) {                                                \
            float a = acc[i];                                                         \
            acc[i] = (a > 15.f) ? a : __logf(1.f + __expf(a));                        \
        }                                                                             \
        float4* dp = reinterpret_cast<float4*>(&(DDB)[ca * 52 + ja]);                 \
        dp[0] = make_float4(acc[0], acc[1], acc[2], acc[3]);                          \
        dp[1] = make_float4(acc[4], acc[5], acc[6], acc[7]);                          \
        dp[2] = make_float4(acc[8], acc[9], acc[10], acc[11]);                        \
    } while (0)

    // ---- prologue ----
    uint4 u_a[6], u_b[6];
    uint4 px_a = {0,0,0,0}, px_b = {0,0,0,0}, px1 = {0,0,0,0};
    if (isScan) {
        #pragma unroll
        for (int i = 0; i < 6; ++i) u_a[i] = *reinterpret_cast<const uint4*>(gu + i * 8);  // chunk 0
        gu += ustep;
        #pragma unroll
        for (int i = 0; i < 6; ++i) u_b[i] = *reinterpret_cast<const uint4*>(gu + i * 8);  // chunk 1
        gu += ustep;                                           // -> chunk 2
    } else {
        uint4 px0 = {0,0,0,0};
        if (xload) {
            px0  = *reinterpret_cast<const uint4*>(gx);        // chunk 0
            px1  = *reinterpret_cast<const uint4*>(gx + 48);   // chunk 1
            px_a = *reinterpret_cast<const uint4*>(gx + 96);   // chunk 2
            px_b = *reinterpret_cast<const uint4*>(gx + 144);  // chunk 3
            gx += 192;                                         // -> chunk 4
        }
        COMMIT_BLOCK(px0, xr3[0], bcv3[0]);
    }
    SCAN_BARRIER();
    if (!isScan) {
        DELTA_BLOCK(xr3[0], dd3[0]);
        COMMIT_BLOCK(px1, xr3[1], bcv3[1]);
    }
    SCAN_BARRIER();

    // buffer cursors
    int s_cur = 0;              // scan:  buf of chunk ch
    int d_idx = 1, c_idx = 2;   // prod:  delta buf (ch+1), commit buf (ch+2)

    #define PROD_BODY(CH, PX) do {                                                    \
        const int chp_ = (CH);                                                        \
        if (chp_ + 2 < 48) COMMIT_BLOCK(PX, xr3[c_idx], bcv3[c_idx]);                 \
        if (chp_ + 4 < 48 && xload) { PX = *reinterpret_cast<const uint4*>(gx); gx += 48; } \
        if (chp_ + 1 < 48) DELTA_BLOCK(xr3[d_idx], dd3[d_idx]);                       \
        ROT3(d_idx); ROT3(c_idx);                                                     \
    } while (0)

    #define SCAN_CHUNK(CH, UC) do {                                                   \
        const int ch_ = (CH);                                                         \
        uint4 nu[6];                                                                  \
        if (!rev) {                                                                   \
            nu[0] = UC[0]; nu[1] = UC[1]; nu[2] = UC[2];                              \
            nu[3] = UC[3]; nu[4] = UC[4]; nu[5] = UC[5];                              \
        } else {                                                                      \
            _Pragma("unroll")                                                         \
            for (int qq = 0; qq < 6; ++qq) {                                          \
                nu[qq].x = rot16(UC[5 - qq].w); nu[qq].y = rot16(UC[5 - qq].z);       \
                nu[qq].z = rot16(UC[5 - qq].y); nu[qq].w = rot16(UC[5 - qq].x);       \
            }                                                                         \
        }                                                                             \
        {                                                                             \
            const int l0 = ch_ * 48;                                                  \
            const float* ddc = &dd3[s_cur][ca * 52];                                  \
            const float* bcc = &bcv3[s_cur][p * 4];                                   \
            _Pragma("unroll")                                                         \
            for (int gg = 0; gg < 6; ++gg) {                                          \
                unsigned pk[4];                                                       \
                _Pragma("unroll")                                                     \
                for (int half = 0; half < 2; ++half) {                                \
                    const int j0 = gg * 8 + half * 4;                                 \
                    float4 d4 = *reinterpret_cast<const float4*>(ddc + j0);           \
                    const float* df = reinterpret_cast<const float*>(&d4);            \
                    _Pragma("unroll")                                                 \
                    for (int s = 0; s < 4; ++s) {                                     \
                        const int j = j0 + s;                                         \
                        const unsigned uwv = UWORD(nu, j >> 1);                       \
                        float u = (j & 1) ? bfhi(uwv) : bflo(uwv);                    \
                        float d = df[s];                                              \
                        float4 bq = *reinterpret_cast<const float4*>(bcc + j * 16);   \
                        float du = d * u;                                             \
                        float dA0 = fexp2(d * A0L);                                   \
                        float dA1 = fexp2(d * A1L);                                   \
                        h0 = fmaf(dA0, h0, du * bq.x);                                \
                        h1 = fmaf(dA1, h1, du * bq.y);                                \
                        float y = fmaf(h0, bq.z, h1 * bq.w);                          \
                        y += qxor(y, 1); y += qxor(y, 0);                             \
                        y = fmaf(Dc, u, y);                                           \
                        unsigned hb = (unsigned)__builtin_bit_cast(unsigned short, f2b(y)); \
                        const int sl = half * 4 + s;                                  \
                        if (sl & 1) pk[sl >> 1] |= hb << 16; else pk[sl >> 1] = hb;   \
                    }                                                                 \
                }                                                                     \
                if (p == 0) {                                                         \
                    uint4 wv4; wv4.x = pk[0]; wv4.y = pk[1]; wv4.z = pk[2]; wv4.w = pk[3]; \
                    *reinterpret_cast<uint4*>(yp + l0 + gg * 8) = wv4;                \
                }                                                                     \
            }                                                                         \
        }                                                                             \
        if (ch_ + 2 < 48) {                                                           \
            _Pragma("unroll")                                                         \
            for (int i = 0; i < 6; ++i) UC[i] = *reinterpret_cast<const uint4*>(gu + i * 8); \
            gu += ustep;                                                              \
        }                                                                             \
        ROT3(s_cur);                                                                  \
    } while (0)

    for (int t = 0; t < 24; ++t) {
        if (isScan) SCAN_CHUNK(2 * t, u_a);
        else        PROD_BODY(2 * t, px_a);
        SCAN_BARRIER();
        if (isScan) SCAN_CHUNK(2 * t + 1, u_b);
        else        PROD_BODY(2 * t + 1, px_b);
        SCAN_BARRIER();
    }

    #undef SCAN_CHUNK
    #undef PROD_BODY
    #undef DELTA_BLOCK
    #undef COMMIT_BLOCK
}

// ============================================================================
// K4b: k_sum — combine 4 directions into one tensor at combine-index m
// grid (96, 16, 4) = (c, b, q), block 256
// ============================================================================
__global__ __launch_bounds__(256) void k_sum(
    const bf16* __restrict__ ys, bf16* __restrict__ s_out)
{
    const int c = blockIdx.x, b = blockIdx.y, q = blockIdx.z;
    const int qb = q * BQ + b;
    const int tid = threadIdx.x;
    __shared__ float t0[48 * 49];
    __shared__ float t2[48 * 49];
    const size_t base0 = ((size_t)(qb * NK + 0) * CN + c) * LL;
    const size_t base1 = ((size_t)(qb * NK + 1) * CN + c) * LL;
    const size_t base2 = ((size_t)(qb * NK + 2) * CN + c) * LL;
    const size_t base3 = ((size_t)(qb * NK + 3) * CN + c) * LL;
    for (int idx = tid; idx < 288; idx += 256) {
        int e0 = idx * 8, h = e0 / 48, w = e0 % 48;
        float f[8];
        unpack8(*reinterpret_cast<const uint4*>(&ys[base0 + e0]), f);
        #pragma unroll
        for (int i = 0; i < 8; ++i) t0[h * 49 + w + i] = f[i];
        unpack8(*reinterpret_cast<const uint4*>(&ys[base2 + e0]), f);
        #pragma unroll
        for (int i = 0; i < 8; ++i) t2[h * 49 + w + i] = f[i];
    }
    __syncthreads();
    const size_t cbase = ((size_t)qb * CN + c) * LL;
    for (int idx = tid; idx < 288; idx += 256) {
        int m0 = idx * 8, ww = m0 / 48, hh = m0 % 48;
        float f1[8], f3[8];
        unpack8(*reinterpret_cast<const uint4*>(&ys[base1 + m0]), f1);
        unpack8(*reinterpret_cast<const uint4*>(&ys[base3 + (LL - 8 - m0)]), f3);
        float o[8];
        #pragma unroll
        for (int i = 0; i < 8; ++i) {
            float v0 = t0[(hh + i) * 49 + ww];
            float v2 = t2[(47 - hh - i) * 49 + (47 - ww)];
            o[i] = v0 + f1[i] + v2 + f3[7 - i];
        }
        uint4 w;
        w.x = packbf(o[0], o[1]); w.y = packbf(o[2], o[3]);
        w.z = packbf(o[4], o[5]); w.w = packbf(o[6], o[7]);
        *reinterpret_cast<uint4*>(&s_out[cbase + m0]) = w;
    }
}

// ============================================================================
// K5: combine: LN(ssln) + LN(p2n) + y=a*z + attention partial sums
// grid (48, 16, 4) = (ww, b, q), block 256
// ============================================================================
__global__ __launch_bounds__(256) void k_combine(
    const bf16* __restrict__ s_in, const bf16* __restrict__ a_in,
    const float* __restrict__ ssg, const float* __restrict__ ssb,
    const float* __restrict__ png, const float* __restrict__ pnb,
    const int* __restrict__ bidx,
    bf16* __restrict__ y_out, float* __restrict__ s_buf)
{
    const int ww = blockIdx.x, b = blockIdx.y, q = blockIdx.z;
    const int qb = q * BQ + b;
    const int tid = threadIdx.x;
    __shared__ float o[CN * 48];
    __shared__ float mu[48], rs[48];
    __shared__ float pp[192], pp2[192];
    for (int v = tid; v < 576; v += 256) {
        int e0 = v * 8, cc = e0 / 48, hh = e0 % 48;
        float f[8];
        unpack8(*reinterpret_cast<const uint4*>(&s_in[((size_t)qb * CN + cc) * LL + ww * 48 + hh]), f);
        #pragma unroll
        for (int i = 0; i < 8; ++i) o[cc * 48 + hh + i] = f[i];
    }
    __syncthreads();
    // stats phase 1: 192 threads = 48 hh x 4 parts of 24 ch
    if (tid < 192) {
        int hh = tid % 48, part = tid / 48;
        float s = 0.f, s2 = 0.f;
        int c0 = part * 24;
        for (int cc = c0; cc < c0 + 24; ++cc) { float v = o[cc * 48 + hh]; s += v; s2 += v * v; }
        pp[tid] = s; pp2[tid] = s2;
    }
    __syncthreads();
    if (tid < 48) {
        float s = pp[tid] + pp[tid + 48] + pp[tid + 96] + pp[tid + 144];
        float s2 = pp2[tid] + pp2[tid + 48] + pp2[tid + 96] + pp2[tid + 144];
        float m = s * (1.f / 96.f), var = s2 * (1.f / 96.f) - m * m;
        mu[tid] = m; rs[tid] = rsqrtf(var + 1e-6f);
    }
    __syncthreads();
    for (int t = tid; t < CN * 48; t += 256) {
        int cc = t / 48, hh = t % 48;
        o[t] = (o[t] - mu[hh]) * rs[hh] * ssg[q * CN + cc] + ssb[q * CN + cc];
    }
    __syncthreads();
    // stats phase 2
    if (tid < 192) {
        int hh = tid % 48, part = tid / 48;
        float s = 0.f, s2 = 0.f;
        int c0 = part * 24;
        for (int cc = c0; cc < c0 + 24; ++cc) { float v = o[cc * 48 + hh]; s += v; s2 += v * v; }
        pp[tid] = s; pp2[tid] = s2;
    }
    __syncthreads();
    if (tid < 48) {
        float s = pp[tid] + pp[tid + 48] + pp[tid + 96] + pp[tid + 144];
        float s2 = pp2[tid] + pp2[tid + 48] + pp2[tid + 96] + pp2[tid + 144];
        float m = s * (1.f / 96.f), var = s2 * (1.f / 96.f) - m * m;
        mu[tid] = m; rs[tid] = rsqrtf(var + 1e-6f);
    }
    __syncthreads();
    const bool even = ((bidx[0] & 1) == 0);
    if (even) {
        for (int v = tid; v < 576; v += 256) {
            int e0 = v * 8, cc = e0 / 48, hh = e0 % 48;
            size_t oidx = ((size_t)qb * CN + cc) * LL + ww * 48 + hh;
            float af[8];
            unpack8(*reinterpret_cast<const uint4*>(&a_in[oidx]), af);
            float yv[8];
            #pragma unroll
            for (int i = 0; i < 8; ++i) {
                float z2 = (o[cc * 48 + hh + i] - mu[hh + i]) * rs[hh + i] * png[q * CN + cc] + pnb[q * CN + cc];
                yv[i] = af[i] * z2;
                o[cc * 48 + hh + i] = yv[i];
            }
            uint4 w;
            w.x = packbf(yv[0], yv[1]); w.y = packbf(yv[2], yv[3]);
            w.z = packbf(yv[4], yv[5]); w.w = packbf(yv[6], yv[7]);
            *reinterpret_cast<uint4*>(&y_out[oidx]) = w;
        }
    } else {
        for (int t = tid; t < CN * 48; t += 256) {
            int cc = t / 48, hh = t % 48;
            float z2 = (o[t] - mu[hh]) * rs[hh] * png[q * CN + cc] + pnb[q * CN + cc];
            size_t oidx = ((size_t)qb * CN + cc) * LL + (47 - hh) * 48 + (47 - ww);
            float yv = b2f(a_in[oidx]) * z2;
            y_out[oidx] = f2b(yv);
            o[t] = yv;
        }
    }
    __syncthreads();
    if (tid < CN) {
        float s = 0.f;
        for (int j = 0; j < 48; ++j) s += o[tid * 48 + j];
        atomicAdd(&s_buf[qb * CN + tid], s);
    }
}

// ============================================================================
// K7: out = x + y * att  with channel attention computed in-block
// grid (96, 16, 4) = (c, b, q), block 256
// ============================================================================
__global__ __launch_bounds__(256) void k_final(
    const float* __restrict__ x, const bf16* __restrict__ y_in,
    const float* __restrict__ s_buf,
    const float* __restrict__ w1, const float* __restrict__ b1,
    const float* __restrict__ w2, const float* __restrict__ b2,
    float* __restrict__ out)
{
    const int c = blockIdx.x, b = blockIdx.y, q = blockIdx.z;
    const int h0 = (q >> 1) * HQ, w0 = (q & 1) * HQ;
    const int qb = q * BQ + b;
    const int tid = threadIdx.x;
    __shared__ float tl[CRr];
    __shared__ float tpart[16 * CRr];
    __shared__ float attv;
    if (tid < 192) {
        int r = tid % CRr, part = tid / CRr;   // 16 parts x 6 channels
        float acc = 0.f;
        const float* wr = w1 + (q * CRr + r) * CN;
        const float* sb = s_buf + qb * CN;
        int c0 = part * 6;
        for (int cc = c0; cc < c0 + 6; ++cc)
            acc = fmaf(wr[cc], sb[cc] * (1.f / (float)LL), acc);
        tpart[part * CRr + r] = acc;
    }
    __syncthreads();
    if (tid < CRr) {
        float acc = b1[q * CRr + tid];
        #pragma unroll
        for (int pt = 0; pt < 16; ++pt) acc += tpart[pt * CRr + tid];
        tl[tid] = siluf(acc);
    }
    __syncthreads();
    if (tid == 0) {
        float acc = b2[q * CN + c];
        #pragma unroll
        for (int r = 0; r < CRr; ++r) acc = fmaf(w2[(q * CN + c) * CRr + r], tl[r], acc);
        attv = sigf(acc);
    }
    __syncthreads();
    const float av = attv;
    const size_t ybase = (size_t)(qb * CN + c) * LL;
    const int xb = (b * CN + c) * 9216 + h0 * 96 + w0;
    for (int t = tid; t < LL / 8; t += 256) {
        int e0 = t * 8;
        int gi = xb + (e0 / 48) * 96 + (e0 % 48);
        uint4 yv = *reinterpret_cast<const uint4*>(&y_in[ybase + e0]);
        float yf[8]; unpack8(yv, yf);
        float4 xa = *reinterpret_cast<const float4*>(&x[gi]);
        float4 xc = *reinterpret_cast<const float4*>(&x[gi + 4]);
        float4 o0 = {xa.x + yf[0]*av, xa.y + yf[1]*av, xa.z + yf[2]*av, xa.w + yf[3]*av};
        float4 o1 = {xc.x + yf[4]*av, xc.y + yf[5]*av, xc.z + yf[6]*av, xc.w + yf[7]*av};
        *reinterpret_cast<float4*>(&out[gi])     = o0;
        *reinterpret_cast<float4*>(&out[gi + 4]) = o1;
    }
}

// ============================================================================
extern "C" void kernel_launch(void* const* d_in, const int* in_sizes, int n_in,
                              void* d_out, int out_size, void* d_ws, size_t ws_size,
                              hipStream_t stream)
{
    (void)in_sizes; (void)n_in; (void)out_size; (void)ws_size;
    const float* x       = (const float*)d_in[0];
    const float* ln_g    = (const float*)d_in[1];
    const float* ln_b    = (const float*)d_in[2];
    const float* p1_w    = (const float*)d_in[3];
    const float* p1_b    = (const float*)d_in[4];
    const float* p2in_w  = (const float*)d_in[5];
    const float* p2in_b  = (const float*)d_in[6];
    const float* dw_w    = (const float*)d_in[7];
    const float* dw_b    = (const float*)d_in[8];
    const float* xproj_w = (const float*)d_in[9];
    const float* dtproj_w= (const float*)d_in[10];
    const float* dtproj_b= (const float*)d_in[11];
    const float* A_logs  = (const float*)d_in[12];
    const float* Ds      = (const float*)d_in[13];
    const float* ssln_g  = (const float*)d_in[14];
    const float* ssln_b  = (const float*)d_in[15];
    const float* p2n_g   = (const float*)d_in[16];
    const float* p2n_b   = (const float*)d_in[17];
    const float* ca_w1   = (const float*)d_in[18];
    const float* ca_b1   = (const float*)d_in[19];
    const float* ca_w2   = (const float*)d_in[20];
    const float* ca_b2   = (const float*)d_in[21];
    const int*  bidx     = (const int*)d_in[22];
    float* out = (float*)d_out;

    char* ws = (char*)d_ws;
    const size_t off_a    = 0;                                  // bf16, live K1->K5
    const size_t off_zt   = 28311552;                           // bf16, live K2->K4
    const size_t off_ztT  = 56623104;                           // bf16, live K2->K4
    const size_t off_xdbl = 84934656;                           // bf16, live K3->K4
    const size_t off_ys   = 110886912;                          // bf16, live K4->K4b
    const size_t off_z0   = off_ys;                             // bf16 alias (dead before ys)
    const size_t off_s    = off_zt;                             // bf16 alias: sum tensor (K4b->K5)
    const size_t off_y    = off_ztT;                            // bf16 alias: gated y (K5->K7)
    const size_t off_sb   = 224133120;                          // fp32 attention sums

    bf16*  a_buf   = (bf16*)(ws + off_a);
    bf16*  zt_buf  = (bf16*)(ws + off_zt);
    bf16*  ztT_buf = (bf16*)(ws + off_ztT);
    bf16*  xdbl_buf= (bf16*)(ws + off_xdbl);
    bf16*  ys_buf  = (bf16*)(ws + off_ys);
    bf16*  z0_buf  = (bf16*)(ws + off_z0);
    bf16*  s_sum   = (bf16*)(ws + off_s);
    bf16*  y_buf   = (bf16*)(ws + off_y);
    float* s_buf   = (float*)(ws + off_sb);

    (void)hipMemsetAsync(ws + off_sb, 0, 24576, stream);

    k_lnconv<<<dim3(24, 16, 4), 192, 0, stream>>>(
        x, ln_g, ln_b, p1_w, p1_b, p2in_w, p2in_b, a_buf, z0_buf);
    k_dwconv<<<dim3(96, 16, 4), 256, 0, stream>>>(
        z0_buf, dw_w, dw_b, bidx, zt_buf, ztT_buf);
    k_xdbl<<<dim3(12, 4, 64), 256, 0, stream>>>(
        zt_buf, ztT_buf, xproj_w, xdbl_buf);
    k_scan<<<dim3(512), 384, 0, stream>>>(
        zt_buf, ztT_buf, xdbl_buf, dtproj_w, dtproj_b, A_logs, Ds, ys_buf);
    k_sum<<<dim3(96, 16, 4), 256, 0, stream>>>(
        ys_buf, s_sum);
    k_combine<<<dim3(48, 16, 4), 256, 0, stream>>>(
        s_sum, a_buf, ssln_g, ssln_b, p2n_g, p2n_b, bidx, y_buf, s_buf);
    k_final<<<dim3(96, 16, 4), 256, 0, stream>>>(
        x, y_buf, s_buf, ca_w1, ca_b1, ca_w2, ca_b2, out);
}

// Round 9
// 630.049 us; speedup vs baseline: 1.1694x; 1.0043x over previous
//
#include <hip/hip_runtime.h>
#include <hip/hip_bf16.h>

// ---- problem constants ----
#define BQ 16      // batch
#define CN 96      // channels
#define HQ 48      // quadrant H = W
#define LL 2304    // HQ*HQ
#define NK 4       // scan directions
#define RR 6       // dt rank
#define NNS 8      // state size
#define DPJ 22     // R + 2N
#define CRr 12     // attention rank
#define LOG2E 1.4426950408889634f

using bf16 = __hip_bfloat16;

typedef __attribute__((ext_vector_type(8))) short bf16x8;   // 8 bf16 (4 VGPRs)
typedef __attribute__((ext_vector_type(4))) float f32x4;    // 4 fp32 acc

__device__ __forceinline__ float b2f(bf16 v) { return __bfloat162float(v); }
__device__ __forceinline__ bf16  f2b(float v){ return __float2bfloat16(v); }
__device__ __forceinline__ float bflo(unsigned u){ return __uint_as_float(u << 16); }
__device__ __forceinline__ float bfhi(unsigned u){ return __uint_as_float(u & 0xffff0000u); }
__device__ __forceinline__ float sigf(float x){ return 1.f / (1.f + __expf(-x)); }
__device__ __forceinline__ float siluf(float x){ return x / (1.f + __expf(-x)); }
__device__ __forceinline__ unsigned packbf(float a, float b){
    unsigned lo = (unsigned)__builtin_bit_cast(unsigned short, f2b(a));
    unsigned hi = (unsigned)__builtin_bit_cast(unsigned short, f2b(b));
    return lo | (hi << 16);
}
__device__ __forceinline__ unsigned rot16(unsigned u){ return (u >> 16) | (u << 16); }
__device__ __forceinline__ void unpack8(uint4 v, float* f){
    f[0]=bflo(v.x); f[1]=bfhi(v.x); f[2]=bflo(v.y); f[3]=bfhi(v.y);
    f[4]=bflo(v.z); f[5]=bfhi(v.z); f[6]=bflo(v.w); f[7]=bfhi(v.w);
}
__device__ __forceinline__ void unpack4(uint2 v, float* f){
    f[0]=bflo(v.x); f[1]=bfhi(v.x); f[2]=bflo(v.y); f[3]=bfhi(v.y);
}
__device__ __forceinline__ float fexp2(float x){
#if __has_builtin(__builtin_amdgcn_exp2f)
    return __builtin_amdgcn_exp2f(x);
#else
    return __expf(x * 0.6931471805599453f);
#endif
}
// quad_perm DPP xor within groups of 4 lanes (VALU pipe, no LDS)
__device__ __forceinline__ float qxor(float v, int ctrl_b1){
    int x;
    if (ctrl_b1) x = __builtin_amdgcn_mov_dpp(__float_as_int(v), 0xB1, 0xF, 0xF, true);
    else         x = __builtin_amdgcn_mov_dpp(__float_as_int(v), 0x4E, 0xF, 0xF, true);
    return __int_as_float(x);
}

// ============================================================================
// K1: channel LN + conv1x1 via MFMA (a-branch silu, z-branch raw -> bf16)
// grid (24, 16, 4) = (hh-pair, b, q), block 192 = 3 waves
// Verified R8: 729->633 us total. Unchanged this round.
// ============================================================================
__global__ __launch_bounds__(192) void k_lnconv(
    const float* __restrict__ x, const float* __restrict__ ln_g, const float* __restrict__ ln_b,
    const float* __restrict__ p1w, const float* __restrict__ p1b,
    const float* __restrict__ p2w, const float* __restrict__ p2b,
    bf16* __restrict__ a_out, bf16* __restrict__ z0_out)
{
    const int hh2 = blockIdx.x;           // 0..23 (covers 2 rows each)
    const int b = blockIdx.y, q = blockIdx.z;
    const int h0 = (q >> 1) * HQ, w0 = (q & 1) * HQ;
    const int tid = threadIdx.x;
    const int qb = q * BQ + b;

    __shared__ alignas(16) bf16 wl2[192 * 104];   // [row][k]
    __shared__ alignas(16) bf16 hn2[96 * 104];    // [p][c]
    __shared__ float mu[96], rs[96];
    __shared__ float pmu[192], pv2[192];
    __shared__ float biasLds[192];
    __shared__ float gl[96], bl[96];

    // stage weights [row][k] bf16: rows 0-95 = p1 (a), 96-191 = p2 (z)
    for (int t = tid; t < 192 * 24; t += 192) {
        int row = t / 24, c4 = (t % 24) * 4;
        const float* srcw = (row < 96) ? &p1w[(q * CN + row) * CN + c4]
                                       : &p2w[(q * CN + (row - 96)) * CN + c4];
        float4 wv = *reinterpret_cast<const float4*>(srcw);
        uint2 pk; pk.x = packbf(wv.x, wv.y); pk.y = packbf(wv.z, wv.w);
        *reinterpret_cast<uint2*>(&wl2[row * 104 + c4]) = pk;
    }
    if (tid < 192)
        biasLds[tid] = (tid < 96) ? p1b[q * CN + tid] : p2b[q * CN + (tid - 96)];
    if (tid < 96) { gl[tid] = ln_g[q * CN + tid]; bl[tid] = ln_b[q * CN + tid]; }
    // stage x tile TRANSPOSED to [p][c]
    for (int t = tid; t < CN * 24; t += 192) {
        int c = t / 24, v = t % 24;
        int row = v / 12, col = (v % 12) * 4;
        int p = row * 48 + col;
        float4 xv = *reinterpret_cast<const float4*>(
            &x[((b * CN + c) * 96 + h0 + 2 * hh2 + row) * 96 + w0 + col]);
        hn2[p * 104 + c]       = f2b(xv.x);
        hn2[(p + 1) * 104 + c] = f2b(xv.y);
        hn2[(p + 2) * 104 + c] = f2b(xv.z);
        hn2[(p + 3) * 104 + c] = f2b(xv.w);
    }
    __syncthreads();
    // LN stats: 192 thr = 96 pos x 2 halves of 48 ch (vectorized)
    {
        int p = tid % 96, half = tid / 96;
        const bf16* hp = &hn2[p * 104 + half * 48];
        float s = 0.f, s2 = 0.f;
        #pragma unroll
        for (int c8 = 0; c8 < 48; c8 += 8) {
            float f[8]; unpack8(*reinterpret_cast<const uint4*>(hp + c8), f);
            #pragma unroll
            for (int i = 0; i < 8; ++i) { s += f[i]; s2 += f[i] * f[i]; }
        }
        pmu[half * 96 + p] = s; pv2[half * 96 + p] = s2;
    }
    __syncthreads();
    if (tid < 96) {
        float s = pmu[tid] + pmu[96 + tid];
        float s2 = pv2[tid] + pv2[96 + tid];
        float m = s * (1.f / 96.f);
        float var = s2 * (1.f / 96.f) - m * m;
        mu[tid] = m; rs[tid] = rsqrtf(var + 1e-6f);
    }
    __syncthreads();
    // normalize in place: 96 pos x 12 octets
    for (int t = tid; t < 96 * 12; t += 192) {
        int p = t / 12, c8 = (t % 12) * 8;
        float f[8]; unpack8(*reinterpret_cast<const uint4*>(&hn2[p * 104 + c8]), f);
        float m = mu[p], r = rs[p];
        unsigned ou[4];
        #pragma unroll
        for (int i = 0; i < 8; i += 2) {
            float v0 = (f[i]     - m) * r * gl[c8 + i]     + bl[c8 + i];
            float v1 = (f[i + 1] - m) * r * gl[c8 + i + 1] + bl[c8 + i + 1];
            ou[i >> 1] = packbf(v0, v1);
        }
        uint4 ov; ov.x = ou[0]; ov.y = ou[1]; ov.z = ou[2]; ov.w = ou[3];
        *reinterpret_cast<uint4*>(&hn2[p * 104 + c8]) = ov;
    }
    __syncthreads();
    // MFMA: wave w owns M rows [w*64, w*64+64) = 4 M-tiles x 6 N-tiles
    const int w = tid >> 6;
    const int l = tid & 63;
    const int lr = l & 15;          // M row / N col within tile
    const int lq = l >> 4;          // quarter: k-block for A/B, row-block for D
    f32x4 acc[4][6];
    #pragma unroll
    for (int m = 0; m < 4; ++m)
        #pragma unroll
        for (int n = 0; n < 6; ++n)
            acc[m][n] = (f32x4){0.f, 0.f, 0.f, 0.f};
    #pragma unroll
    for (int k0 = 0; k0 < 96; k0 += 32) {
        bf16x8 afr[4], bfr[6];
        #pragma unroll
        for (int m = 0; m < 4; ++m)
            afr[m] = *reinterpret_cast<const bf16x8*>(
                &wl2[(w * 64 + m * 16 + lr) * 104 + k0 + lq * 8]);
        #pragma unroll
        for (int n = 0; n < 6; ++n)
            bfr[n] = *reinterpret_cast<const bf16x8*>(
                &hn2[(n * 16 + lr) * 104 + k0 + lq * 8]);
        #pragma unroll
        for (int m = 0; m < 4; ++m)
            #pragma unroll
            for (int n = 0; n < 6; ++n)
                acc[m][n] = __builtin_amdgcn_mfma_f32_16x16x32_bf16(
                    afr[m], bfr[n], acc[m][n], 0, 0, 0);
    }
    // epilogue: bias + (silu for a-rows) + bf16 store
    #pragma unroll
    for (int m = 0; m < 4; ++m) {
        const int Rbase = w * 64 + m * 16 + lq * 4;
        #pragma unroll
        for (int n = 0; n < 6; ++n) {
            const int col = n * 16 + lr;
            const int colin = (col >= 48) ? (col - 48) : col;       // col % 48 (48 != pow2!)
            const int lbase = (2 * hh2 + (col >= 48 ? 1 : 0)) * 48 + colin;
            #pragma unroll
            for (int r = 0; r < 4; ++r) {
                const int R = Rbase + r;
                const bool isA = R < 96;
                const int d = isA ? R : R - 96;
                float v = acc[m][n][r] + biasLds[R];
                if (isA) v = siluf(v);
                bf16* dst = isA ? a_out : z0_out;
                dst[(size_t)(qb * CN + d) * LL + lbase] = f2b(v);
            }
        }
    }
}

// ============================================================================
// K2: depthwise 3x3 SAME + bias + silu + block_idx transform (bf16 in/out)
// grid (96, 16, 4) = (c, b, q), block 256
// ============================================================================
__global__ __launch_bounds__(256) void k_dwconv(
    const bf16* __restrict__ z0, const float* __restrict__ dww, const float* __restrict__ dwb,
    const int* __restrict__ bidx, bf16* __restrict__ zt, bf16* __restrict__ ztT)
{
    const int c = blockIdx.x, b = blockIdx.y, q = blockIdx.z;
    const int tid = threadIdx.x;
    const int base = ((q * BQ + b) * CN + c) * LL;
    __shared__ float zin[50 * 50];  // 1-elem zero border
    __shared__ float zo[48 * 49];   // padded rows: conflict-free transposed reads
    // zero the border (196 cells, disjoint from interior staging)
    if (tid < 196) {
        int idx;
        if (tid < 50)       idx = tid;                    // row 0
        else if (tid < 100) idx = 49 * 50 + (tid - 50);   // row 49
        else if (tid < 148) idx = (tid - 99) * 50;        // col 0, rows 1..48
        else                idx = (tid - 147) * 50 + 49;  // col 49, rows 1..48
        zin[idx] = 0.f;
    }
    for (int t = tid; t < 288; t += 256) {
        uint4 v = *reinterpret_cast<const uint4*>(&z0[base + t * 8]);
        float f[8]; unpack8(v, f);
        int e0 = t * 8, row = e0 / 48, col = e0 % 48;
        float* dst = &zin[(row + 1) * 50 + col + 1];
        #pragma unroll
        for (int i = 0; i < 8; ++i) dst[i] = f[i];
    }
    float wk[9];
    #pragma unroll
    for (int i = 0; i < 9; ++i) wk[i] = dww[(q * CN + c) * 9 + i];
    const float bias = dwb[q * CN + c];
    __syncthreads();
    for (int t = tid; t < LL; t += 256) {
        int hh = t / 48, ww = t % 48;
        const float* z0r = &zin[hh * 50 + ww];        // top-left tap
        float s = bias;
        s = fmaf(wk[0], z0r[0],        s);
        s = fmaf(wk[1], z0r[1],        s);
        s = fmaf(wk[2], z0r[2],        s);
        s = fmaf(wk[3], z0r[50],       s);
        s = fmaf(wk[4], z0r[51],       s);
        s = fmaf(wk[5], z0r[52],       s);
        s = fmaf(wk[6], z0r[100],      s);
        s = fmaf(wk[7], z0r[101],      s);
        s = fmaf(wk[8], z0r[102],      s);
        zo[hh * 49 + ww] = siluf(s);
    }
    __syncthreads();
    const bool even = ((bidx[0] & 1) == 0);
    for (int t = tid; t < LL; t += 256) {
        int i = t / 48, j = t % 48;
        float vz, vzT;
        if (even) { vz = zo[j * 49 + i];               vzT = zo[i * 49 + j]; }
        else      { vz = zo[(47 - i) * 49 + (47 - j)]; vzT = zo[(47 - j) * 49 + (47 - i)]; }
        zt[base + t]  = f2b(vz);
        ztT[base + t] = f2b(vzT);
    }
}

// ============================================================================
// K3: x_dbl = xproj_w @ u_k via MFMA (direction mapping + reversal folded in)
// grid (12, 4, 64) = (l-tile, k, q*16+b), block 256 = 4 waves
// R9: VALU matvec -> v_mfma_f32_16x16x32_bf16.
//   Per block: D[22 d][192 l] = W[22][96k] x U[96k][192 l].
//   M=22 pad 32 (2 tiles), N=192 (12 tiles, 3/wave), K=96 (3 steps) =
//   18 MFMA/wave. wl3 [d][k] pad 104 (rows 22-31 zeroed); ub [l][c] pad 104,
//   staged transposed (K1-proven scatter pattern). D: col=lane&15,
//   row=(lane>>4)*4+reg; store guarded d < 22.
// ============================================================================
__global__ __launch_bounds__(256) void k_xdbl(
    const bf16* __restrict__ zt, const bf16* __restrict__ ztT,
    const float* __restrict__ xprojw, bf16* __restrict__ xdbl)
{
    const int lt = blockIdx.x, k = blockIdx.y, qb = blockIdx.z;
    const int tid = threadIdx.x;
    const int l0 = lt * 192;
    const int q = qb >> 4;
    __shared__ alignas(16) bf16 ub[192 * 104];    // [l][c]
    __shared__ alignas(16) bf16 wl3[32 * 104];    // [d][c], rows 22-31 zero
    const bf16* __restrict__ src = (k & 1) ? ztT : zt;
    const bool rev = (k >= 2);

    // zero pad rows 22..31 of wl3 (10*104 bf16 = 520 dwords; offset 22*104 even)
    for (int t = tid; t < 520; t += 256)
        reinterpret_cast<unsigned*>(&wl3[22 * 104])[t] = 0u;
    // stage weights [d][c] bf16 (global fp32 [d][c] row-major)
    for (int t = tid; t < DPJ * 24; t += 256) {
        int d = t / 24, c4 = (t % 24) * 4;
        float4 wv = *reinterpret_cast<const float4*>(
            &xprojw[((q * NK + k) * DPJ + d) * CN + c4]);
        uint2 pk; pk.x = packbf(wv.x, wv.y); pk.y = packbf(wv.z, wv.w);
        *reinterpret_cast<uint2*>(&wl3[d * 104 + c4]) = pk;
    }
    // stage u TRANSPOSED [l][c] with direction mapping (coalesced global reads)
    for (int t = tid; t < CN * 24; t += 256) {
        int cc = t / 24, j0 = (t % 24) * 8;
        uint4 v;
        if (!rev) {
            v = *reinterpret_cast<const uint4*>(&src[(size_t)(qb * CN + cc) * LL + l0 + j0]);
        } else {
            v = *reinterpret_cast<const uint4*>(&src[(size_t)(qb * CN + cc) * LL + (LL - (l0 + j0) - 8)]);
            uint4 r; r.x = rot16(v.w); r.y = rot16(v.z); r.z = rot16(v.y); r.w = rot16(v.x);
            v = r;
        }
        const unsigned short* ev = reinterpret_cast<const unsigned short*>(&v);
        unsigned short* ubs = reinterpret_cast<unsigned short*>(ub);
        #pragma unroll
        for (int i = 0; i < 8; ++i) ubs[(j0 + i) * 104 + cc] = ev[i];
    }
    __syncthreads();
    // MFMA: wave w owns N-tiles 3w..3w+2; M-tiles 0 (d 0-15) and 1 (d 16-21+pad)
    const int w = tid >> 6;
    const int l = tid & 63;
    const int lr = l & 15;          // M row / N col within tile
    const int lq = l >> 4;          // quarter: k-block for A/B, row-block for D
    f32x4 acc[2][3];
    #pragma unroll
    for (int m = 0; m < 2; ++m)
        #pragma unroll
        for (int n = 0; n < 3; ++n)
            acc[m][n] = (f32x4){0.f, 0.f, 0.f, 0.f};
    #pragma unroll
    for (int k0 = 0; k0 < 96; k0 += 32) {
        bf16x8 afr[2], bfr[3];
        #pragma unroll
        for (int m = 0; m < 2; ++m)
            afr[m] = *reinterpret_cast<const bf16x8*>(
                &wl3[(m * 16 + lr) * 104 + k0 + lq * 8]);
        #pragma unroll
        for (int n = 0; n < 3; ++n)
            bfr[n] = *reinterpret_cast<const bf16x8*>(
                &ub[((w * 3 + n) * 16 + lr) * 104 + k0 + lq * 8]);
        #pragma unroll
        for (int m = 0; m < 2; ++m)
            #pragma unroll
            for (int n = 0; n < 3; ++n)
                acc[m][n] = __builtin_amdgcn_mfma_f32_16x16x32_bf16(
                    afr[m], bfr[n], acc[m][n], 0, 0, 0);
    }
    // store: D row = m*16 + lq*4 + r (guard < 22), col = l0 + (w*3+n)*16 + lr
    const size_t obase = (size_t)(qb * NK + k) * (DPJ * LL);
    #pragma unroll
    for (int m = 0; m < 2; ++m) {
        #pragma unroll
        for (int n = 0; n < 3; ++n) {
            const int lpos = l0 + (w * 3 + n) * 16 + lr;
            #pragma unroll
            for (int r = 0; r < 4; ++r) {
                const int d = m * 16 + lq * 4 + r;
                if (d < DPJ)
                    xdbl[obase + (size_t)d * LL + lpos] = f2b(acc[m][n][r]);
            }
        }
    }
}

// ============================================================================
// K4: fused delta(softplus) + selective scan + Ds*u term
// grid (512), block 384 producer/consumer — UNCHANGED (anchor, 262 us warm)
// ============================================================================

// raw barrier: drain LDS (cross-wave visibility of ds_writes) but NOT vmcnt
#define SCAN_BARRIER() asm volatile("s_waitcnt lgkmcnt(0)\n\ts_barrier" ::: "memory")

// word IDX (0..23) of a 6-uint4 register array holding 48 bf16
#define UWORD(NUA, IDX) (((IDX) & 3) == 0 ? NUA[(IDX) >> 2].x : \
                         ((IDX) & 3) == 1 ? NUA[(IDX) >> 2].y : \
                         ((IDX) & 3) == 2 ? NUA[(IDX) >> 2].z : NUA[(IDX) >> 2].w)

#define ROT3(v) (v) = ((v) == 2) ? 0 : ((v) + 1)

__global__ __launch_bounds__(384) void k_scan(
    const bf16* __restrict__ zt, const bf16* __restrict__ ztT,
    const bf16* __restrict__ xdbl,
    const float* __restrict__ dtw_g, const float* __restrict__ dtb_g,
    const float* __restrict__ Alog_g, const float* __restrict__ Ds_g,
    bf16* __restrict__ ys)
{
    const int bid = blockIdx.x;
    const int ch2 = bid & 1, k = (bid >> 1) & 3, qb = bid >> 3, q = qb >> 4;
    const int qk = q * NK + k;
    const int tid = threadIdx.x;
    const bool isScan = (tid < 192);
    const int lt = isScan ? tid : (tid - 192);   // role-local 0..191
    const int ca = lt >> 2, p = lt & 3;
    const int c = ch2 * 48 + ca;          // global channel

    __shared__ float dd3[3][48 * 52];
    __shared__ float xr3[3][6 * 52];          // dts rows
    __shared__ float bcv3[3][48 * 16];        // [j][p*4 + {B0,B1,C0,C1}]

    const bf16* __restrict__ src = (k & 1) ? ztT : zt;
    const bool rev = (k >= 2);
    const int ja = p * 12;

    // ---- producer-role parameters ----
    float wdt[6] = {0.f, 0.f, 0.f, 0.f, 0.f, 0.f};
    float dtbc = 0.f;
    if (!isScan) {
        const float* wp = dtw_g + (size_t)qk * CN * RR + c * RR;
        float2 wa = *reinterpret_cast<const float2*>(wp);
        float2 wb = *reinterpret_cast<const float2*>(wp + 2);
        float2 wc = *reinterpret_cast<const float2*>(wp + 4);
        wdt[0] = wa.x; wdt[1] = wa.y; wdt[2] = wb.x; wdt[3] = wb.y; wdt[4] = wc.x; wdt[5] = wc.y;
        dtbc = dtb_g[qk * CN + c];
    }
    // xdbl staging: producer threads with lt<132 stage one uint4 from row vr
    const bool xload = (!isScan) && (lt < 132);
    const int vr = lt / 6, jx = (lt % 6) * 8;
    const bf16* gx = xdbl + (size_t)(qb * NK + k) * (DPJ * LL) + (size_t)vr * LL + jx;
    int bccol = 0;
    if (vr >= 6) {
        int v = vr - 6;           // 0..15: 0-7 B, 8-15 C
        int n = v & 7;
        bccol = (n >> 1) * 4 + ((v >= 8) ? 2 : 0) + (n & 1);
    }

    // ---- scan-role parameters ----
    float A0L = 0.f, A1L = 0.f, Dc = 0.f;
    if (isScan) {
        A0L = -__expf(Alog_g[((size_t)qk * CN + c) * NNS + 2 * p])     * LOG2E;
        A1L = -__expf(Alog_g[((size_t)qk * CN + c) * NNS + 2 * p + 1]) * LOG2E;
        Dc = Ds_g[qk * CN + c];
    }
    float h0 = 0.f, h1 = 0.f;
    const bf16* gu = src + (size_t)(qb * CN + c) * LL + (rev ? (LL - 48) : 0);
    const int ustep = rev ? -48 : 48;
    bf16* yp = ys + (size_t)(qb * NK + k) * (CN * LL) + (size_t)c * LL;  // p==0 stores

    #define COMMIT_BLOCK(PXV, XRB, BCB) do {                                          \
        if (xload) {                                                                  \
            float g[8]; unpack8(PXV, g);                                              \
            if (vr < 6) {                                                             \
                *reinterpret_cast<float4*>(&(XRB)[vr * 52 + jx])                      \
                    = make_float4(g[0], g[1], g[2], g[3]);                            \
                *reinterpret_cast<float4*>(&(XRB)[vr * 52 + jx + 4])                  \
                    = make_float4(g[4], g[5], g[6], g[7]);                            \
            } else {                                                                  \
                _Pragma("unroll")                                                     \
                for (int i = 0; i < 8; ++i) (BCB)[(jx + i) * 16 + bccol] = g[i];      \
            }                                                                         \
        }                                                                             \
    } while (0)

    #define DELTA_BLOCK(XRB, DDB) do {                                                \
        float acc[12];                                                                \
        _Pragma("unroll")                                                             \
        for (int i = 0; i < 12; ++i) acc[i] = dtbc;                                   \
        _Pragma("unroll")                                                             \
        for (int r = 0; r < 6; ++r) {                                                 \
            float4 d0 = *reinterpret_cast<const float4*>(&(XRB)[r * 52 + ja]);        \
            float4 d1 = *reinterpret_cast<const float4*>(&(XRB)[r * 52 + ja + 4]);    \
            float4 d2 = *reinterpret_cast<const float4*>(&(XRB)[r * 52 + ja + 8]);    \
            float wr_ = wdt[r];                                                       \
            acc[0] = fmaf(wr_, d0.x, acc[0]);  acc[1] = fmaf(wr_, d0.y, acc[1]);      \
            acc[2] = fmaf(wr_, d0.z, acc[2]);  acc[3] = fmaf(wr_, d0.w, acc[3]);      \
            acc[4] = fmaf(wr_, d1.x, acc[4]);  acc[5] = fmaf(wr_, d1.y, acc[5]);      \
            acc[6] = fmaf(wr_, d1.z, acc[6]);  acc[7] = fmaf(wr_, d1.w, acc[7]);      \
            acc[8] = fmaf(wr_, d2.x, acc[8]);  acc[9] = fmaf(wr_, d2.y, acc[9]);      \
            acc[10] = fmaf(wr_, d2.z, acc[10]); acc[11] = fmaf(wr_, d2.w, acc[11]);   \
        }                                                                             \
        _Pragma("unroll")                                                             \
        for (int i = 0; i < 12; ++i) {                                                \
            float a = acc[i];                                                         \
            acc[i] = (a > 15.f) ? a : __logf(1.f + __expf(a));                        \
        }                                                                             \
        float4* dp = reinterpret_cast<float4*>(&(DDB)[ca * 52 + ja]);                 \
        dp[0] = make_float4(acc[0], acc[1], acc[2], acc[3]);                          \
        dp[1] = make_float4(acc[4], acc[5], acc[6], acc[7]);                          \
        dp[2] = make_float4(acc[8], acc[9], acc[10], acc[11]);                        \
    } while (0)

    // ---- prologue ----
    uint4 u_a[6], u_b[6];
    uint4 px_a = {0,0,0,0}, px_b = {0,0,0,0}, px1 = {0,0,0,0};
    if (isScan) {
        #pragma unroll
        for (int i = 0; i < 6; ++i) u_a[i] = *reinterpret_cast<const uint4*>(gu + i * 8);  // chunk 0
        gu += ustep;
        #pragma unroll
        for (int i = 0; i < 6; ++i) u_b[i] = *reinterpret_cast<const uint4*>(gu + i * 8);  // chunk 1
        gu += ustep;                                           // -> chunk 2
    } else {
        uint4 px0 = {0,0,0,0};
        if (xload) {
            px0  = *reinterpret_cast<const uint4*>(gx);        // chunk 0
            px1  = *reinterpret_cast<const uint4*>(gx + 48);   // chunk 1
            px_a = *reinterpret_cast<const uint4*>(gx + 96);   // chunk 2
            px_b = *reinterpret_cast<const uint4*>(gx + 144);  // chunk 3
            gx += 192;                                         // -> chunk 4
        }
        COMMIT_BLOCK(px0, xr3[0], bcv3[0]);
    }
    SCAN_BARRIER();
    if (!isScan) {
        DELTA_BLOCK(xr3[0], dd3[0]);
        COMMIT_BLOCK(px1, xr3[1], bcv3[1]);
    }
    SCAN_BARRIER();

    // buffer cursors
    int s_cur = 0;              // scan:  buf of chunk ch
    int d_idx = 1, c_idx = 2;   // prod:  delta buf (ch+1), commit buf (ch+2)

    #define PROD_BODY(CH, PX) do {                                                    \
        const int chp_ = (CH);                                                        \
        if (chp_ + 2 < 48) COMMIT_BLOCK(PX, xr3[c_idx], bcv3[c_idx]);                 \
        if (chp_ + 4 < 48 && xload) { PX = *reinterpret_cast<const uint4*>(gx); gx += 48; } \
        if (chp_ + 1 < 48) DELTA_BLOCK(xr3[d_idx], dd3[d_idx]);                       \
        ROT3(d_idx); ROT3(c_idx);                                                     \
    } while (0)

    #define SCAN_CHUNK(CH, UC) do {                                                   \
        const int ch_ = (CH);                                                         \
        uint4 nu[6];                                                                  \
        if (!rev) {                                                                   \
            nu[0] = UC[0]; nu[1] = UC[1]; nu[2] = UC[2];                              \
            nu[3] = UC[3]; nu[4] = UC[4]; nu[5] = UC[5];                              \
        } else {                                                                      \
            _Pragma("unroll")                                                         \
            for (int qq = 0; qq < 6; ++qq) {                                          \
                nu[qq].x = rot16(UC[5 - qq].w); nu[qq].y = rot16(UC[5 - qq].z);       \
                nu[qq].z = rot16(UC[5 - qq].y); nu[qq].w = rot16(UC[5 - qq].x);       \
            }                                                                         \
        }                                                                             \
        {                                                                             \
            const int l0 = ch_ * 48;                                                  \
            const float* ddc = &dd3[s_cur][ca * 52];                                  \
            const float* bcc = &bcv3[s_cur][p * 4];                                   \
            _Pragma("unroll")                                                         \
            for (int gg = 0; gg < 6; ++gg) {                                          \
                unsigned pk[4];                                                       \
                _Pragma("unroll")                                                     \
                for (int half = 0; half < 2; ++half) {                                \
                    const int j0 = gg * 8 + half * 4;                                 \
                    float4 d4 = *reinterpret_cast<const float4*>(ddc + j0);           \
                    const float* df = reinterpret_cast<const float*>(&d4);            \
                    _Pragma("unroll")                                                 \
                    for (int s = 0; s < 4; ++s) {                                     \
                        const int j = j0 + s;                                         \
                        const unsigned uwv = UWORD(nu, j >> 1);                       \
                        float u = (j & 1) ? bfhi(uwv) : bflo(uwv);                    \
                        float d = df[s];                                              \
                        float4 bq = *reinterpret_cast<const float4*>(bcc + j * 16);   \
                        float du = d * u;                                             \
                        float dA0 = fexp2(d * A0L);                                   \
                        float dA1 = fexp2(d * A1L);                                   \
                        h0 = fmaf(dA0, h0, du * bq.x);                                \
                        h1 = fmaf(dA1, h1, du * bq.y);                                \
                        float y = fmaf(h0, bq.z, h1 * bq.w);                          \
                        y += qxor(y, 1); y += qxor(y, 0);                             \
                        y = fmaf(Dc, u, y);                                           \
                        unsigned hb = (unsigned)__builtin_bit_cast(unsigned short, f2b(y)); \
                        const int sl = half * 4 + s;                                  \
                        if (sl & 1) pk[sl >> 1] |= hb << 16; else pk[sl >> 1] = hb;   \
                    }                                                                 \
                }                                                                     \
                if (p == 0) {                                                         \
                    uint4 wv4; wv4.x = pk[0]; wv4.y = pk[1]; wv4.z = pk[2]; wv4.w = pk[3]; \
                    *reinterpret_cast<uint4*>(yp + l0 + gg * 8) = wv4;                \
                }                                                                     \
            }                                                                         \
        }                                                                             \
        if (ch_ + 2 < 48) {                                                           \
            _Pragma("unroll")                                                         \
            for (int i = 0; i < 6; ++i) UC[i] = *reinterpret_cast<const uint4*>(gu + i * 8); \
            gu += ustep;                                                              \
        }                                                                             \
        ROT3(s_cur);                                                                  \
    } while (0)

    for (int t = 0; t < 24; ++t) {
        if (isScan) SCAN_CHUNK(2 * t, u_a);
        else        PROD_BODY(2 * t, px_a);
        SCAN_BARRIER();
        if (isScan) SCAN_CHUNK(2 * t + 1, u_b);
        else        PROD_BODY(2 * t + 1, px_b);
        SCAN_BARRIER();
    }

    #undef SCAN_CHUNK
    #undef PROD_BODY
    #undef DELTA_BLOCK
    #undef COMMIT_BLOCK
}

// ============================================================================
// K4b: k_sum — combine 4 directions into one tensor at combine-index m
// grid (96, 16, 4) = (c, b, q), block 256
// ============================================================================
__global__ __launch_bounds__(256) void k_sum(
    const bf16* __restrict__ ys, bf16* __restrict__ s_out)
{
    const int c = blockIdx.x, b = blockIdx.y, q = blockIdx.z;
    const int qb = q * BQ + b;
    const int tid = threadIdx.x;
    __shared__ float t0[48 * 49];
    __shared__ float t2[48 * 49];
    const size_t base0 = ((size_t)(qb * NK + 0) * CN + c) * LL;
    const size_t base1 = ((size_t)(qb * NK + 1) * CN + c) * LL;
    const size_t base2 = ((size_t)(qb * NK + 2) * CN + c) * LL;
    const size_t base3 = ((size_t)(qb * NK + 3) * CN + c) * LL;
    for (int idx = tid; idx < 288; idx += 256) {
        int e0 = idx * 8, h = e0 / 48, w = e0 % 48;
        float f[8];
        unpack8(*reinterpret_cast<const uint4*>(&ys[base0 + e0]), f);
        #pragma unroll
        for (int i = 0; i < 8; ++i) t0[h * 49 + w + i] = f[i];
        unpack8(*reinterpret_cast<const uint4*>(&ys[base2 + e0]), f);
        #pragma unroll
        for (int i = 0; i < 8; ++i) t2[h * 49 + w + i] = f[i];
    }
    __syncthreads();
    const size_t cbase = ((size_t)qb * CN + c) * LL;
    for (int idx = tid; idx < 288; idx += 256) {
        int m0 = idx * 8, ww = m0 / 48, hh = m0 % 48;
        float f1[8], f3[8];
        unpack8(*reinterpret_cast<const uint4*>(&ys[base1 + m0]), f1);
        unpack8(*reinterpret_cast<const uint4*>(&ys[base3 + (LL - 8 - m0)]), f3);
        float o[8];
        #pragma unroll
        for (int i = 0; i < 8; ++i) {
            float v0 = t0[(hh + i) * 49 + ww];
            float v2 = t2[(47 - hh - i) * 49 + (47 - ww)];
            o[i] = v0 + f1[i] + v2 + f3[7 - i];
        }
        uint4 w;
        w.x = packbf(o[0], o[1]); w.y = packbf(o[2], o[3]);
        w.z = packbf(o[4], o[5]); w.w = packbf(o[6], o[7]);
        *reinterpret_cast<uint4*>(&s_out[cbase + m0]) = w;
    }
}

// ============================================================================
// K5: combine: LN(ssln) + LN(p2n) + y=a*z + attention partial sums
// grid (48, 16, 4) = (ww, b, q), block 256
// ============================================================================
__global__ __launch_bounds__(256) void k_combine(
    const bf16* __restrict__ s_in, const bf16* __restrict__ a_in,
    const float* __restrict__ ssg, const float* __restrict__ ssb,
    const float* __restrict__ png, const float* __restrict__ pnb,
    const int* __restrict__ bidx,
    bf16* __restrict__ y_out, float* __restrict__ s_buf)
{
    const int ww = blockIdx.x, b = blockIdx.y, q = blockIdx.z;
    const int qb = q * BQ + b;
    const int tid = threadIdx.x;
    __shared__ float o[CN * 48];
    __shared__ float mu[48], rs[48];
    __shared__ float pp[192], pp2[192];
    for (int v = tid; v < 576; v += 256) {
        int e0 = v * 8, cc = e0 / 48, hh = e0 % 48;
        float f[8];
        unpack8(*reinterpret_cast<const uint4*>(&s_in[((size_t)qb * CN + cc) * LL + ww * 48 + hh]), f);
        #pragma unroll
        for (int i = 0; i < 8; ++i) o[cc * 48 + hh + i] = f[i];
    }
    __syncthreads();
    // stats phase 1: 192 threads = 48 hh x 4 parts of 24 ch
    if (tid < 192) {
        int hh = tid % 48, part = tid / 48;
        float s = 0.f, s2 = 0.f;
        int c0 = part * 24;
        for (int cc = c0; cc < c0 + 24; ++cc) { float v = o[cc * 48 + hh]; s += v; s2 += v * v; }
        pp[tid] = s; pp2[tid] = s2;
    }
    __syncthreads();
    if (tid < 48) {
        float s = pp[tid] + pp[tid + 48] + pp[tid + 96] + pp[tid + 144];
        float s2 = pp2[tid] + pp2[tid + 48] + pp2[tid + 96] + pp2[tid + 144];
        float m = s * (1.f / 96.f), var = s2 * (1.f / 96.f) - m * m;
        mu[tid] = m; rs[tid] = rsqrtf(var + 1e-6f);
    }
    __syncthreads();
    for (int t = tid; t < CN * 48; t += 256) {
        int cc = t / 48, hh = t % 48;
        o[t] = (o[t] - mu[hh]) * rs[hh] * ssg[q * CN + cc] + ssb[q * CN + cc];
    }
    __syncthreads();
    // stats phase 2
    if (tid < 192) {
        int hh = tid % 48, part = tid / 48;
        float s = 0.f, s2 = 0.f;
        int c0 = part * 24;
        for (int cc = c0; cc < c0 + 24; ++cc) { float v = o[cc * 48 + hh]; s += v; s2 += v * v; }
        pp[tid] = s; pp2[tid] = s2;
    }
    __syncthreads();
    if (tid < 48) {
        float s = pp[tid] + pp[tid + 48] + pp[tid + 96] + pp[tid + 144];
        float s2 = pp2[tid] + pp2[tid + 48] + pp2[tid + 96] + pp2[tid + 144];
        float m = s * (1.f / 96.f), var = s2 * (1.f / 96.f) - m * m;
        mu[tid] = m; rs[tid] = rsqrtf(var + 1e-6f);
    }
    __syncthreads();
    const bool even = ((bidx[0] & 1) == 0);
    if (even) {
        for (int v = tid; v < 576; v += 256) {
            int e0 = v * 8, cc = e0 / 48, hh = e0 % 48;
            size_t oidx = ((size_t)qb * CN + cc) * LL + ww * 48 + hh;
            float af[8];
            unpack8(*reinterpret_cast<const uint4*>(&a_in[oidx]), af);
            float yv[8];
            #pragma unroll
            for (int i = 0; i < 8; ++i) {
                float z2 = (o[cc * 48 + hh + i] - mu[hh + i]) * rs[hh + i] * png[q * CN + cc] + pnb[q * CN + cc];
                yv[i] = af[i] * z2;
                o[cc * 48 + hh + i] = yv[i];
            }
            uint4 w;
            w.x = packbf(yv[0], yv[1]); w.y = packbf(yv[2], yv[3]);
            w.z = packbf(yv[4], yv[5]); w.w = packbf(yv[6], yv[7]);
            *reinterpret_cast<uint4*>(&y_out[oidx]) = w;
        }
    } else {
        for (int t = tid; t < CN * 48; t += 256) {
            int cc = t / 48, hh = t % 48;
            float z2 = (o[t] - mu[hh]) * rs[hh] * png[q * CN + cc] + pnb[q * CN + cc];
            size_t oidx = ((size_t)qb * CN + cc) * LL + (47 - hh) * 48 + (47 - ww);
            float yv = b2f(a_in[oidx]) * z2;
            y_out[oidx] = f2b(yv);
            o[t] = yv;
        }
    }
    __syncthreads();
    if (tid < CN) {
        float s = 0.f;
        for (int j = 0; j < 48; ++j) s += o[tid * 48 + j];
        atomicAdd(&s_buf[qb * CN + tid], s);
    }
}

// ============================================================================
// K7: out = x + y * att  with channel attention computed in-block
// grid (96, 16, 4) = (c, b, q), block 256
// ============================================================================
__global__ __launch_bounds__(256) void k_final(
    const float* __restrict__ x, const bf16* __restrict__ y_in,
    const float* __restrict__ s_buf,
    const float* __restrict__ w1, const float* __restrict__ b1,
    const float* __restrict__ w2, const float* __restrict__ b2,
    float* __restrict__ out)
{
    const int c = blockIdx.x, b = blockIdx.y, q = blockIdx.z;
    const int h0 = (q >> 1) * HQ, w0 = (q & 1) * HQ;
    const int qb = q * BQ + b;
    const int tid = threadIdx.x;
    __shared__ float tl[CRr];
    __shared__ float tpart[16 * CRr];
    __shared__ float attv;
    if (tid < 192) {
        int r = tid % CRr, part = tid / CRr;   // 16 parts x 6 channels
        float acc = 0.f;
        const float* wr = w1 + (q * CRr + r) * CN;
        const float* sb = s_buf + qb * CN;
        int c0 = part * 6;
        for (int cc = c0; cc < c0 + 6; ++cc)
            acc = fmaf(wr[cc], sb[cc] * (1.f / (float)LL), acc);
        tpart[part * CRr + r] = acc;
    }
    __syncthreads();
    if (tid < CRr) {
        float acc = b1[q * CRr + tid];
        #pragma unroll
        for (int pt = 0; pt < 16; ++pt) acc += tpart[pt * CRr + tid];
        tl[tid] = siluf(acc);
    }
    __syncthreads();
    if (tid == 0) {
        float acc = b2[q * CN + c];
        #pragma unroll
        for (int r = 0; r < CRr; ++r) acc = fmaf(w2[(q * CN + c) * CRr + r], tl[r], acc);
        attv = sigf(acc);
    }
    __syncthreads();
    const float av = attv;
    const size_t ybase = (size_t)(qb * CN + c) * LL;
    const int xb = (b * CN + c) * 9216 + h0 * 96 + w0;
    for (int t = tid; t < LL / 8; t += 256) {
        int e0 = t * 8;
        int gi = xb + (e0 / 48) * 96 + (e0 % 48);
        uint4 yv = *reinterpret_cast<const uint4*>(&y_in[ybase + e0]);
        float yf[8]; unpack8(yv, yf);
        float4 xa = *reinterpret_cast<const float4*>(&x[gi]);
        float4 xc = *reinterpret_cast<const float4*>(&x[gi + 4]);
        float4 o0 = {xa.x + yf[0]*av, xa.y + yf[1]*av, xa.z + yf[2]*av, xa.w + yf[3]*av};
        float4 o1 = {xc.x + yf[4]*av, xc.y + yf[5]*av, xc.z + yf[6]*av, xc.w + yf[7]*av};
        *reinterpret_cast<float4*>(&out[gi])     = o0;
        *reinterpret_cast<float4*>(&out[gi + 4]) = o1;
    }
}

// ============================================================================
extern "C" void kernel_launch(void* const* d_in, const int* in_sizes, int n_in,
                              void* d_out, int out_size, void* d_ws, size_t ws_size,
                              hipStream_t stream)
{
    (void)in_sizes; (void)n_in; (void)out_size; (void)ws_size;
    const float* x       = (const float*)d_in[0];
    const float* ln_g    = (const float*)d_in[1];
    const float* ln_b    = (const float*)d_in[2];
    const float* p1_w    = (const float*)d_in[3];
    const float* p1_b    = (const float*)d_in[4];
    const float* p2in_w  = (const float*)d_in[5];
    const float* p2in_b  = (const float*)d_in[6];
    const float* dw_w    = (const float*)d_in[7];
    const float* dw_b    = (const float*)d_in[8];
    const float* xproj_w = (const float*)d_in[9];
    const float* dtproj_w= (const float*)d_in[10];
    const float* dtproj_b= (const float*)d_in[11];
    const float* A_logs  = (const float*)d_in[12];
    const float* Ds      = (const float*)d_in[13];
    const float* ssln_g  = (const float*)d_in[14];
    const float* ssln_b  = (const float*)d_in[15];
    const float* p2n_g   = (const float*)d_in[16];
    const float* p2n_b   = (const float*)d_in[17];
    const float* ca_w1   = (const float*)d_in[18];
    const float* ca_b1   = (const float*)d_in[19];
    const float* ca_w2   = (const float*)d_in[20];
    const float* ca_b2   = (const float*)d_in[21];
    const int*  bidx     = (const int*)d_in[22];
    float* out = (float*)d_out;

    char* ws = (char*)d_ws;
    const size_t off_a    = 0;                                  // bf16, live K1->K5
    const size_t off_zt   = 28311552;                           // bf16, live K2->K4
    const size_t off_ztT  = 56623104;                           // bf16, live K2->K4
    const size_t off_xdbl = 84934656;                           // bf16, live K3->K4
    const size_t off_ys   = 110886912;                          // bf16, live K4->K4b
    const size_t off_z0   = off_ys;                             // bf16 alias (dead before ys)
    const size_t off_s    = off_zt;                             // bf16 alias: sum tensor (K4b->K5)
    const size_t off_y    = off_ztT;                            // bf16 alias: gated y (K5->K7)
    const size_t off_sb   = 224133120;                          // fp32 attention sums

    bf16*  a_buf   = (bf16*)(ws + off_a);
    bf16*  zt_buf  = (bf16*)(ws + off_zt);
    bf16*  ztT_buf = (bf16*)(ws + off_ztT);
    bf16*  xdbl_buf= (bf16*)(ws + off_xdbl);
    bf16*  ys_buf  = (bf16*)(ws + off_ys);
    bf16*  z0_buf  = (bf16*)(ws + off_z0);
    bf16*  s_sum   = (bf16*)(ws + off_s);
    bf16*  y_buf   = (bf16*)(ws + off_y);
    float* s_buf   = (float*)(ws + off_sb);

    (void)hipMemsetAsync(ws + off_sb, 0, 24576, stream);

    k_lnconv<<<dim3(24, 16, 4), 192, 0, stream>>>(
        x, ln_g, ln_b, p1_w, p1_b, p2in_w, p2in_b, a_buf, z0_buf);
    k_dwconv<<<dim3(96, 16, 4), 256, 0, stream>>>(
        z0_buf, dw_w, dw_b, bidx, zt_buf, ztT_buf);
    k_xdbl<<<dim3(12, 4, 64), 256, 0, stream>>>(
        zt_buf, ztT_buf, xproj_w, xdbl_buf);
    k_scan<<<dim3(512), 384, 0, stream>>>(
        zt_buf, ztT_buf, xdbl_buf, dtproj_w, dtproj_b, A_logs, Ds, ys_buf);
    k_sum<<<dim3(96, 16, 4), 256, 0, stream>>>(
        ys_buf, s_sum);
    k_combine<<<dim3(48, 16, 4), 256, 0, stream>>>(
        s_sum, a_buf, ssln_g, ssln_b, p2n_g, p2n_b, bidx, y_buf, s_buf);
    k_final<<<dim3(96, 16, 4), 256, 0, stream>>>(
        x, y_buf, s_buf, ca_w1, ca_b1, ca_w2, ca_b2, out);
}

// Round 11
// 604.762 us; speedup vs baseline: 1.2183x; 1.0418x over previous
//
#include <hip/hip_runtime.h>
#include <hip/hip_bf16.h>

// ---- problem constants ----
#define BQ 16      // batch
#define CN 96      // channels
#define HQ 48      // quadrant H = W
#define LL 2304    // HQ*HQ
#define NK 4       // scan directions
#define RR 6       // dt rank
#define NNS 8      // state size
#define DPJ 22     // R + 2N
#define CRr 12     // attention rank
#define LOG2E 1.4426950408889634f

using bf16 = __hip_bfloat16;

typedef __attribute__((ext_vector_type(8))) short bf16x8;   // 8 bf16 (4 VGPRs)
typedef __attribute__((ext_vector_type(4))) float f32x4;    // 4 fp32 acc

__device__ __forceinline__ float b2f(bf16 v) { return __bfloat162float(v); }
__device__ __forceinline__ bf16  f2b(float v){ return __float2bfloat16(v); }
__device__ __forceinline__ float bflo(unsigned u){ return __uint_as_float(u << 16); }
__device__ __forceinline__ float bfhi(unsigned u){ return __uint_as_float(u & 0xffff0000u); }
__device__ __forceinline__ float sigf(float x){ return 1.f / (1.f + __expf(-x)); }
__device__ __forceinline__ float siluf(float x){ return x / (1.f + __expf(-x)); }
__device__ __forceinline__ unsigned packbf(float a, float b){
    unsigned lo = (unsigned)__builtin_bit_cast(unsigned short, f2b(a));
    unsigned hi = (unsigned)__builtin_bit_cast(unsigned short, f2b(b));
    return lo | (hi << 16);
}
__device__ __forceinline__ unsigned rot16(unsigned u){ return (u >> 16) | (u << 16); }
__device__ __forceinline__ void unpack8(uint4 v, float* f){
    f[0]=bflo(v.x); f[1]=bfhi(v.x); f[2]=bflo(v.y); f[3]=bfhi(v.y);
    f[4]=bflo(v.z); f[5]=bfhi(v.z); f[6]=bflo(v.w); f[7]=bfhi(v.w);
}
__device__ __forceinline__ void unpack4(uint2 v, float* f){
    f[0]=bflo(v.x); f[1]=bfhi(v.x); f[2]=bflo(v.y); f[3]=bfhi(v.y);
}
__device__ __forceinline__ float fexp2(float x){
#if __has_builtin(__builtin_amdgcn_exp2f)
    return __builtin_amdgcn_exp2f(x);
#else
    return __expf(x * 0.6931471805599453f);
#endif
}
// quad_perm DPP xor within groups of 4 lanes (VALU pipe, no LDS)
__device__ __forceinline__ float qxor(float v, int ctrl_b1){
    int x;
    if (ctrl_b1) x = __builtin_amdgcn_mov_dpp(__float_as_int(v), 0xB1, 0xF, 0xF, true);
    else         x = __builtin_amdgcn_mov_dpp(__float_as_int(v), 0x4E, 0xF, 0xF, true);
    return __int_as_float(x);
}

// ============================================================================
// K1: channel LN + conv1x1 via MFMA (a-branch silu, z-branch raw -> bf16)
// grid (24, 16, 4) = (hh-pair, b, q), block 192 = 3 waves
// Verified R8: 729->633 us total. Unchanged.
// ============================================================================
__global__ __launch_bounds__(192) void k_lnconv(
    const float* __restrict__ x, const float* __restrict__ ln_g, const float* __restrict__ ln_b,
    const float* __restrict__ p1w, const float* __restrict__ p1b,
    const float* __restrict__ p2w, const float* __restrict__ p2b,
    bf16* __restrict__ a_out, bf16* __restrict__ z0_out)
{
    const int hh2 = blockIdx.x;           // 0..23 (covers 2 rows each)
    const int b = blockIdx.y, q = blockIdx.z;
    const int h0 = (q >> 1) * HQ, w0 = (q & 1) * HQ;
    const int tid = threadIdx.x;
    const int qb = q * BQ + b;

    __shared__ alignas(16) bf16 wl2[192 * 104];   // [row][k]
    __shared__ alignas(16) bf16 hn2[96 * 104];    // [p][c]
    __shared__ float mu[96], rs[96];
    __shared__ float pmu[192], pv2[192];
    __shared__ float biasLds[192];
    __shared__ float gl[96], bl[96];

    // stage weights [row][k] bf16: rows 0-95 = p1 (a), 96-191 = p2 (z)
    for (int t = tid; t < 192 * 24; t += 192) {
        int row = t / 24, c4 = (t % 24) * 4;
        const float* srcw = (row < 96) ? &p1w[(q * CN + row) * CN + c4]
                                       : &p2w[(q * CN + (row - 96)) * CN + c4];
        float4 wv = *reinterpret_cast<const float4*>(srcw);
        uint2 pk; pk.x = packbf(wv.x, wv.y); pk.y = packbf(wv.z, wv.w);
        *reinterpret_cast<uint2*>(&wl2[row * 104 + c4]) = pk;
    }
    if (tid < 192)
        biasLds[tid] = (tid < 96) ? p1b[q * CN + tid] : p2b[q * CN + (tid - 96)];
    if (tid < 96) { gl[tid] = ln_g[q * CN + tid]; bl[tid] = ln_b[q * CN + tid]; }
    // stage x tile TRANSPOSED to [p][c]
    for (int t = tid; t < CN * 24; t += 192) {
        int c = t / 24, v = t % 24;
        int row = v / 12, col = (v % 12) * 4;
        int p = row * 48 + col;
        float4 xv = *reinterpret_cast<const float4*>(
            &x[((b * CN + c) * 96 + h0 + 2 * hh2 + row) * 96 + w0 + col]);
        hn2[p * 104 + c]       = f2b(xv.x);
        hn2[(p + 1) * 104 + c] = f2b(xv.y);
        hn2[(p + 2) * 104 + c] = f2b(xv.z);
        hn2[(p + 3) * 104 + c] = f2b(xv.w);
    }
    __syncthreads();
    // LN stats: 192 thr = 96 pos x 2 halves of 48 ch (vectorized)
    {
        int p = tid % 96, half = tid / 96;
        const bf16* hp = &hn2[p * 104 + half * 48];
        float s = 0.f, s2 = 0.f;
        #pragma unroll
        for (int c8 = 0; c8 < 48; c8 += 8) {
            float f[8]; unpack8(*reinterpret_cast<const uint4*>(hp + c8), f);
            #pragma unroll
            for (int i = 0; i < 8; ++i) { s += f[i]; s2 += f[i] * f[i]; }
        }
        pmu[half * 96 + p] = s; pv2[half * 96 + p] = s2;
    }
    __syncthreads();
    if (tid < 96) {
        float s = pmu[tid] + pmu[96 + tid];
        float s2 = pv2[tid] + pv2[96 + tid];
        float m = s * (1.f / 96.f);
        float var = s2 * (1.f / 96.f) - m * m;
        mu[tid] = m; rs[tid] = rsqrtf(var + 1e-6f);
    }
    __syncthreads();
    // normalize in place: 96 pos x 12 octets
    for (int t = tid; t < 96 * 12; t += 192) {
        int p = t / 12, c8 = (t % 12) * 8;
        float f[8]; unpack8(*reinterpret_cast<const uint4*>(&hn2[p * 104 + c8]), f);
        float m = mu[p], r = rs[p];
        unsigned ou[4];
        #pragma unroll
        for (int i = 0; i < 8; i += 2) {
            float v0 = (f[i]     - m) * r * gl[c8 + i]     + bl[c8 + i];
            float v1 = (f[i + 1] - m) * r * gl[c8 + i + 1] + bl[c8 + i + 1];
            ou[i >> 1] = packbf(v0, v1);
        }
        uint4 ov; ov.x = ou[0]; ov.y = ou[1]; ov.z = ou[2]; ov.w = ou[3];
        *reinterpret_cast<uint4*>(&hn2[p * 104 + c8]) = ov;
    }
    __syncthreads();
    // MFMA: wave w owns M rows [w*64, w*64+64) = 4 M-tiles x 6 N-tiles
    const int w = tid >> 6;
    const int l = tid & 63;
    const int lr = l & 15;          // M row / N col within tile
    const int lq = l >> 4;          // quarter: k-block for A/B, row-block for D
    f32x4 acc[4][6];
    #pragma unroll
    for (int m = 0; m < 4; ++m)
        #pragma unroll
        for (int n = 0; n < 6; ++n)
            acc[m][n] = (f32x4){0.f, 0.f, 0.f, 0.f};
    #pragma unroll
    for (int k0 = 0; k0 < 96; k0 += 32) {
        bf16x8 afr[4], bfr[6];
        #pragma unroll
        for (int m = 0; m < 4; ++m)
            afr[m] = *reinterpret_cast<const bf16x8*>(
                &wl2[(w * 64 + m * 16 + lr) * 104 + k0 + lq * 8]);
        #pragma unroll
        for (int n = 0; n < 6; ++n)
            bfr[n] = *reinterpret_cast<const bf16x8*>(
                &hn2[(n * 16 + lr) * 104 + k0 + lq * 8]);
        #pragma unroll
        for (int m = 0; m < 4; ++m)
            #pragma unroll
            for (int n = 0; n < 6; ++n)
                acc[m][n] = __builtin_amdgcn_mfma_f32_16x16x32_bf16(
                    afr[m], bfr[n], acc[m][n], 0, 0, 0);
    }
    // epilogue: bias + (silu for a-rows) + bf16 store
    #pragma unroll
    for (int m = 0; m < 4; ++m) {
        const int Rbase = w * 64 + m * 16 + lq * 4;
        #pragma unroll
        for (int n = 0; n < 6; ++n) {
            const int col = n * 16 + lr;
            const int colin = (col >= 48) ? (col - 48) : col;       // col % 48 (48 != pow2!)
            const int lbase = (2 * hh2 + (col >= 48 ? 1 : 0)) * 48 + colin;
            #pragma unroll
            for (int r = 0; r < 4; ++r) {
                const int R = Rbase + r;
                const bool isA = R < 96;
                const int d = isA ? R : R - 96;
                float v = acc[m][n][r] + biasLds[R];
                if (isA) v = siluf(v);
                bf16* dst = isA ? a_out : z0_out;
                dst[(size_t)(qb * CN + d) * LL + lbase] = f2b(v);
            }
        }
    }
}

// ============================================================================
// K2: depthwise 3x3 SAME + bias + silu + block_idx transform (bf16 in/out)
// grid (96, 16, 4) = (c, b, q), block 256
// R10: output loop re-tiled to 8-wide -> uint4 stores (was 2B scalar).
// ============================================================================
__global__ __launch_bounds__(256) void k_dwconv(
    const bf16* __restrict__ z0, const float* __restrict__ dww, const float* __restrict__ dwb,
    const int* __restrict__ bidx, bf16* __restrict__ zt, bf16* __restrict__ ztT)
{
    const int c = blockIdx.x, b = blockIdx.y, q = blockIdx.z;
    const int tid = threadIdx.x;
    const int base = ((q * BQ + b) * CN + c) * LL;
    __shared__ float zin[50 * 50];  // 1-elem zero border
    __shared__ float zo[48 * 49];   // padded rows: conflict-free transposed reads
    // zero the border (196 cells, disjoint from interior staging)
    if (tid < 196) {
        int idx;
        if (tid < 50)       idx = tid;                    // row 0
        else if (tid < 100) idx = 49 * 50 + (tid - 50);   // row 49
        else if (tid < 148) idx = (tid - 99) * 50;        // col 0, rows 1..48
        else                idx = (tid - 147) * 50 + 49;  // col 49, rows 1..48
        zin[idx] = 0.f;
    }
    for (int t = tid; t < 288; t += 256) {
        uint4 v = *reinterpret_cast<const uint4*>(&z0[base + t * 8]);
        float f[8]; unpack8(v, f);
        int e0 = t * 8, row = e0 / 48, col = e0 % 48;
        float* dst = &zin[(row + 1) * 50 + col + 1];
        #pragma unroll
        for (int i = 0; i < 8; ++i) dst[i] = f[i];
    }
    float wk[9];
    #pragma unroll
    for (int i = 0; i < 9; ++i) wk[i] = dww[(q * CN + c) * 9 + i];
    const float bias = dwb[q * CN + c];
    __syncthreads();
    for (int t = tid; t < LL; t += 256) {
        int hh = t / 48, ww = t % 48;
        const float* z0r = &zin[hh * 50 + ww];        // top-left tap
        float s = bias;
        s = fmaf(wk[0], z0r[0],        s);
        s = fmaf(wk[1], z0r[1],        s);
        s = fmaf(wk[2], z0r[2],        s);
        s = fmaf(wk[3], z0r[50],       s);
        s = fmaf(wk[4], z0r[51],       s);
        s = fmaf(wk[5], z0r[52],       s);
        s = fmaf(wk[6], z0r[100],      s);
        s = fmaf(wk[7], z0r[101],      s);
        s = fmaf(wk[8], z0r[102],      s);
        zo[hh * 49 + ww] = siluf(s);
    }
    __syncthreads();
    const bool even = ((bidx[0] & 1) == 0);
    for (int idx = tid; idx < 288; idx += 256) {
        int e0 = idx * 8, i = e0 / 48, j = e0 % 48;   // j..j+7 same row (48 % 8 == 0)
        float vz[8], vzT[8];
        if (even) {
            #pragma unroll
            for (int m = 0; m < 8; ++m) { vz[m] = zo[(j + m) * 49 + i];  vzT[m] = zo[i * 49 + j + m]; }
        } else {
            #pragma unroll
            for (int m = 0; m < 8; ++m) { vz[m] = zo[(47 - i) * 49 + (47 - j - m)];
                                          vzT[m] = zo[(47 - j - m) * 49 + (47 - i)]; }
        }
        uint4 oa, ob;
        oa.x = packbf(vz[0], vz[1]);   oa.y = packbf(vz[2], vz[3]);
        oa.z = packbf(vz[4], vz[5]);   oa.w = packbf(vz[6], vz[7]);
        ob.x = packbf(vzT[0], vzT[1]); ob.y = packbf(vzT[2], vzT[3]);
        ob.z = packbf(vzT[4], vzT[5]); ob.w = packbf(vzT[6], vzT[7]);
        *reinterpret_cast<uint4*>(&zt[base + e0])  = oa;
        *reinterpret_cast<uint4*>(&ztT[base + e0]) = ob;
    }
}

// ============================================================================
// K3: x_dbl = xproj_w @ u_k via MFMA (direction mapping + reversal folded in)
// grid (24, 4, 64) = (l-tile of 96, k, q*16+b), block 192 = 3 waves
// R10: two-stage LDS transpose to kill R9's ~24-way scatter bank conflicts:
//   stage1 global->tmp[c][l] (linear uint4), stage2 tmp->ub[l][c] with l
//   varying across lanes (reads hit 32 distinct banks; writes one uint4/row).
//   MFMA/stores identical to R9-verified math (absmax 0.2255859).
// ============================================================================
__global__ __launch_bounds__(192) void k_xdbl(
    const bf16* __restrict__ zt, const bf16* __restrict__ ztT,
    const float* __restrict__ xprojw, bf16* __restrict__ xdbl)
{
    const int lt = blockIdx.x, k = blockIdx.y, qb = blockIdx.z;
    const int tid = threadIdx.x;
    const int l0 = lt * 96;
    const int q = qb >> 4;
    __shared__ alignas(16) bf16 wl3[32 * 104];    // [d][c], rows 22-31 zero
    __shared__ alignas(16) bf16 tmp[96 * 104];    // [c][l_local]
    __shared__ alignas(16) bf16 ub[96 * 104];     // [l_local][c]
    const bf16* __restrict__ src = (k & 1) ? ztT : zt;
    const bool rev = (k >= 2);

    // zero pad rows 22..31 of wl3 (520 dwords)
    for (int t = tid; t < 520; t += 192)
        reinterpret_cast<unsigned*>(&wl3[22 * 104])[t] = 0u;
    // stage weights [d][c] bf16
    for (int t = tid; t < DPJ * 24; t += 192) {
        int d = t / 24, c4 = (t % 24) * 4;
        float4 wv = *reinterpret_cast<const float4*>(
            &xprojw[((q * NK + k) * DPJ + d) * CN + c4]);
        uint2 pk; pk.x = packbf(wv.x, wv.y); pk.y = packbf(wv.z, wv.w);
        *reinterpret_cast<uint2*>(&wl3[d * 104 + c4]) = pk;
    }
    // stage1: coalesced global -> tmp[c][l] linear (reversal folded in)
    for (int t = tid; t < CN * 12; t += 192) {     // 96 c x 12 groups of 8
        int cc = t / 12, j0 = (t % 12) * 8;
        uint4 v;
        if (!rev) {
            v = *reinterpret_cast<const uint4*>(&src[(size_t)(qb * CN + cc) * LL + l0 + j0]);
        } else {
            v = *reinterpret_cast<const uint4*>(&src[(size_t)(qb * CN + cc) * LL + (LL - (l0 + j0) - 8)]);
            uint4 r; r.x = rot16(v.w); r.y = rot16(v.z); r.z = rot16(v.y); r.w = rot16(v.x);
            v = r;
        }
        *reinterpret_cast<uint4*>(&tmp[cc * 104 + j0]) = v;
    }
    __syncthreads();
    // stage2: transpose tmp -> ub; l fastest across lanes (conflict-free reads)
    for (int t = tid; t < 96 * 12; t += 192) {
        int ll = t % 96, c0 = (t / 96) * 8;
        const unsigned short* ts = reinterpret_cast<const unsigned short*>(tmp);
        unsigned e[8];
        #pragma unroll
        for (int i = 0; i < 8; ++i) e[i] = ts[(c0 + i) * 104 + ll];
        uint4 v;
        v.x = e[0] | (e[1] << 16); v.y = e[2] | (e[3] << 16);
        v.z = e[4] | (e[5] << 16); v.w = e[6] | (e[7] << 16);
        *reinterpret_cast<uint4*>(&ub[ll * 104 + c0]) = v;
    }
    __syncthreads();
    // MFMA: wave w owns n-tiles 2w, 2w+1; M-tiles 0 (d 0-15), 1 (d 16-21+pad)
    const int w = tid >> 6;
    const int ln = tid & 63;
    const int lr = ln & 15;          // M row / N col within tile
    const int lq = ln >> 4;          // quarter: k-block for A/B, row-block for D
    f32x4 acc[2][2];
    #pragma unroll
    for (int m = 0; m < 2; ++m)
        #pragma unroll
        for (int n = 0; n < 2; ++n)
            acc[m][n] = (f32x4){0.f, 0.f, 0.f, 0.f};
    #pragma unroll
    for (int k0 = 0; k0 < 96; k0 += 32) {
        bf16x8 afr[2], bfr[2];
        #pragma unroll
        for (int m = 0; m < 2; ++m)
            afr[m] = *reinterpret_cast<const bf16x8*>(
                &wl3[(m * 16 + lr) * 104 + k0 + lq * 8]);
        #pragma unroll
        for (int n = 0; n < 2; ++n)
            bfr[n] = *reinterpret_cast<const bf16x8*>(
                &ub[((2 * w + n) * 16 + lr) * 104 + k0 + lq * 8]);
        #pragma unroll
        for (int m = 0; m < 2; ++m)
            #pragma unroll
            for (int n = 0; n < 2; ++n)
                acc[m][n] = __builtin_amdgcn_mfma_f32_16x16x32_bf16(
                    afr[m], bfr[n], acc[m][n], 0, 0, 0);
    }
    // store: D row = m*16 + lq*4 + r (guard < 22), col = l0 + (2w+n)*16 + lr
    const size_t obase = (size_t)(qb * NK + k) * (DPJ * LL);
    #pragma unroll
    for (int m = 0; m < 2; ++m) {
        #pragma unroll
        for (int n = 0; n < 2; ++n) {
            const int lpos = l0 + (2 * w + n) * 16 + lr;
            #pragma unroll
            for (int r = 0; r < 4; ++r) {
                const int d = m * 16 + lq * 4 + r;
                if (d < DPJ)
                    xdbl[obase + (size_t)d * LL + lpos] = f2b(acc[m][n][r]);
            }
        }
    }
}

// ============================================================================
// K4: fused delta(softplus) + selective scan + Ds*u term
// grid (512), block 384 producer/consumer — UNCHANGED (anchor, ~263 us warm)
// ============================================================================

// raw barrier: drain LDS (cross-wave visibility of ds_writes) but NOT vmcnt
#define SCAN_BARRIER() asm volatile("s_waitcnt lgkmcnt(0)\n\ts_barrier" ::: "memory")

// word IDX (0..23) of a 6-uint4 register array holding 48 bf16
#define UWORD(NUA, IDX) (((IDX) & 3) == 0 ? NUA[(IDX) >> 2].x : \
                         ((IDX) & 3) == 1 ? NUA[(IDX) >> 2].y : \
                         ((IDX) & 3) == 2 ? NUA[(IDX) >> 2].z : NUA[(IDX) >> 2].w)

#define ROT3(v) (v) = ((v) == 2) ? 0 : ((v) + 1)

__global__ __launch_bounds__(384) void k_scan(
    const bf16* __restrict__ zt, const bf16* __restrict__ ztT,
    const bf16* __restrict__ xdbl,
    const float* __restrict__ dtw_g, const float* __restrict__ dtb_g,
    const float* __restrict__ Alog_g, const float* __restrict__ Ds_g,
    bf16* __restrict__ ys)
{
    const int bid = blockIdx.x;
    const int ch2 = bid & 1, k = (bid >> 1) & 3, qb = bid >> 3, q = qb >> 4;
    const int qk = q * NK + k;
    const int tid = threadIdx.x;
    const bool isScan = (tid < 192);
    const int lt = isScan ? tid : (tid - 192);   // role-local 0..191
    const int ca = lt >> 2, p = lt & 3;
    const int c = ch2 * 48 + ca;          // global channel

    __shared__ float dd3[3][48 * 52];
    __shared__ float xr3[3][6 * 52];          // dts rows
    __shared__ float bcv3[3][48 * 16];        // [j][p*4 + {B0,B1,C0,C1}]

    const bf16* __restrict__ src = (k & 1) ? ztT : zt;
    const bool rev = (k >= 2);
    const int ja = p * 12;

    // ---- producer-role parameters ----
    float wdt[6] = {0.f, 0.f, 0.f, 0.f, 0.f, 0.f};
    float dtbc = 0.f;
    if (!isScan) {
        const float* wp = dtw_g + (size_t)qk * CN * RR + c * RR;
        float2 wa = *reinterpret_cast<const float2*>(wp);
        float2 wb = *reinterpret_cast<const float2*>(wp + 2);
        float2 wc = *reinterpret_cast<const float2*>(wp + 4);
        wdt[0] = wa.x; wdt[1] = wa.y; wdt[2] = wb.x; wdt[3] = wb.y; wdt[4] = wc.x; wdt[5] = wc.y;
        dtbc = dtb_g[qk * CN + c];
    }
    // xdbl staging: producer threads with lt<132 stage one uint4 from row vr
    const bool xload = (!isScan) && (lt < 132);
    const int vr = lt / 6, jx = (lt % 6) * 8;
    const bf16* gx = xdbl + (size_t)(qb * NK + k) * (DPJ * LL) + (size_t)vr * LL + jx;
    int bccol = 0;
    if (vr >= 6) {
        int v = vr - 6;           // 0..15: 0-7 B, 8-15 C
        int n = v & 7;
        bccol = (n >> 1) * 4 + ((v >= 8) ? 2 : 0) + (n & 1);
    }

    // ---- scan-role parameters ----
    float A0L = 0.f, A1L = 0.f, Dc = 0.f;
    if (isScan) {
        A0L = -__expf(Alog_g[((size_t)qk * CN + c) * NNS + 2 * p])     * LOG2E;
        A1L = -__expf(Alog_g[((size_t)qk * CN + c) * NNS + 2 * p + 1]) * LOG2E;
        Dc = Ds_g[qk * CN + c];
    }
    float h0 = 0.f, h1 = 0.f;
    const bf16* gu = src + (size_t)(qb * CN + c) * LL + (rev ? (LL - 48) : 0);
    const int ustep = rev ? -48 : 48;
    bf16* yp = ys + (size_t)(qb * NK + k) * (CN * LL) + (size_t)c * LL;  // p==0 stores

    #define COMMIT_BLOCK(PXV, XRB, BCB) do {                                          \
        if (xload) {                                                                  \
            float g[8]; unpack8(PXV, g);                                              \
            if (vr < 6) {                                                             \
                *reinterpret_cast<float4*>(&(XRB)[vr * 52 + jx])                      \
                    = make_float4(g[0], g[1], g[2], g[3]);                            \
                *reinterpret_cast<float4*>(&(XRB)[vr * 52 + jx + 4])                  \
                    = make_float4(g[4], g[5], g[6], g[7]);                            \
            } else {                                                                  \
                _Pragma("unroll")                                                     \
                for (int i = 0; i < 8; ++i) (BCB)[(jx + i) * 16 + bccol] = g[i];      \
            }                                                                         \
        }                                                                             \
    } while (0)

    #define DELTA_BLOCK(XRB, DDB) do {                                                \
        float acc[12];                                                                \
        _Pragma("unroll")                                                             \
        for (int i = 0; i < 12; ++i) acc[i] = dtbc;                                   \
        _Pragma("unroll")                                                             \
        for (int r = 0; r < 6; ++r) {                                                 \
            float4 d0 = *reinterpret_cast<const float4*>(&(XRB)[r * 52 + ja]);        \
            float4 d1 = *reinterpret_cast<const float4*>(&(XRB)[r * 52 + ja + 4]);    \
            float4 d2 = *reinterpret_cast<const float4*>(&(XRB)[r * 52 + ja + 8]);    \
            float wr_ = wdt[r];                                                       \
            acc[0] = fmaf(wr_, d0.x, acc[0]);  acc[1] = fmaf(wr_, d0.y, acc[1]);      \
            acc[2] = fmaf(wr_, d0.z, acc[2]);  acc[3] = fmaf(wr_, d0.w, acc[3]);      \
            acc[4] = fmaf(wr_, d1.x, acc[4]);  acc[5] = fmaf(wr_, d1.y, acc[5]);      \
            acc[6] = fmaf(wr_, d1.z, acc[6]);  acc[7] = fmaf(wr_, d1.w, acc[7]);      \
            acc[8] = fmaf(wr_, d2.x, acc[8]);  acc[9] = fmaf(wr_, d2.y, acc[9]);      \
            acc[10] = fmaf(wr_, d2.z, acc[10]); acc[11] = fmaf(wr_, d2.w, acc[11]);   \
        }                                                                             \
        _Pragma("unroll")                                                             \
        for (int i = 0; i < 12; ++i) {                                                \
            float a = acc[i];                                                         \
            acc[i] = (a > 15.f) ? a : __logf(1.f + __expf(a));                        \
        }                                                                             \
        float4* dp = reinterpret_cast<float4*>(&(DDB)[ca * 52 + ja]);                 \
        dp[0] = make_float4(acc[0], acc[1], acc[2], acc[3]);                          \
        dp[1] = make_float4(acc[4], acc[5], acc[6], acc[7]);                          \
        dp[2] = make_float4(acc[8], acc[9], acc[10], acc[11]);                        \
    } while (0)

    // ---- prologue ----
    uint4 u_a[6], u_b[6];
    uint4 px_a = {0,0,0,0}, px_b = {0,0,0,0}, px1 = {0,0,0,0};
    if (isScan) {
        #pragma unroll
        for (int i = 0; i < 6; ++i) u_a[i] = *reinterpret_cast<const uint4*>(gu + i * 8);  // chunk 0
        gu += ustep;
        #pragma unroll
        for (int i = 0; i < 6; ++i) u_b[i] = *reinterpret_cast<const uint4*>(gu + i * 8);  // chunk 1
        gu += ustep;                                           // -> chunk 2
    } else {
        uint4 px0 = {0,0,0,0};
        if (xload) {
            px0  = *reinterpret_cast<const uint4*>(gx);        // chunk 0
            px1  = *reinterpret_cast<const uint4*>(gx + 48);   // chunk 1
            px_a = *reinterpret_cast<const uint4*>(gx + 96);   // chunk 2
            px_b = *reinterpret_cast<const uint4*>(gx + 144);  // chunk 3
            gx += 192;                                         // -> chunk 4
        }
        COMMIT_BLOCK(px0, xr3[0], bcv3[0]);
    }
    SCAN_BARRIER();
    if (!isScan) {
        DELTA_BLOCK(xr3[0], dd3[0]);
        COMMIT_BLOCK(px1, xr3[1], bcv3[1]);
    }
    SCAN_BARRIER();

    // buffer cursors
    int s_cur = 0;              // scan:  buf of chunk ch
    int d_idx = 1, c_idx = 2;   // prod:  delta buf (ch+1), commit buf (ch+2)

    #define PROD_BODY(CH, PX) do {                                                    \
        const int chp_ = (CH);                                                        \
        if (chp_ + 2 < 48) COMMIT_BLOCK(PX, xr3[c_idx], bcv3[c_idx]);                 \
        if (chp_ + 4 < 48 && xload) { PX = *reinterpret_cast<const uint4*>(gx); gx += 48; } \
        if (chp_ + 1 < 48) DELTA_BLOCK(xr3[d_idx], dd3[d_idx]);                       \
        ROT3(d_idx); ROT3(c_idx);                                                     \
    } while (0)

    #define SCAN_CHUNK(CH, UC) do {                                                   \
        const int ch_ = (CH);                                                         \
        uint4 nu[6];                                                                  \
        if (!rev) {                                                                   \
            nu[0] = UC[0]; nu[1] = UC[1]; nu[2] = UC[2];                              \
            nu[3] = UC[3]; nu[4] = UC[4]; nu[5] = UC[5];                              \
        } else {                                                                      \
            _Pragma("unroll")                                                         \
            for (int qq = 0; qq < 6; ++qq) {                                          \
                nu[qq].x = rot16(UC[5 - qq].w); nu[qq].y = rot16(UC[5 - qq].z);       \
                nu[qq].z = rot16(UC[5 - qq].y); nu[qq].w = rot16(UC[5 - qq].x);       \
            }                                                                         \
        }                                                                             \
        {                                                                             \
            const int l0 = ch_ * 48;                                                  \
            const float* ddc = &dd3[s_cur][ca * 52];                                  \
            const float* bcc = &bcv3[s_cur][p * 4];                                   \
            _Pragma("unroll")                                                         \
            for (int gg = 0; gg < 6; ++gg) {                                          \
                unsigned pk[4];                                                       \
                _Pragma("unroll")                                                     \
                for (int half = 0; half < 2; ++half) {                                \
                    const int j0 = gg * 8 + half * 4;                                 \
                    float4 d4 = *reinterpret_cast<const float4*>(ddc + j0);           \
                    const float* df = reinterpret_cast<const float*>(&d4);            \
                    _Pragma("unroll")                                                 \
                    for (int s = 0; s < 4; ++s) {                                     \
                        const int j = j0 + s;                                         \
                        const unsigned uwv = UWORD(nu, j >> 1);                       \
                        float u = (j & 1) ? bfhi(uwv) : bflo(uwv);                    \
                        float d = df[s];                                              \
                        float4 bq = *reinterpret_cast<const float4*>(bcc + j * 16);   \
                        float du = d * u;                                             \
                        float dA0 = fexp2(d * A0L);                                   \
                        float dA1 = fexp2(d * A1L);                                   \
                        h0 = fmaf(dA0, h0, du * bq.x);                                \
                        h1 = fmaf(dA1, h1, du * bq.y);                                \
                        float y = fmaf(h0, bq.z, h1 * bq.w);                          \
                        y += qxor(y, 1); y += qxor(y, 0);                             \
                        y = fmaf(Dc, u, y);                                           \
                        unsigned hb = (unsigned)__builtin_bit_cast(unsigned short, f2b(y)); \
                        const int sl = half * 4 + s;                                  \
                        if (sl & 1) pk[sl >> 1] |= hb << 16; else pk[sl >> 1] = hb;   \
                    }                                                                 \
                }                                                                     \
                if (p == 0) {                                                         \
                    uint4 wv4; wv4.x = pk[0]; wv4.y = pk[1]; wv4.z = pk[2]; wv4.w = pk[3]; \
                    *reinterpret_cast<uint4*>(yp + l0 + gg * 8) = wv4;                \
                }                                                                     \
            }                                                                         \
        }                                                                             \
        if (ch_ + 2 < 48) {                                                           \
            _Pragma("unroll")                                                         \
            for (int i = 0; i < 6; ++i) UC[i] = *reinterpret_cast<const uint4*>(gu + i * 8); \
            gu += ustep;                                                              \
        }                                                                             \
        ROT3(s_cur);                                                                  \
    } while (0)

    for (int t = 0; t < 24; ++t) {
        if (isScan) SCAN_CHUNK(2 * t, u_a);
        else        PROD_BODY(2 * t, px_a);
        SCAN_BARRIER();
        if (isScan) SCAN_CHUNK(2 * t + 1, u_b);
        else        PROD_BODY(2 * t + 1, px_b);
        SCAN_BARRIER();
    }

    #undef SCAN_CHUNK
    #undef PROD_BODY
    #undef DELTA_BLOCK
    #undef COMMIT_BLOCK
}

// ============================================================================
// K4b: k_sum — combine 4 directions into one tensor at combine-index m
// grid (96, 16, 4) = (c, b, q), block 256
// ============================================================================
__global__ __launch_bounds__(256) void k_sum(
    const bf16* __restrict__ ys, bf16* __restrict__ s_out)
{
    const int c = blockIdx.x, b = blockIdx.y, q = blockIdx.z;
    const int qb = q * BQ + b;
    const int tid = threadIdx.x;
    __shared__ float t0[48 * 49];
    __shared__ float t2[48 * 49];
    const size_t base0 = ((size_t)(qb * NK + 0) * CN + c) * LL;
    const size_t base1 = ((size_t)(qb * NK + 1) * CN + c) * LL;
    const size_t base2 = ((size_t)(qb * NK + 2) * CN + c) * LL;
    const size_t base3 = ((size_t)(qb * NK + 3) * CN + c) * LL;
    for (int idx = tid; idx < 288; idx += 256) {
        int e0 = idx * 8, h = e0 / 48, w = e0 % 48;
        float f[8];
        unpack8(*reinterpret_cast<const uint4*>(&ys[base0 + e0]), f);
        #pragma unroll
        for (int i = 0; i < 8; ++i) t0[h * 49 + w + i] = f[i];
        unpack8(*reinterpret_cast<const uint4*>(&ys[base2 + e0]), f);
        #pragma unroll
        for (int i = 0; i < 8; ++i) t2[h * 49 + w + i] = f[i];
    }
    __syncthreads();
    const size_t cbase = ((size_t)qb * CN + c) * LL;
    for (int idx = tid; idx < 288; idx += 256) {
        int m0 = idx * 8, ww = m0 / 48, hh = m0 % 48;
        float f1[8], f3[8];
        unpack8(*reinterpret_cast<const uint4*>(&ys[base1 + m0]), f1);
        unpack8(*reinterpret_cast<const uint4*>(&ys[base3 + (LL - 8 - m0)]), f3);
        float o[8];
        #pragma unroll
        for (int i = 0; i < 8; ++i) {
            float v0 = t0[(hh + i) * 49 + ww];
            float v2 = t2[(47 - hh - i) * 49 + (47 - ww)];
            o[i] = v0 + f1[i] + v2 + f3[7 - i];
        }
        uint4 w;
        w.x = packbf(o[0], o[1]); w.y = packbf(o[2], o[3]);
        w.z = packbf(o[4], o[5]); w.w = packbf(o[6], o[7]);
        *reinterpret_cast<uint4*>(&s_out[cbase + m0]) = w;
    }
}

// ============================================================================
// K5: combine: LN(ssln) + LN(p2n) + y=a*z + attention partial sums
// grid (48, 16, 4) = (ww, b, q), block 256
// ============================================================================
__global__ __launch_bounds__(256) void k_combine(
    const bf16* __restrict__ s_in, const bf16* __restrict__ a_in,
    const float* __restrict__ ssg, const float* __restrict__ ssb,
    const float* __restrict__ png, const float* __restrict__ pnb,
    const int* __restrict__ bidx,
    bf16* __restrict__ y_out, float* __restrict__ s_buf)
{
    const int ww = blockIdx.x, b = blockIdx.y, q = blockIdx.z;
    const int qb = q * BQ + b;
    const int tid = threadIdx.x;
    __shared__ float o[CN * 48];
    __shared__ float mu[48], rs[48];
    __shared__ float pp[192], pp2[192];
    for (int v = tid; v < 576; v += 256) {
        int e0 = v * 8, cc = e0 / 48, hh = e0 % 48;
        float f[8];
        unpack8(*reinterpret_cast<const uint4*>(&s_in[((size_t)qb * CN + cc) * LL + ww * 48 + hh]), f);
        #pragma unroll
        for (int i = 0; i < 8; ++i) o[cc * 48 + hh + i] = f[i];
    }
    __syncthreads();
    // stats phase 1: 192 threads = 48 hh x 4 parts of 24 ch
    if (tid < 192) {
        int hh = tid % 48, part = tid / 48;
        float s = 0.f, s2 = 0.f;
        int c0 = part * 24;
        for (int cc = c0; cc < c0 + 24; ++cc) { float v = o[cc * 48 + hh]; s += v; s2 += v * v; }
        pp[tid] = s; pp2[tid] = s2;
    }
    __syncthreads();
    if (tid < 48) {
        float s = pp[tid] + pp[tid + 48] + pp[tid + 96] + pp[tid + 144];
        float s2 = pp2[tid] + pp2[tid + 48] + pp2[tid + 96] + pp2[tid + 144];
        float m = s * (1.f / 96.f), var = s2 * (1.f / 96.f) - m * m;
        mu[tid] = m; rs[tid] = rsqrtf(var + 1e-6f);
    }
    __syncthreads();
    for (int t = tid; t < CN * 48; t += 256) {
        int cc = t / 48, hh = t % 48;
        o[t] = (o[t] - mu[hh]) * rs[hh] * ssg[q * CN + cc] + ssb[q * CN + cc];
    }
    __syncthreads();
    // stats phase 2
    if (tid < 192) {
        int hh = tid % 48, part = tid / 48;
        float s = 0.f, s2 = 0.f;
        int c0 = part * 24;
        for (int cc = c0; cc < c0 + 24; ++cc) { float v = o[cc * 48 + hh]; s += v; s2 += v * v; }
        pp[tid] = s; pp2[tid] = s2;
    }
    __syncthreads();
    if (tid < 48) {
        float s = pp[tid] + pp[tid + 48] + pp[tid + 96] + pp[tid + 144];
        float s2 = pp2[tid] + pp2[tid + 48] + pp2[tid + 96] + pp2[tid + 144];
        float m = s * (1.f / 96.f), var = s2 * (1.f / 96.f) - m * m;
        mu[tid] = m; rs[tid] = rsqrtf(var + 1e-6f);
    }
    __syncthreads();
    const bool even = ((bidx[0] & 1) == 0);
    if (even) {
        for (int v = tid; v < 576; v += 256) {
            int e0 = v * 8, cc = e0 / 48, hh = e0 % 48;
            size_t oidx = ((size_t)qb * CN + cc) * LL + ww * 48 + hh;
            float af[8];
            unpack8(*reinterpret_cast<const uint4*>(&a_in[oidx]), af);
            float yv[8];
            #pragma unroll
            for (int i = 0; i < 8; ++i) {
                float z2 = (o[cc * 48 + hh + i] - mu[hh + i]) * rs[hh + i] * png[q * CN + cc] + pnb[q * CN + cc];
                yv[i] = af[i] * z2;
                o[cc * 48 + hh + i] = yv[i];
            }
            uint4 w;
            w.x = packbf(yv[0], yv[1]); w.y = packbf(yv[2], yv[3]);
            w.z = packbf(yv[4], yv[5]); w.w = packbf(yv[6], yv[7]);
            *reinterpret_cast<uint4*>(&y_out[oidx]) = w;
        }
    } else {
        for (int t = tid; t < CN * 48; t += 256) {
            int cc = t / 48, hh = t % 48;
            float z2 = (o[t] - mu[hh]) * rs[hh] * png[q * CN + cc] + pnb[q * CN + cc];
            size_t oidx = ((size_t)qb * CN + cc) * LL + (47 - hh) * 48 + (47 - ww);
            float yv = b2f(a_in[oidx]) * z2;
            y_out[oidx] = f2b(yv);
            o[t] = yv;
        }
    }
    __syncthreads();
    if (tid < CN) {
        float s = 0.f;
        for (int j = 0; j < 48; ++j) s += o[tid * 48 + j];
        atomicAdd(&s_buf[qb * CN + tid], s);
    }
}

// ============================================================================
// K7: out = x + y * att  with channel attention computed in-block
// grid (96, 16, 4) = (c, b, q), block 256
// ============================================================================
__global__ __launch_bounds__(256) void k_final(
    const float* __restrict__ x, const bf16* __restrict__ y_in,
    const float* __restrict__ s_buf,
    const float* __restrict__ w1, const float* __restrict__ b1,
    const float* __restrict__ w2, const float* __restrict__ b2,
    float* __restrict__ out)
{
    const int c = blockIdx.x, b = blockIdx.y, q = blockIdx.z;
    const int h0 = (q >> 1) * HQ, w0 = (q & 1) * HQ;
    const int qb = q * BQ + b;
    const int tid = threadIdx.x;
    __shared__ float tl[CRr];
    __shared__ float tpart[16 * CRr];
    __shared__ float attv;
    if (tid < 192) {
        int r = tid % CRr, part = tid / CRr;   // 16 parts x 6 channels
        float acc = 0.f;
        const float* wr = w1 + (q * CRr + r) * CN;
        const float* sb = s_buf + qb * CN;
        int c0 = part * 6;
        for (int cc = c0; cc < c0 + 6; ++cc)
            acc = fmaf(wr[cc], sb[cc] * (1.f / (float)LL), acc);
        tpart[part * CRr + r] = acc;
    }
    __syncthreads();
    if (tid < CRr) {
        float acc = b1[q * CRr + tid];
        #pragma unroll
        for (int pt = 0; pt < 16; ++pt) acc += tpart[pt * CRr + tid];
        tl[tid] = siluf(acc);
    }
    __syncthreads();
    if (tid == 0) {
        float acc = b2[q * CN + c];
        #pragma unroll
        for (int r = 0; r < CRr; ++r) acc = fmaf(w2[(q * CN + c) * CRr + r], tl[r], acc);
        attv = sigf(acc);
    }
    __syncthreads();
    const float av = attv;
    const size_t ybase = (size_t)(qb * CN + c) * LL;
    const int xb = (b * CN + c) * 9216 + h0 * 96 + w0;
    for (int t = tid; t < LL / 8; t += 256) {
        int e0 = t * 8;
        int gi = xb + (e0 / 48) * 96 + (e0 % 48);
        uint4 yv = *reinterpret_cast<const uint4*>(&y_in[ybase + e0]);
        float yf[8]; unpack8(yv, yf);
        float4 xa = *reinterpret_cast<const float4*>(&x[gi]);
        float4 xc = *reinterpret_cast<const float4*>(&x[gi + 4]);
        float4 o0 = {xa.x + yf[0]*av, xa.y + yf[1]*av, xa.z + yf[2]*av, xa.w + yf[3]*av};
        float4 o1 = {xc.x + yf[4]*av, xc.y + yf[5]*av, xc.z + yf[6]*av, xc.w + yf[7]*av};
        *reinterpret_cast<float4*>(&out[gi])     = o0;
        *reinterpret_cast<float4*>(&out[gi + 4]) = o1;
    }
}

// ============================================================================
extern "C" void kernel_launch(void* const* d_in, const int* in_sizes, int n_in,
                              void* d_out, int out_size, void* d_ws, size_t ws_size,
                              hipStream_t stream)
{
    (void)in_sizes; (void)n_in; (void)out_size; (void)ws_size;
    const float* x       = (const float*)d_in[0];
    const float* ln_g    = (const float*)d_in[1];
    const float* ln_b    = (const float*)d_in[2];
    const float* p1_w    = (const float*)d_in[3];
    const float* p1_b    = (const float*)d_in[4];
    const float* p2in_w  = (const float*)d_in[5];
    const float* p2in_b  = (const float*)d_in[6];
    const float* dw_w    = (const float*)d_in[7];
    const float* dw_b    = (const float*)d_in[8];
    const float* xproj_w = (const float*)d_in[9];
    const float* dtproj_w= (const float*)d_in[10];
    const float* dtproj_b= (const float*)d_in[11];
    const float* A_logs  = (const float*)d_in[12];
    const float* Ds      = (const float*)d_in[13];
    const float* ssln_g  = (const float*)d_in[14];
    const float* ssln_b  = (const float*)d_in[15];
    const float* p2n_g   = (const float*)d_in[16];
    const float* p2n_b   = (const float*)d_in[17];
    const float* ca_w1   = (const float*)d_in[18];
    const float* ca_b1   = (const float*)d_in[19];
    const float* ca_w2   = (const float*)d_in[20];
    const float* ca_b2   = (const float*)d_in[21];
    const int*  bidx     = (const int*)d_in[22];
    float* out = (float*)d_out;

    char* ws = (char*)d_ws;
    const size_t off_a    = 0;                                  // bf16, live K1->K5
    const size_t off_zt   = 28311552;                           // bf16, live K2->K4
    const size_t off_ztT  = 56623104;                           // bf16, live K2->K4
    const size_t off_xdbl = 84934656;                           // bf16, live K3->K4
    const size_t off_ys   = 110886912;                          // bf16, live K4->K4b
    const size_t off_z0   = off_ys;                             // bf16 alias (dead before ys)
    const size_t off_s    = off_zt;                             // bf16 alias: sum tensor (K4b->K5)
    const size_t off_y    = off_ztT;                            // bf16 alias: gated y (K5->K7)
    const size_t off_sb   = 224133120;                          // fp32 attention sums

    bf16*  a_buf   = (bf16*)(ws + off_a);
    bf16*  zt_buf  = (bf16*)(ws + off_zt);
    bf16*  ztT_buf = (bf16*)(ws + off_ztT);
    bf16*  xdbl_buf= (bf16*)(ws + off_xdbl);
    bf16*  ys_buf  = (bf16*)(ws + off_ys);
    bf16*  z0_buf  = (bf16*)(ws + off_z0);
    bf16*  s_sum   = (bf16*)(ws + off_s);
    bf16*  y_buf   = (bf16*)(ws + off_y);
    float* s_buf   = (float*)(ws + off_sb);

    (void)hipMemsetAsync(ws + off_sb, 0, 24576, stream);

    k_lnconv<<<dim3(24, 16, 4), 192, 0, stream>>>(
        x, ln_g, ln_b, p1_w, p1_b, p2in_w, p2in_b, a_buf, z0_buf);
    k_dwconv<<<dim3(96, 16, 4), 256, 0, stream>>>(
        z0_buf, dw_w, dw_b, bidx, zt_buf, ztT_buf);
    k_xdbl<<<dim3(24, 4, 64), 192, 0, stream>>>(
        zt_buf, ztT_buf, xproj_w, xdbl_buf);
    k_scan<<<dim3(512), 384, 0, stream>>>(
        zt_buf, ztT_buf, xdbl_buf, dtproj_w, dtproj_b, A_logs, Ds, ys_buf);
    k_sum<<<dim3(96, 16, 4), 256, 0, stream>>>(
        ys_buf, s_sum);
    k_combine<<<dim3(48, 16, 4), 256, 0, stream>>>(
        s_sum, a_buf, ssln_g, ssln_b, p2n_g, p2n_b, bidx, y_buf, s_buf);
    k_final<<<dim3(96, 16, 4), 256, 0, stream>>>(
        x, y_buf, s_buf, ca_w1, ca_b1, ca_w2, ca_b2, out);
}